// Round 2
// baseline (1244.471 us; speedup 1.0000x reference)
//
#include <hip/hip_runtime.h>
#include <stdint.h>

#define N_TASK 50000
#define N_RET 20000
#define N_DRAM 5000
#define N_LINK 100000
#define E_RET 1000000
#define E_DRAM 250000
#define E_LINK 2000000
#define HF 64

// histogram partitioning for per-task min/max
#define R_PART 3125            // tasks per partition (LDS: 3125*2*4B = 25 KB)
#define P_PART 16              // partitions: 16*3125 = 50000 == N_TASK
#define B_RET 6                // edge slices per partition, etype ret
#define B_DRAM 2
#define B_LINK 12
#define PW_RET 0                                   // word offsets in pmax plane
#define PW_DRAM (P_PART * B_RET * R_PART)          // 300000
#define PW_LINK (PW_DRAM + P_PART * B_DRAM * R_PART)  // 400000
#define PW_TOT (PW_LINK + P_PART * B_LINK * R_PART)   // 1000000 words per plane

// ---- order-preserving float<->uint transform (for min/max on float as uint) ----
// ford(f) is strictly monotone; ford never produces 0x00000000 nor 0xFFFFFFFF for
// non-NaN inputs, so 0 / 0xFFFFFFFF are safe "empty" sentinels for max / min.
__device__ __forceinline__ unsigned ford(float f) {
  unsigned u = __float_as_uint(f);
  return (u & 0x80000000u) ? ~u : (u | 0x80000000u);
}
__device__ __forceinline__ float funord(unsigned t) {
  unsigned u = (t & 0x80000000u) ? (t & 0x7fffffffu) : ~t;
  return __uint_as_float(u);
}

// ---- K1: scalar segment sums per module + link degree counts ----
__global__ void k_segsum(const float* __restrict__ fr, const float* __restrict__ fd,
                         const float* __restrict__ fl,
                         const int* __restrict__ mr, const int* __restrict__ md,
                         const int* __restrict__ ml,
                         float* s_ret, float* s_dram, float* s_link, int* cnt) {
  int i = blockIdx.x * blockDim.x + threadIdx.x;
  const int total = E_RET + E_DRAM + E_LINK;
  if (i >= total) return;
  if (i < E_RET) {
    atomicAdd(&s_ret[mr[i]], fr[i]);
  } else if (i < E_RET + E_DRAM) {
    int j = i - E_RET;
    atomicAdd(&s_dram[md[j]], fd[j]);
  } else {
    int j = i - (E_RET + E_DRAM);
    int m = ml[j];
    atomicAdd(&s_link[m], fl[j]);
    atomicAdd(&cnt[m], 1);
  }
}

// ---- K2a: LDS-privatized per-task min/max histogram (no global atomics) ----
// Block = (etype, partition p over task range, slice b over edges).
// Flushes full R_PART-range partials (sentinels where untouched) to `partials`:
// pmax plane at [0, PW_TOT), pmin plane at [PW_TOT, 2*PW_TOT).
__global__ __launch_bounds__(256) void k_hist(
    const int* __restrict__ tr, const int* __restrict__ mr,
    const int* __restrict__ td, const int* __restrict__ md,
    const int* __restrict__ tl, const int* __restrict__ ml,
    const float* __restrict__ s_ret, const float* __restrict__ s_dram,
    const float* __restrict__ s_link, unsigned* __restrict__ partials) {
  __shared__ unsigned lmax[R_PART];
  __shared__ unsigned lmin[R_PART];
  int blk = blockIdx.x;
  const int* task; const int* mod; const float* s;
  int B, E0, base;
  if (blk < P_PART * B_RET) {
    task = tr; mod = mr; s = s_ret; B = B_RET; E0 = E_RET; base = PW_RET;
  } else if (blk < P_PART * (B_RET + B_DRAM)) {
    blk -= P_PART * B_RET;
    task = td; mod = md; s = s_dram; B = B_DRAM; E0 = E_DRAM; base = PW_DRAM;
  } else {
    blk -= P_PART * (B_RET + B_DRAM);
    task = tl; mod = ml; s = s_link; B = B_LINK; E0 = E_LINK; base = PW_LINK;
  }
  int p = blk % P_PART;      // task partition
  int b = blk / P_PART;      // edge slice (same-slice blocks adjacent -> L2/L3 reuse)
  int tid = threadIdx.x;

  for (int idx = tid; idx < R_PART; idx += 256) {
    lmax[idx] = 0u;
    lmin[idx] = 0xFFFFFFFFu;
  }
  __syncthreads();

  int C = (E0 + B - 1) / B;
  int start = b * C;
  int end = start + C; if (end > E0) end = E0;
  int tbase = p * R_PART;
  for (int i = start + tid; i < end; i += 256) {
    int t = task[i];
    unsigned r = (unsigned)(t - tbase);
    if (r < R_PART) {
      int m = mod[i];
      unsigned u = ford(s[m]);
      atomicMax(&lmax[r], u);
      atomicMin(&lmin[r], u);
    }
  }
  __syncthreads();

  int gbase = base + (p * B + b) * R_PART;
  for (int idx = tid; idx < R_PART; idx += 256) {
    partials[gbase + idx] = lmax[idx];
    partials[PW_TOT + gbase + idx] = lmin[idx];
  }
}

// ---- K2b: fold B partials per (etype, task) into tmax / tmin ----
__global__ __launch_bounds__(256) void k_mmred(const unsigned* __restrict__ partials,
                                               unsigned* __restrict__ tmax,
                                               unsigned* __restrict__ tmin) {
  int gid = blockIdx.x * 256 + threadIdx.x;
  if (gid >= 3 * N_TASK) return;
  int e = gid / N_TASK;
  int t = gid - e * N_TASK;
  int B, base;
  if (e == 0) { B = B_RET; base = PW_RET; }
  else if (e == 1) { B = B_DRAM; base = PW_DRAM; }
  else { B = B_LINK; base = PW_LINK; }
  int p = t / R_PART;
  int r = t - p * R_PART;
  unsigned umax = 0u, umin = 0xFFFFFFFFu;
  for (int bb = 0; bb < B; bb++) {
    int idx = base + (p * B + bb) * R_PART + r;
    unsigned w = partials[idx];
    if (w > umax) umax = w;
    unsigned w2 = partials[PW_TOT + idx];
    if (w2 < umin) umin = w2;
  }
  tmax[gid] = umax;
  tmin[gid] = umin;
}

// ---- scan chain for CSR offsets over cnt[N_LINK] ----
__global__ void k_part(const int* __restrict__ cnt, int* part) {
  __shared__ int sm[256];
  int i = blockIdx.x * 256 + threadIdx.x;
  sm[threadIdx.x] = (i < N_LINK) ? cnt[i] : 0;
  __syncthreads();
  for (int s = 128; s > 0; s >>= 1) {
    if (threadIdx.x < s) sm[threadIdx.x] += sm[threadIdx.x + s];
    __syncthreads();
  }
  if (threadIdx.x == 0) part[blockIdx.x] = sm[0];
}

__global__ void k_scanpart(const int* __restrict__ part, int* partx, int npart) {
  __shared__ int sm[512];
  int t = threadIdx.x;
  int v = (t < npart) ? part[t] : 0;
  sm[t] = v;
  __syncthreads();
  for (int d = 1; d < 512; d <<= 1) {
    int x = (t >= d) ? sm[t - d] : 0;
    __syncthreads();
    sm[t] += x;
    __syncthreads();
  }
  if (t < npart) partx[t] = sm[t] - v;  // exclusive
}

__global__ void k_offs(const int* __restrict__ cnt, const int* __restrict__ partx,
                       int* offs, int* cursor) {
  __shared__ int sm[256];
  int i = blockIdx.x * 256 + threadIdx.x;
  int t = threadIdx.x;
  int v = (i < N_LINK) ? cnt[i] : 0;
  sm[t] = v;
  __syncthreads();
  for (int d = 1; d < 256; d <<= 1) {
    int x = (t >= d) ? sm[t - d] : 0;
    __syncthreads();
    sm[t] += x;
    __syncthreads();
  }
  if (i < N_LINK) {
    int o = partx[blockIdx.x] + sm[t] - v;  // exclusive start
    offs[i] = o;
    cursor[i] = o;
  }
}

__global__ void k_scatter(const int* __restrict__ tl, const int* __restrict__ ml,
                          int* cursor, int* csr) {
  int i = blockIdx.x * blockDim.x + threadIdx.x;
  if (i >= E_LINK) return;
  int pos = atomicAdd(&cursor[ml[i]], 1);
  csr[pos] = tl[i];
}

// ---- K3: h_task = tanh(h_cat @ W_task^T + b_task), h_cat built on the fly ----
__global__ __launch_bounds__(64) void k_task(
    const float* __restrict__ W_ret, const float* __restrict__ b_ret,
    const float* __restrict__ W_dram, const float* __restrict__ b_dram,
    const float* __restrict__ W_link, const float* __restrict__ b_link,
    const float* __restrict__ W_task, const float* __restrict__ b_task,
    const unsigned* __restrict__ tmax, const unsigned* __restrict__ tmin,
    unsigned short* __restrict__ h_task) {
  __shared__ __attribute__((aligned(16))) float hcS[64 * 64];  // [task_local][k]
  __shared__ __attribute__((aligned(16))) float wtS[64 * 64];  // [k][o]
  int tid = threadIdx.x;
  int tx = tid & 7, ty = tid >> 3;
  int o0 = tx * 8;
  int tile0 = blockIdx.x * 64;

  float acc[8][8];
#pragma unroll
  for (int i = 0; i < 8; i++)
#pragma unroll
    for (int j = 0; j < 8; j++) acc[i][j] = 0.f;

  const float* We[3] = {W_ret, W_dram, W_link};
  const float* be[3] = {b_ret, b_dram, b_link};

  for (int e = 0; e < 3; e++) {
    for (int idx = tid; idx < 4096; idx += 64) {
      int k = idx >> 6, o = idx & 63;
      wtS[idx] = W_task[o * 192 + e * 64 + k];
    }
    for (int idx = tid; idx < 4096; idx += 64) {
      int tl = idx >> 6, k = idx & 63;
      int t = tile0 + tl;
      float hc = 0.f;
      if (t < N_TASK) {
        unsigned um = tmax[e * N_TASK + t];
        if (um != 0u) {  // deg>0
          float smax = funord(um);
          float smin = funord(tmin[e * N_TASK + t]);
          float w = We[e][k];
          float ssel = (w >= 0.f) ? smax : smin;  // monotone tanh: pick extreme s
          hc = tanhf(fmaf(ssel, w, be[e][k]));
        }
      }
      hcS[idx] = hc;
    }
    __syncthreads();
#pragma unroll
    for (int k4 = 0; k4 < 16; k4++) {
      int k = k4 * 4;
      float4 hv[8];
#pragma unroll
      for (int i = 0; i < 8; i++) hv[i] = *(const float4*)&hcS[(ty * 8 + i) * 64 + k];
      float wv[4][8];
#pragma unroll
      for (int dk = 0; dk < 4; dk++) {
        float4 a = *(const float4*)&wtS[(k + dk) * 64 + o0];
        float4 b = *(const float4*)&wtS[(k + dk) * 64 + o0 + 4];
        wv[dk][0] = a.x; wv[dk][1] = a.y; wv[dk][2] = a.z; wv[dk][3] = a.w;
        wv[dk][4] = b.x; wv[dk][5] = b.y; wv[dk][6] = b.z; wv[dk][7] = b.w;
      }
#pragma unroll
      for (int i = 0; i < 8; i++) {
        float hvv[4] = {hv[i].x, hv[i].y, hv[i].z, hv[i].w};
#pragma unroll
        for (int dk = 0; dk < 4; dk++)
#pragma unroll
          for (int j = 0; j < 8; j++)
            acc[i][j] = fmaf(hvv[dk], wv[dk][j], acc[i][j]);
      }
    }
    __syncthreads();
  }

#pragma unroll
  for (int i = 0; i < 8; i++) {
    int t = tile0 + ty * 8 + i;
    if (t < N_TASK) {
#pragma unroll
      for (int g = 0; g < 2; g++) {
        ushort4 r;
        unsigned short rr[4];
#pragma unroll
        for (int j = 0; j < 4; j++) {
          float v = tanhf(acc[i][g * 4 + j] + b_task[o0 + g * 4 + j]);
          unsigned u = __float_as_uint(v);
          rr[j] = (unsigned short)((u + 0x7fffu + ((u >> 16) & 1u)) >> 16);
        }
        r.x = rr[0]; r.y = rr[1]; r.z = rr[2]; r.w = rr[3];
        *(ushort4*)&h_task[t * 64 + o0 + g * 4] = r;
      }
    }
  }
}

// ---- K4: per-link mean of h_task rows via CSR; wave per link, lane = feature ----
__global__ __launch_bounds__(256) void k_link(const unsigned short* __restrict__ h_task,
                                              const int* __restrict__ offs,
                                              const int* __restrict__ cnt,
                                              const int* __restrict__ csr,
                                              float* __restrict__ out) {
  int wid = threadIdx.x >> 6, lane = threadIdx.x & 63;
  int l = blockIdx.x * 4 + wid;  // grid exact: 25000*4 == N_LINK
  int start = offs[l];
  int c = cnt[l];
  float acc = 0.f;
  for (int q = 0; q < c; q++) {
    int task = csr[start + q];
    unsigned hs = h_task[task * 64 + lane];
    acc += __uint_as_float(hs << 16);
  }
  out[l * 64 + lane] = (c > 0) ? acc / (float)c : 0.f;
}

extern "C" void kernel_launch(void* const* d_in, const int* in_sizes, int n_in,
                              void* d_out, int out_size, void* d_ws, size_t ws_size,
                              hipStream_t stream) {
  const float* feat_ret  = (const float*)d_in[0];
  const float* feat_dram = (const float*)d_in[1];
  const float* feat_link = (const float*)d_in[2];
  const float* W_ret  = (const float*)d_in[3];
  const float* b_ret  = (const float*)d_in[4];
  const float* W_dram = (const float*)d_in[5];
  const float* b_dram = (const float*)d_in[6];
  const float* W_link = (const float*)d_in[7];
  const float* b_link = (const float*)d_in[8];
  const float* W_task = (const float*)d_in[9];
  const float* b_task = (const float*)d_in[10];
  const int* task_ret  = (const int*)d_in[11];
  const int* mod_ret   = (const int*)d_in[12];
  const int* task_dram = (const int*)d_in[13];
  const int* mod_dram  = (const int*)d_in[14];
  const int* task_link = (const int*)d_in[15];
  const int* mod_link  = (const int*)d_in[16];
  float* out = (float*)d_out;

  // ---- workspace layout (bytes) ----
  char* ws = (char*)d_ws;
  float*    s_ret  = (float*)(ws + 0);            // 20000 f
  float*    s_dram = (float*)(ws + 80000);        // 5000 f
  float*    s_link = (float*)(ws + 100000);       // 100000 f
  int*      cnt    = (int*)(ws + 500000);         // 100000 i
  // zero region: [0, 900000)
  unsigned* tmax   = (unsigned*)(ws + 900000);    // 150000 u (written by k_mmred)
  unsigned* tmin   = (unsigned*)(ws + 1500000);   // 150000 u (written by k_mmred)
  int*      offs   = (int*)(ws + 2100000);        // 100000 i
  int*      cursor = (int*)(ws + 2500000);        // 100000 i
  int*      part   = (int*)(ws + 2900000);        // <=512 i
  int*      partx  = (int*)(ws + 2904096);        // <=512 i
  // partials (8 MB, 2M words) ALIASES csr: used only between k_hist and k_mmred;
  // csr is written later by k_scatter.
  unsigned* partials = (unsigned*)(ws + 2908192); // 2*PW_TOT = 2000000 u
  int*      csr    = (int*)(ws + 2908192);        // 2000000 i
  unsigned short* h_task = (unsigned short*)(ws + 10908192);  // 3200000 us

  hipMemsetAsync(ws, 0, 900000, stream);

  const int totalE = E_RET + E_DRAM + E_LINK;
  int nblk_e = (totalE + 255) / 256;
  k_segsum<<<nblk_e, 256, 0, stream>>>(feat_ret, feat_dram, feat_link,
                                       mod_ret, mod_dram, mod_link,
                                       s_ret, s_dram, s_link, cnt);
  const int nhist = P_PART * (B_RET + B_DRAM + B_LINK);  // 320 blocks
  k_hist<<<nhist, 256, 0, stream>>>(task_ret, mod_ret, task_dram, mod_dram,
                                    task_link, mod_link,
                                    s_ret, s_dram, s_link, partials);
  k_mmred<<<(3 * N_TASK + 255) / 256, 256, 0, stream>>>(partials, tmax, tmin);
  const int npart = (N_LINK + 255) / 256;  // 391
  k_part<<<npart, 256, 0, stream>>>(cnt, part);
  k_scanpart<<<1, 512, 0, stream>>>(part, partx, npart);
  k_offs<<<npart, 256, 0, stream>>>(cnt, partx, offs, cursor);
  k_scatter<<<(E_LINK + 255) / 256, 256, 0, stream>>>(task_link, mod_link, cursor, csr);
  k_task<<<(N_TASK + 63) / 64, 64, 0, stream>>>(W_ret, b_ret, W_dram, b_dram,
                                                W_link, b_link, W_task, b_task,
                                                tmax, tmin, h_task);
  k_link<<<N_LINK / 4, 256, 0, stream>>>(h_task, offs, cnt, csr, out);
}

// Round 3
// 794.056 us; speedup vs baseline: 1.5672x; 1.5672x over previous
//
#include <hip/hip_runtime.h>
#include <stdint.h>

#define N_TASK 50000
#define N_RET 20000
#define N_DRAM 5000
#define N_LINK 100000
#define E_RET 1000000
#define E_DRAM 250000
#define E_LINK 2000000

// ---- task-range bucketing ----
#define R_PART 3125                 // tasks per bucket; 16*3125 == N_TASK
#define NB_RET 3907                 // edge blocks (256 threads each)
#define NB_DRAM 977
#define NB_LINK 7813
#define CAP_RET 72000               // per-bucket record capacity (exact counts << cap)
#define CAP_DRAM 20000
#define CAP_LINK 137500
#define SUB_RET 8                   // passB sub-blocks per bucket
#define SUB_DRAM 2
#define SUB_LINK 16
#define PB_RET 0                    // partial-plane word offsets
#define PB_DRAM (16 * SUB_RET * R_PART)                 // 400000
#define PB_LINK (PB_DRAM + 16 * SUB_DRAM * R_PART)      // 500000
#define PB_TOT (PB_LINK + 16 * SUB_LINK * R_PART)       // 1300000 words per plane

// ---- workspace byte offsets ----
#define WS_SRET_REP 0              // 4*20000 f
#define WS_SDRAM_REP 320000        // 4*5000 f
#define WS_SLINK_REP 400000        // 2*100000 f
#define WS_CNT_REP 1200000         // 2*100000 i
#define WS_ZERO_END 2000000
#define WS_SRET 2000000
#define WS_SDRAM 2080000
#define WS_SLINK 2100000
#define WS_CNT 2500000
#define WS_TMAX 2900000
#define WS_TMIN 3500000
#define WS_OFFS 4100000
#define WS_CUR2 4500000
#define WS_PART 4900000
#define WS_PARTX 4901600
#define WS_BCNT 4903200            // 48 i
#define WS_BKT_RET 4903424         // 16*72000*8  -> 14119424
#define WS_BKT_DRAM 14119424       // 16*20000*8  -> 16679424
#define WS_BKT_LINK 16679424       // 16*137500*8 -> 34279424
#define WS_PARTIALS 34279424       // 2*1300000*4 -> 44679424 (blkcnt aliases here)
#define WS_BLKCNT 34279424         // 203152 i (dead before partials written)
#define WS_CSR 4903424             // 2M i, aliases ret buckets (written after passB)
#define WS_HTASK 14119424          // 3.2M u16, aliases dram/link buckets
#define WS_NEED 44679424
#define WS_NEED_FALLBACK 20519424

// ---- order-preserving float<->uint (min/max as uint); 0 / 0xFFFFFFFF unreachable ----
__device__ __forceinline__ unsigned ford(float f) {
  unsigned u = __float_as_uint(f);
  return (u & 0x80000000u) ? ~u : (u | 0x80000000u);
}
__device__ __forceinline__ float funord(unsigned t) {
  unsigned u = (t & 0x80000000u) ? (t & 0x7fffffffu) : ~t;
  return __uint_as_float(u);
}

// ---- K1: replicated scalar segment sums per module + link degree counts ----
__global__ void k_segsum(const float* __restrict__ fr, const float* __restrict__ fd,
                         const float* __restrict__ fl,
                         const int* __restrict__ mr, const int* __restrict__ md,
                         const int* __restrict__ ml,
                         float* s_ret_rep, float* s_dram_rep, float* s_link_rep,
                         int* cnt_rep) {
  int i = blockIdx.x * blockDim.x + threadIdx.x;
  const int total = E_RET + E_DRAM + E_LINK;
  if (i >= total) return;
  int r4 = blockIdx.x & 3, r2 = blockIdx.x & 1;
  if (i < E_RET) {
    atomicAdd(&s_ret_rep[r4 * N_RET + mr[i]], fr[i]);
  } else if (i < E_RET + E_DRAM) {
    int j = i - E_RET;
    atomicAdd(&s_dram_rep[r4 * N_DRAM + md[j]], fd[j]);
  } else {
    int j = i - (E_RET + E_DRAM);
    int m = ml[j];
    atomicAdd(&s_link_rep[r2 * N_LINK + m], fl[j]);
    atomicAdd(&cnt_rep[r2 * N_LINK + m], 1);
  }
}

// ---- fold replicas into canonical arrays ----
__global__ void k_fold(const float* __restrict__ s_ret_rep, const float* __restrict__ s_dram_rep,
                       const float* __restrict__ s_link_rep, const int* __restrict__ cnt_rep,
                       float* s_ret, float* s_dram, float* s_link, int* cnt) {
  int i = blockIdx.x * 256 + threadIdx.x;
  if (i < N_RET)
    s_ret[i] = s_ret_rep[i] + s_ret_rep[N_RET + i] + s_ret_rep[2 * N_RET + i] + s_ret_rep[3 * N_RET + i];
  if (i < N_DRAM)
    s_dram[i] = s_dram_rep[i] + s_dram_rep[N_DRAM + i] + s_dram_rep[2 * N_DRAM + i] + s_dram_rep[3 * N_DRAM + i];
  if (i < N_LINK) {
    s_link[i] = s_link_rep[i] + s_link_rep[N_LINK + i];
    cnt[i] = cnt_rep[i] + cnt_rep[N_LINK + i];
  }
}

// ---- block/etype decode shared by A0 and A-scatter ----
__device__ __forceinline__ void decode_eblk(int blk, int& e, int& blk_local, int& E0,
                                            int& NB) {
  if (blk < NB_RET) { e = 0; blk_local = blk; E0 = E_RET; NB = NB_RET; }
  else if (blk < NB_RET + NB_DRAM) { e = 1; blk_local = blk - NB_RET; E0 = E_DRAM; NB = NB_DRAM; }
  else { e = 2; blk_local = blk - NB_RET - NB_DRAM; E0 = E_LINK; NB = NB_LINK; }
}

// ---- A0: per-(block,bucket) counts -> blkcnt[etype-region][b*NB + blk_local] ----
__global__ __launch_bounds__(256) void k_a0(const int* __restrict__ tr,
                                            const int* __restrict__ td,
                                            const int* __restrict__ tl,
                                            int* __restrict__ blkcnt) {
  __shared__ int c[16];
  if (threadIdx.x < 16) c[threadIdx.x] = 0;
  __syncthreads();
  int e, blk_local, E0, NB;
  decode_eblk(blockIdx.x, e, blk_local, E0, NB);
  const int* task = (e == 0) ? tr : (e == 1) ? td : tl;
  int i = blk_local * 256 + threadIdx.x;
  if (i < E0) {
    int b = task[i] / R_PART;
    atomicAdd(&c[b], 1);
  }
  __syncthreads();
  int base = (e == 0) ? 0 : (e == 1) ? 16 * NB_RET : 16 * (NB_RET + NB_DRAM);
  if (threadIdx.x < 16) blkcnt[base + threadIdx.x * NB + blk_local] = c[threadIdx.x];
}

// ---- A-scan: exclusive scan per (etype,bucket) over blocks; totals -> bcnt ----
__global__ __launch_bounds__(1024) void k_ascan(int* __restrict__ blkcnt, int* __restrict__ bcnt) {
  __shared__ int sm[1024];
  int gb = blockIdx.x;  // 0..47
  int e = gb >> 4, b = gb & 15;
  int NB = (e == 0) ? NB_RET : (e == 1) ? NB_DRAM : NB_LINK;
  int base = (e == 0) ? 0 : (e == 1) ? 16 * NB_RET : 16 * (NB_RET + NB_DRAM);
  int* arr = blkcnt + base + b * NB;
  int carry = 0;
  for (int t0 = 0; t0 < NB; t0 += 1024) {
    int i = t0 + threadIdx.x;
    int v = (i < NB) ? arr[i] : 0;
    sm[threadIdx.x] = v;
    __syncthreads();
    for (int d = 1; d < 1024; d <<= 1) {
      int x = (threadIdx.x >= d) ? sm[threadIdx.x - d] : 0;
      __syncthreads();
      sm[threadIdx.x] += x;
      __syncthreads();
    }
    if (i < NB) arr[i] = carry + sm[threadIdx.x] - v;  // exclusive prefix
    int tot = sm[1023];
    __syncthreads();
    carry += tot;
  }
  if (threadIdx.x == 0) bcnt[gb] = carry;
}

// ---- A-scatter: write (value|taskLocal) records to exact bucket slots ----
__global__ __launch_bounds__(256) void k_ascatter(
    const int* __restrict__ tr, const int* __restrict__ mr,
    const int* __restrict__ td, const int* __restrict__ md,
    const int* __restrict__ tl, const int* __restrict__ ml,
    const float* __restrict__ s_ret, const float* __restrict__ s_dram,
    const float* __restrict__ s_link, const int* __restrict__ blkcnt,
    unsigned long long* __restrict__ bkt_ret, unsigned long long* __restrict__ bkt_dram,
    unsigned long long* __restrict__ bkt_link) {
  __shared__ int lbase[16];
  __shared__ int lc[16];
  int e, blk_local, E0, NB;
  decode_eblk(blockIdx.x, e, blk_local, E0, NB);
  int base = (e == 0) ? 0 : (e == 1) ? 16 * NB_RET : 16 * (NB_RET + NB_DRAM);
  if (threadIdx.x < 16) {
    lbase[threadIdx.x] = blkcnt[base + threadIdx.x * NB + blk_local];
    lc[threadIdx.x] = 0;
  }
  __syncthreads();
  const int* task = (e == 0) ? tr : (e == 1) ? td : tl;
  const int* mod = (e == 0) ? mr : (e == 1) ? md : ml;
  const float* s = (e == 0) ? s_ret : (e == 1) ? s_dram : s_link;
  unsigned long long* bkt = (e == 0) ? bkt_ret : (e == 1) ? bkt_dram : bkt_link;
  int CAP = (e == 0) ? CAP_RET : (e == 1) ? CAP_DRAM : CAP_LINK;
  int i = blk_local * 256 + threadIdx.x;
  if (i < E0) {
    int t = task[i];
    int b = t / R_PART;
    unsigned r = (unsigned)(t - b * R_PART);
    unsigned u = ford(s[mod[i]]);
    int slot = lbase[b] + atomicAdd(&lc[b], 1);
    if (slot < CAP)
      bkt[(long)b * CAP + slot] = ((unsigned long long)u << 32) | r;
  }
}

// ---- passB: per-bucket LDS min/max over records, flush partial planes ----
__global__ __launch_bounds__(256) void k_passb(
    const unsigned long long* __restrict__ bkt_ret,
    const unsigned long long* __restrict__ bkt_dram,
    const unsigned long long* __restrict__ bkt_link,
    const int* __restrict__ bcnt, unsigned* __restrict__ partials) {
  __shared__ unsigned lmax[R_PART];
  __shared__ unsigned lmin[R_PART];
  int blk = blockIdx.x;
  int e, b, sub, Nb, PB, CAP;
  const unsigned long long* bkt;
  if (blk < 16 * SUB_RET) {
    e = 0; b = blk >> 3; sub = blk & 7; Nb = SUB_RET; PB = PB_RET; CAP = CAP_RET; bkt = bkt_ret;
  } else if (blk < 16 * (SUB_RET + SUB_DRAM)) {
    int q = blk - 16 * SUB_RET;
    e = 1; b = q >> 1; sub = q & 1; Nb = SUB_DRAM; PB = PB_DRAM; CAP = CAP_DRAM; bkt = bkt_dram;
  } else {
    int q = blk - 16 * (SUB_RET + SUB_DRAM);
    e = 2; b = q >> 4; sub = q & 15; Nb = SUB_LINK; PB = PB_LINK; CAP = CAP_LINK; bkt = bkt_link;
  }
  for (int idx = threadIdx.x; idx < R_PART; idx += 256) {
    lmax[idx] = 0u;
    lmin[idx] = 0xFFFFFFFFu;
  }
  __syncthreads();
  int count = bcnt[e * 16 + b];
  if (count > CAP) count = CAP;
  int chunk = (count + Nb - 1) / Nb;
  int s0 = sub * chunk;
  int s1 = s0 + chunk; if (s1 > count) s1 = count;
  const unsigned long long* p = bkt + (long)b * CAP;
  for (int i = s0 + threadIdx.x; i < s1; i += 256) {
    unsigned long long rec = p[i];
    unsigned r = (unsigned)rec;
    unsigned u = (unsigned)(rec >> 32);
    atomicMax(&lmax[r], u);
    atomicMin(&lmin[r], u);
  }
  __syncthreads();
  unsigned gbase = PB + (unsigned)(b * Nb + sub) * R_PART;
  for (int idx = threadIdx.x; idx < R_PART; idx += 256) {
    partials[gbase + idx] = lmax[idx];
    partials[PB_TOT + gbase + idx] = lmin[idx];
  }
}

// ---- reduce partials -> tmax/tmin ----
__global__ __launch_bounds__(256) void k_mmred2(const unsigned* __restrict__ partials,
                                                unsigned* __restrict__ tmax,
                                                unsigned* __restrict__ tmin) {
  int gid = blockIdx.x * 256 + threadIdx.x;
  if (gid >= 3 * N_TASK) return;
  int e = gid / N_TASK;
  int t = gid - e * N_TASK;
  int Nb = (e == 0) ? SUB_RET : (e == 1) ? SUB_DRAM : SUB_LINK;
  int PB = (e == 0) ? PB_RET : (e == 1) ? PB_DRAM : PB_LINK;
  int b = t / R_PART;
  int r = t - b * R_PART;
  unsigned umax = 0u, umin = 0xFFFFFFFFu;
  for (int sub = 0; sub < Nb; sub++) {
    unsigned idx = PB + (unsigned)(b * Nb + sub) * R_PART + r;
    unsigned w = partials[idx];
    if (w > umax) umax = w;
    unsigned w2 = partials[PB_TOT + idx];
    if (w2 < umin) umin = w2;
  }
  tmax[gid] = umax;
  tmin[gid] = umin;
}

// ---- fallback: round-1 global-atomic min/max (used only if ws too small) ----
__global__ void k_minmax_atomic(const float* __restrict__ s_ret, const float* __restrict__ s_dram,
                                const float* __restrict__ s_link,
                                const int* __restrict__ tr, const int* __restrict__ mr,
                                const int* __restrict__ td, const int* __restrict__ md,
                                const int* __restrict__ tl, const int* __restrict__ ml,
                                unsigned* tmax, unsigned* tmin) {
  int i = blockIdx.x * blockDim.x + threadIdx.x;
  const int total = E_RET + E_DRAM + E_LINK;
  if (i >= total) return;
  int e, task; unsigned u;
  if (i < E_RET) {
    u = ford(s_ret[mr[i]]); task = tr[i]; e = 0;
  } else if (i < E_RET + E_DRAM) {
    int j = i - E_RET;
    u = ford(s_dram[md[j]]); task = td[j]; e = 1;
  } else {
    int j = i - (E_RET + E_DRAM);
    u = ford(s_link[ml[j]]); task = tl[j]; e = 2;
  }
  atomicMax(&tmax[e * N_TASK + task], u);
  atomicMin(&tmin[e * N_TASK + task], u);
}

// ---- scan chain for CSR offsets over cnt[N_LINK] ----
__global__ void k_part(const int* __restrict__ cnt, int* part) {
  __shared__ int sm[256];
  int i = blockIdx.x * 256 + threadIdx.x;
  sm[threadIdx.x] = (i < N_LINK) ? cnt[i] : 0;
  __syncthreads();
  for (int s = 128; s > 0; s >>= 1) {
    if (threadIdx.x < s) sm[threadIdx.x] += sm[threadIdx.x + s];
    __syncthreads();
  }
  if (threadIdx.x == 0) part[blockIdx.x] = sm[0];
}

__global__ void k_scanpart(const int* __restrict__ part, int* partx, int npart) {
  __shared__ int sm[512];
  int t = threadIdx.x;
  int v = (t < npart) ? part[t] : 0;
  sm[t] = v;
  __syncthreads();
  for (int d = 1; d < 512; d <<= 1) {
    int x = (t >= d) ? sm[t - d] : 0;
    __syncthreads();
    sm[t] += x;
    __syncthreads();
  }
  if (t < npart) partx[t] = sm[t] - v;  // exclusive
}

__global__ void k_offs(const int* __restrict__ cnt, const int* __restrict__ partx,
                       int* offs, int* cursor) {
  __shared__ int sm[256];
  int i = blockIdx.x * 256 + threadIdx.x;
  int t = threadIdx.x;
  int v = (i < N_LINK) ? cnt[i] : 0;
  sm[t] = v;
  __syncthreads();
  for (int d = 1; d < 256; d <<= 1) {
    int x = (t >= d) ? sm[t - d] : 0;
    __syncthreads();
    sm[t] += x;
    __syncthreads();
  }
  if (i < N_LINK) {
    int o = partx[blockIdx.x] + sm[t] - v;
    offs[i] = o;
    cursor[i] = o;
  }
}

__global__ void k_scatter(const int* __restrict__ tl, const int* __restrict__ ml,
                          int* cursor, int* csr) {
  int i = blockIdx.x * blockDim.x + threadIdx.x;
  if (i >= E_LINK) return;
  int pos = atomicAdd(&cursor[ml[i]], 1);
  csr[pos] = tl[i];
}

// ---- K3: h_task = tanh(h_cat @ W_task^T + b_task), h_cat built on the fly ----
__global__ __launch_bounds__(64) void k_task(
    const float* __restrict__ W_ret, const float* __restrict__ b_ret,
    const float* __restrict__ W_dram, const float* __restrict__ b_dram,
    const float* __restrict__ W_link, const float* __restrict__ b_link,
    const float* __restrict__ W_task, const float* __restrict__ b_task,
    const unsigned* __restrict__ tmax, const unsigned* __restrict__ tmin,
    unsigned short* __restrict__ h_task) {
  __shared__ __attribute__((aligned(16))) float hcS[64 * 64];  // [task_local][k]
  __shared__ __attribute__((aligned(16))) float wtS[64 * 64];  // [k][o]
  int tid = threadIdx.x;
  int tx = tid & 7, ty = tid >> 3;
  int o0 = tx * 8;
  int tile0 = blockIdx.x * 64;

  float acc[8][8];
#pragma unroll
  for (int i = 0; i < 8; i++)
#pragma unroll
    for (int j = 0; j < 8; j++) acc[i][j] = 0.f;

  const float* We[3] = {W_ret, W_dram, W_link};
  const float* be[3] = {b_ret, b_dram, b_link};

  for (int e = 0; e < 3; e++) {
    for (int idx = tid; idx < 4096; idx += 64) {
      int k = idx >> 6, o = idx & 63;
      wtS[idx] = W_task[o * 192 + e * 64 + k];
    }
    for (int idx = tid; idx < 4096; idx += 64) {
      int tl = idx >> 6, k = idx & 63;
      int t = tile0 + tl;
      float hc = 0.f;
      if (t < N_TASK) {
        unsigned um = tmax[e * N_TASK + t];
        if (um != 0u) {  // deg>0
          float smax = funord(um);
          float smin = funord(tmin[e * N_TASK + t]);
          float w = We[e][k];
          float ssel = (w >= 0.f) ? smax : smin;  // monotone tanh: pick extreme s
          hc = tanhf(fmaf(ssel, w, be[e][k]));
        }
      }
      hcS[idx] = hc;
    }
    __syncthreads();
#pragma unroll
    for (int k4 = 0; k4 < 16; k4++) {
      int k = k4 * 4;
      float4 hv[8];
#pragma unroll
      for (int i = 0; i < 8; i++) hv[i] = *(const float4*)&hcS[(ty * 8 + i) * 64 + k];
      float wv[4][8];
#pragma unroll
      for (int dk = 0; dk < 4; dk++) {
        float4 a = *(const float4*)&wtS[(k + dk) * 64 + o0];
        float4 b = *(const float4*)&wtS[(k + dk) * 64 + o0 + 4];
        wv[dk][0] = a.x; wv[dk][1] = a.y; wv[dk][2] = a.z; wv[dk][3] = a.w;
        wv[dk][4] = b.x; wv[dk][5] = b.y; wv[dk][6] = b.z; wv[dk][7] = b.w;
      }
#pragma unroll
      for (int i = 0; i < 8; i++) {
        float hvv[4] = {hv[i].x, hv[i].y, hv[i].z, hv[i].w};
#pragma unroll
        for (int dk = 0; dk < 4; dk++)
#pragma unroll
          for (int j = 0; j < 8; j++)
            acc[i][j] = fmaf(hvv[dk], wv[dk][j], acc[i][j]);
      }
    }
    __syncthreads();
  }

#pragma unroll
  for (int i = 0; i < 8; i++) {
    int t = tile0 + ty * 8 + i;
    if (t < N_TASK) {
#pragma unroll
      for (int g = 0; g < 2; g++) {
        ushort4 r;
        unsigned short rr[4];
#pragma unroll
        for (int j = 0; j < 4; j++) {
          float v = tanhf(acc[i][g * 4 + j] + b_task[o0 + g * 4 + j]);
          unsigned u = __float_as_uint(v);
          rr[j] = (unsigned short)((u + 0x7fffu + ((u >> 16) & 1u)) >> 16);
        }
        r.x = rr[0]; r.y = rr[1]; r.z = rr[2]; r.w = rr[3];
        *(ushort4*)&h_task[t * 64 + o0 + g * 4] = r;
      }
    }
  }
}

// ---- K4: per-link mean of h_task rows via CSR; wave per link, lane = feature ----
__global__ __launch_bounds__(256) void k_link(const unsigned short* __restrict__ h_task,
                                              const int* __restrict__ offs,
                                              const int* __restrict__ cnt,
                                              const int* __restrict__ csr,
                                              float* __restrict__ out) {
  int wid = threadIdx.x >> 6, lane = threadIdx.x & 63;
  int l = blockIdx.x * 4 + wid;  // grid exact: 25000*4 == N_LINK
  int start = offs[l];
  int c = cnt[l];
  float acc = 0.f;
  int tnext = (c > 0) ? csr[start] : 0;
  for (int q = 0; q < c; q++) {
    int task = tnext;
    if (q + 1 < c) tnext = csr[start + q + 1];  // prefetch: breaks serial dep chain
    unsigned hs = h_task[task * 64 + lane];
    acc += __uint_as_float(hs << 16);
  }
  out[l * 64 + lane] = (c > 0) ? acc / (float)c : 0.f;
}

extern "C" void kernel_launch(void* const* d_in, const int* in_sizes, int n_in,
                              void* d_out, int out_size, void* d_ws, size_t ws_size,
                              hipStream_t stream) {
  const float* feat_ret  = (const float*)d_in[0];
  const float* feat_dram = (const float*)d_in[1];
  const float* feat_link = (const float*)d_in[2];
  const float* W_ret  = (const float*)d_in[3];
  const float* b_ret  = (const float*)d_in[4];
  const float* W_dram = (const float*)d_in[5];
  const float* b_dram = (const float*)d_in[6];
  const float* W_link = (const float*)d_in[7];
  const float* b_link = (const float*)d_in[8];
  const float* W_task = (const float*)d_in[9];
  const float* b_task = (const float*)d_in[10];
  const int* task_ret  = (const int*)d_in[11];
  const int* mod_ret   = (const int*)d_in[12];
  const int* task_dram = (const int*)d_in[13];
  const int* mod_dram  = (const int*)d_in[14];
  const int* task_link = (const int*)d_in[15];
  const int* mod_link  = (const int*)d_in[16];
  float* out = (float*)d_out;

  char* ws = (char*)d_ws;
  float* s_ret_rep  = (float*)(ws + WS_SRET_REP);
  float* s_dram_rep = (float*)(ws + WS_SDRAM_REP);
  float* s_link_rep = (float*)(ws + WS_SLINK_REP);
  int*   cnt_rep    = (int*)(ws + WS_CNT_REP);
  float* s_ret  = (float*)(ws + WS_SRET);
  float* s_dram = (float*)(ws + WS_SDRAM);
  float* s_link = (float*)(ws + WS_SLINK);
  int*   cnt    = (int*)(ws + WS_CNT);
  unsigned* tmax = (unsigned*)(ws + WS_TMAX);
  unsigned* tmin = (unsigned*)(ws + WS_TMIN);
  int* offs    = (int*)(ws + WS_OFFS);
  int* cursor2 = (int*)(ws + WS_CUR2);
  int* part    = (int*)(ws + WS_PART);
  int* partx   = (int*)(ws + WS_PARTX);
  int* bcnt    = (int*)(ws + WS_BCNT);
  unsigned long long* bkt_ret  = (unsigned long long*)(ws + WS_BKT_RET);
  unsigned long long* bkt_dram = (unsigned long long*)(ws + WS_BKT_DRAM);
  unsigned long long* bkt_link = (unsigned long long*)(ws + WS_BKT_LINK);
  unsigned* partials = (unsigned*)(ws + WS_PARTIALS);
  int* blkcnt = (int*)(ws + WS_BLKCNT);
  int* csr = (int*)(ws + WS_CSR);
  unsigned short* h_task = (unsigned short*)(ws + WS_HTASK);

  hipMemsetAsync(ws, 0, WS_ZERO_END, stream);

  const int totalE = E_RET + E_DRAM + E_LINK;
  int nblk_e = (totalE + 255) / 256;
  k_segsum<<<nblk_e, 256, 0, stream>>>(feat_ret, feat_dram, feat_link,
                                       mod_ret, mod_dram, mod_link,
                                       s_ret_rep, s_dram_rep, s_link_rep, cnt_rep);
  k_fold<<<(N_LINK + 255) / 256, 256, 0, stream>>>(s_ret_rep, s_dram_rep, s_link_rep,
                                                   cnt_rep, s_ret, s_dram, s_link, cnt);

  if (ws_size >= (size_t)WS_NEED) {
    const int nblkA = NB_RET + NB_DRAM + NB_LINK;  // 12697
    k_a0<<<nblkA, 256, 0, stream>>>(task_ret, task_dram, task_link, blkcnt);
    k_ascan<<<48, 1024, 0, stream>>>(blkcnt, bcnt);
    k_ascatter<<<nblkA, 256, 0, stream>>>(task_ret, mod_ret, task_dram, mod_dram,
                                          task_link, mod_link, s_ret, s_dram, s_link,
                                          blkcnt, bkt_ret, bkt_dram, bkt_link);
    k_passb<<<16 * (SUB_RET + SUB_DRAM + SUB_LINK), 256, 0, stream>>>(
        bkt_ret, bkt_dram, bkt_link, bcnt, partials);
    k_mmred2<<<(3 * N_TASK + 255) / 256, 256, 0, stream>>>(partials, tmax, tmin);
  } else {
    // fallback: global-atomic min/max
    hipMemsetAsync(tmax, 0, 3 * N_TASK * 4, stream);
    hipMemsetAsync(tmin, 0xFF, 3 * N_TASK * 4, stream);
    k_minmax_atomic<<<nblk_e, 256, 0, stream>>>(s_ret, s_dram, s_link,
                                                task_ret, mod_ret, task_dram, mod_dram,
                                                task_link, mod_link, tmax, tmin);
  }

  const int npart = (N_LINK + 255) / 256;  // 391
  k_part<<<npart, 256, 0, stream>>>(cnt, part);
  k_scanpart<<<1, 512, 0, stream>>>(part, partx, npart);
  k_offs<<<npart, 256, 0, stream>>>(cnt, partx, offs, cursor2);
  k_scatter<<<(E_LINK + 255) / 256, 256, 0, stream>>>(task_link, mod_link, cursor2, csr);
  k_task<<<(N_TASK + 63) / 64, 64, 0, stream>>>(W_ret, b_ret, W_dram, b_dram,
                                                W_link, b_link, W_task, b_task,
                                                tmax, tmin, h_task);
  k_link<<<N_LINK / 4, 256, 0, stream>>>(h_task, offs, cnt, csr, out);
}

// Round 4
// 492.171 us; speedup vs baseline: 2.5285x; 1.6134x over previous
//
#include <hip/hip_runtime.h>
#include <stdint.h>

#define N_TASK 50000
#define N_RET 20000
#define N_DRAM 5000
#define N_LINK 100000
#define E_RET 1000000
#define E_DRAM 250000
#define E_LINK 2000000

// ---- module-range bucketing (segment sums + CSR, zero global atomics) ----
#define MBE 1024                // edges per m-block
#define NBM_RET 977
#define NBM_DRAM 245
#define NBM_LINK 1954
#define NBM_TOT (NBM_RET + NBM_DRAM + NBM_LINK)   // 3176
#define MR_RET 64
#define RSZ_RET 313             // 64*313 = 20032 >= 20000
#define MR_DRAM 16
#define RSZ_DRAM 313            // 16*313 = 5008 >= 5000
#define MR_LINK 256
#define RSZ_LINK 391            // 256*391 = 100096 >= 100000
#define RECIP313 107203u        // ceil(2^25/313); exact div for m < 313k
#define RECIP391 85817u         // ceil(2^25/391); exact div for m < 2.2M
#define CAPM_RET 16250          // mean 15625, +5σ
#define CAPM_DRAM 16250
#define CAPM_LINK 8255          // mean 7813, +5σ
#define BM_RET 0                // blkcnt_m element offsets
#define BM_DRAM (MR_RET * NBM_RET)                  // 62528
#define BM_LINK (BM_DRAM + MR_DRAM * NBM_DRAM)      // 66448
#define BM_TOT (BM_LINK + MR_LINK * NBM_LINK)       // 566672

// ---- task-range bucketing (per-task min/max) ----
#define R_PART 3125             // 16*3125 == N_TASK
#define NB_RET 3907             // 256-edge blocks
#define NB_DRAM 977
#define NB_LINK 7813
#define CAP_RET 63800           // mean 62500, +5σ
#define CAP_DRAM 16300
#define CAP_LINK 126800
#define SUB_RET 4
#define SUB_DRAM 1
#define SUB_LINK 8
#define PB_RET 0
#define PB_DRAM (16 * SUB_RET * R_PART)             // 200000
#define PB_LINK (PB_DRAM + 16 * SUB_DRAM * R_PART)  // 250000
#define PB_TOT (PB_LINK + 16 * SUB_LINK * R_PART)   // 650000 words per plane

// ---- workspace byte offsets ----
#define WS_SRET 0               // 20000 f
#define WS_SDRAM 80000          // 5000 f
#define WS_SLINK 100000         // 100000 f
#define WS_CNT 500000           // 100000 i
#define WS_OFFS 900000          // 100000 i
#define WS_TMAX 1300000         // 150000 u
#define WS_TMIN 1900000         // 150000 u
#define WS_BCNT 2500000         // 48 i
#define WS_RCNT 2500192         // 336 i
#define WS_CSR 2501536          // 2M i -> ends 10501536
// profiling-counts region [10501536, 15701536): blkcnt_m, blkcnt_t, then partials
#define WS_BLKM 10501536        // 566672 i (dead after k_mscatter)
#define WS_BLKT 12768224        // 203152 i (dead after k_ascatter)
#define WS_PARTIALS 10501536    // 2*650000 u (written by k_passb, after both dead)
// records union [15701536, 43007776):
#define WS_MREC_RET 15701536    // 64*16250*8  -> 24021536
#define WS_MREC_DRAM 24021536   // 16*16250*8  -> 26101536
#define WS_MREC_LINK 26101536   // 256*8255*8  -> 43007776
#define WS_TREC_RET 15701536    // 16*63800*8  -> 23867936 (after mrec dead)
#define WS_TREC_DRAM 23867936   // 16*16300*8  -> 25954336
#define WS_TREC_LINK 25954336   // 16*126800*8 -> 42184736
#define WS_HTASK 15701536       // 3.2M u16 (after trec dead)
#define WS_NEED 43007776

// ---- order-preserving float<->uint (min/max as uint); 0 / 0xFFFFFFFF unreachable ----
__device__ __forceinline__ unsigned ford(float f) {
  unsigned u = __float_as_uint(f);
  return (u & 0x80000000u) ? ~u : (u | 0x80000000u);
}
__device__ __forceinline__ float funord(unsigned t) {
  unsigned u = (t & 0x80000000u) ? (t & 0x7fffffffu) : ~t;
  return __uint_as_float(u);
}

// =================== module-bucket pipeline ===================

__device__ __forceinline__ void decode_mblk(int bx, int& e, int& blk, int& E0, int& NB,
                                            int& NR, unsigned& RECIP, int& RSZ, int& base) {
  if (bx < NBM_RET) {
    e = 0; blk = bx; E0 = E_RET; NB = NBM_RET; NR = MR_RET; RECIP = RECIP313; RSZ = RSZ_RET; base = BM_RET;
  } else if (bx < NBM_RET + NBM_DRAM) {
    e = 1; blk = bx - NBM_RET; E0 = E_DRAM; NB = NBM_DRAM; NR = MR_DRAM; RECIP = RECIP313; RSZ = RSZ_DRAM; base = BM_DRAM;
  } else {
    e = 2; blk = bx - NBM_RET - NBM_DRAM; E0 = E_LINK; NB = NBM_LINK; NR = MR_LINK; RECIP = RECIP391; RSZ = RSZ_LINK; base = BM_LINK;
  }
}

// count per (m-block, module-range)
__global__ __launch_bounds__(256) void k_m0(const int* __restrict__ mr, const int* __restrict__ md,
                                            const int* __restrict__ ml, int* __restrict__ blkcnt_m) {
  __shared__ int c[256];
  int e, blk, E0, NB, NR, RSZ, base; unsigned RECIP;
  decode_mblk(blockIdx.x, e, blk, E0, NB, NR, RECIP, RSZ, base);
  const int* mod = (e == 0) ? mr : (e == 1) ? md : ml;
  c[threadIdx.x] = 0;
  __syncthreads();
  int i0 = blk * MBE;
#pragma unroll
  for (int q = 0; q < 4; q++) {
    int i = i0 + q * 256 + threadIdx.x;
    if (i < E0) {
      int m = mod[i];
      int r = (int)(((unsigned long long)(unsigned)m * RECIP) >> 25);
      atomicAdd(&c[r], 1);
    }
  }
  __syncthreads();
  for (int r = threadIdx.x; r < NR; r += 256)
    blkcnt_m[base + r * NB + blk] = c[r];
}

// exclusive scan per range over m-blocks (in place); totals -> rcnt[336]
__global__ __launch_bounds__(1024) void k_mscan(int* __restrict__ blkcnt_m, int* __restrict__ rcnt) {
  __shared__ int sm[1024];
  int gb = blockIdx.x;
  int NB, base, rl;
  if (gb < MR_RET) { rl = gb; NB = NBM_RET; base = BM_RET; }
  else if (gb < MR_RET + MR_DRAM) { rl = gb - MR_RET; NB = NBM_DRAM; base = BM_DRAM; }
  else { rl = gb - MR_RET - MR_DRAM; NB = NBM_LINK; base = BM_LINK; }
  int* arr = blkcnt_m + base + rl * NB;
  int carry = 0;
  for (int t0 = 0; t0 < NB; t0 += 1024) {
    int i = t0 + threadIdx.x;
    int v = (i < NB) ? arr[i] : 0;
    sm[threadIdx.x] = v;
    __syncthreads();
    for (int d = 1; d < 1024; d <<= 1) {
      int x = (threadIdx.x >= d) ? sm[threadIdx.x - d] : 0;
      __syncthreads();
      sm[threadIdx.x] += x;
      __syncthreads();
    }
    if (i < NB) arr[i] = carry + sm[threadIdx.x] - v;
    int tot = sm[1023];
    __syncthreads();
    carry += tot;
  }
  if (threadIdx.x == 0) rcnt[gb] = carry;
}

// scatter records (feat32|task16|mloc16) to exact module-bucket slots
__global__ __launch_bounds__(256) void k_mscatter(
    const int* __restrict__ mr, const int* __restrict__ md, const int* __restrict__ ml,
    const int* __restrict__ tl,
    const float* __restrict__ fr, const float* __restrict__ fd, const float* __restrict__ fl,
    const int* __restrict__ blkcnt_m,
    unsigned long long* __restrict__ mrec_ret, unsigned long long* __restrict__ mrec_dram,
    unsigned long long* __restrict__ mrec_link) {
  __shared__ int lb[256];
  __shared__ int lc[256];
  int e, blk, E0, NB, NR, RSZ, base; unsigned RECIP;
  decode_mblk(blockIdx.x, e, blk, E0, NB, NR, RECIP, RSZ, base);
  const int* mod = (e == 0) ? mr : (e == 1) ? md : ml;
  const float* feat = (e == 0) ? fr : (e == 1) ? fd : fl;
  unsigned long long* out = (e == 0) ? mrec_ret : (e == 1) ? mrec_dram : mrec_link;
  int CAP = (e == 0) ? CAPM_RET : (e == 1) ? CAPM_DRAM : CAPM_LINK;
  for (int r = threadIdx.x; r < NR; r += 256) {
    lb[r] = blkcnt_m[base + r * NB + blk];
    lc[r] = 0;
  }
  __syncthreads();
  int i0 = blk * MBE;
#pragma unroll
  for (int q = 0; q < 4; q++) {
    int i = i0 + q * 256 + threadIdx.x;
    if (i < E0) {
      int m = mod[i];
      int r = (int)(((unsigned long long)(unsigned)m * RECIP) >> 25);
      unsigned mloc = (unsigned)(m - r * RSZ);
      unsigned task = (e == 2) ? (unsigned)tl[i] : 0u;
      unsigned fu = __float_as_uint(feat[i]);
      int slot = lb[r] + atomicAdd(&lc[r], 1);
      if (slot < CAP)
        out[(long)r * CAP + slot] = ((unsigned long long)fu << 32) | (task << 16) | mloc;
    }
  }
}

// per-range: LDS sums -> s_*; link also cnt/offs/CSR. No global atomics anywhere.
__global__ __launch_bounds__(256) void k_msum(
    const unsigned long long* __restrict__ mrec_ret,
    const unsigned long long* __restrict__ mrec_dram,
    const unsigned long long* __restrict__ mrec_link,
    const int* __restrict__ rcnt,
    float* __restrict__ s_ret, float* __restrict__ s_dram, float* __restrict__ s_link,
    int* __restrict__ cnt, int* __restrict__ offs, int* __restrict__ csr) {
  __shared__ float ssum[RSZ_LINK];
  __shared__ int scnt[RSZ_LINK];
  __shared__ int soff[RSZ_LINK + 1];
  __shared__ int red[256];
  int gb = blockIdx.x, tid = threadIdx.x;
  int e, rl, RSZ, CAP, Ntot;
  const unsigned long long* p;
  float* sout;
  if (gb < MR_RET) {
    e = 0; rl = gb; p = mrec_ret + (long)rl * CAPM_RET; sout = s_ret;
    RSZ = RSZ_RET; CAP = CAPM_RET; Ntot = N_RET;
  } else if (gb < MR_RET + MR_DRAM) {
    e = 1; rl = gb - MR_RET; p = mrec_dram + (long)rl * CAPM_DRAM; sout = s_dram;
    RSZ = RSZ_DRAM; CAP = CAPM_DRAM; Ntot = N_DRAM;
  } else {
    e = 2; rl = gb - MR_RET - MR_DRAM; p = mrec_link + (long)rl * CAPM_LINK; sout = s_link;
    RSZ = RSZ_LINK; CAP = CAPM_LINK; Ntot = N_LINK;
  }
  int m0 = rl * RSZ;
  int nmod = Ntot - m0; if (nmod > RSZ) nmod = RSZ;
  for (int j = tid; j < RSZ; j += 256) { ssum[j] = 0.f; scnt[j] = 0; }
  __syncthreads();
  int count = rcnt[gb]; if (count > CAP) count = CAP;
  for (int i = tid; i < count; i += 256) {
    unsigned long long rec = p[i];
    int mloc = (int)(rec & 0xFFFFull);
    atomicAdd(&ssum[mloc], __uint_as_float((unsigned)(rec >> 32)));
    if (e == 2) atomicAdd(&scnt[mloc], 1);
  }
  __syncthreads();
  for (int j = tid; j < nmod; j += 256) sout[m0 + j] = ssum[j];
  if (e != 2) return;
  // global range base = sum of preceding link-range totals (gb-80 <= 255)
  int partial = (80 + tid < gb) ? rcnt[80 + tid] : 0;
  red[tid] = partial;
  __syncthreads();
  for (int s = 128; s > 0; s >>= 1) {
    if (tid < s) red[tid] += red[tid + s];
    __syncthreads();
  }
  int rb = red[0];
  __syncthreads();
  // exclusive scan of scnt[0..nmod) -> soff (2 elems/thread)
  int a0 = (2 * tid < nmod) ? scnt[2 * tid] : 0;
  int a1 = (2 * tid + 1 < nmod) ? scnt[2 * tid + 1] : 0;
  red[tid] = a0 + a1;
  __syncthreads();
  for (int d = 1; d < 256; d <<= 1) {
    int x = (tid >= d) ? red[tid - d] : 0;
    __syncthreads();
    red[tid] += x;
    __syncthreads();
  }
  int excl = red[tid] - (a0 + a1);
  if (2 * tid < RSZ_LINK) soff[2 * tid] = excl;
  if (2 * tid + 1 < RSZ_LINK) soff[2 * tid + 1] = excl + a0;
  __syncthreads();
  for (int j = tid; j < nmod; j += 256) {
    cnt[m0 + j] = scnt[j];
    offs[m0 + j] = rb + soff[j];
  }
  __syncthreads();
  // CSR emission via LDS cursors (soff becomes cursor)
  for (int i = tid; i < count; i += 256) {
    unsigned long long rec = p[i];
    int mloc = (int)(rec & 0xFFFFull);
    int task = (int)((rec >> 16) & 0xFFFFull);
    int lp = atomicAdd(&soff[mloc], 1);
    csr[rb + lp] = task;
  }
}

// =================== task-bucket min/max pipeline ===================

__device__ __forceinline__ void decode_tblk(int blk, int& e, int& blk_local, int& E0, int& NB) {
  if (blk < NB_RET) { e = 0; blk_local = blk; E0 = E_RET; NB = NB_RET; }
  else if (blk < NB_RET + NB_DRAM) { e = 1; blk_local = blk - NB_RET; E0 = E_DRAM; NB = NB_DRAM; }
  else { e = 2; blk_local = blk - NB_RET - NB_DRAM; E0 = E_LINK; NB = NB_LINK; }
}

__global__ __launch_bounds__(256) void k_a0(const int* __restrict__ tr,
                                            const int* __restrict__ td,
                                            const int* __restrict__ tl,
                                            int* __restrict__ blkcnt_t) {
  __shared__ int c[16];
  if (threadIdx.x < 16) c[threadIdx.x] = 0;
  __syncthreads();
  int e, blk_local, E0, NB;
  decode_tblk(blockIdx.x, e, blk_local, E0, NB);
  const int* task = (e == 0) ? tr : (e == 1) ? td : tl;
  int i = blk_local * 256 + threadIdx.x;
  if (i < E0) {
    int b = task[i] / R_PART;
    atomicAdd(&c[b], 1);
  }
  __syncthreads();
  int base = (e == 0) ? 0 : (e == 1) ? 16 * NB_RET : 16 * (NB_RET + NB_DRAM);
  if (threadIdx.x < 16) blkcnt_t[base + threadIdx.x * NB + blk_local] = c[threadIdx.x];
}

__global__ __launch_bounds__(1024) void k_ascan(int* __restrict__ blkcnt_t, int* __restrict__ bcnt) {
  __shared__ int sm[1024];
  int gb = blockIdx.x;  // 0..47
  int e = gb >> 4, b = gb & 15;
  int NB = (e == 0) ? NB_RET : (e == 1) ? NB_DRAM : NB_LINK;
  int base = (e == 0) ? 0 : (e == 1) ? 16 * NB_RET : 16 * (NB_RET + NB_DRAM);
  int* arr = blkcnt_t + base + b * NB;
  int carry = 0;
  for (int t0 = 0; t0 < NB; t0 += 1024) {
    int i = t0 + threadIdx.x;
    int v = (i < NB) ? arr[i] : 0;
    sm[threadIdx.x] = v;
    __syncthreads();
    for (int d = 1; d < 1024; d <<= 1) {
      int x = (threadIdx.x >= d) ? sm[threadIdx.x - d] : 0;
      __syncthreads();
      sm[threadIdx.x] += x;
      __syncthreads();
    }
    if (i < NB) arr[i] = carry + sm[threadIdx.x] - v;
    int tot = sm[1023];
    __syncthreads();
    carry += tot;
  }
  if (threadIdx.x == 0) bcnt[gb] = carry;
}

__global__ __launch_bounds__(256) void k_ascatter(
    const int* __restrict__ tr, const int* __restrict__ mr,
    const int* __restrict__ td, const int* __restrict__ md,
    const int* __restrict__ tl, const int* __restrict__ ml,
    const float* __restrict__ s_ret, const float* __restrict__ s_dram,
    const float* __restrict__ s_link, const int* __restrict__ blkcnt_t,
    unsigned long long* __restrict__ trec_ret, unsigned long long* __restrict__ trec_dram,
    unsigned long long* __restrict__ trec_link) {
  __shared__ int lbase[16];
  __shared__ int lc[16];
  int e, blk_local, E0, NB;
  decode_tblk(blockIdx.x, e, blk_local, E0, NB);
  int base = (e == 0) ? 0 : (e == 1) ? 16 * NB_RET : 16 * (NB_RET + NB_DRAM);
  if (threadIdx.x < 16) {
    lbase[threadIdx.x] = blkcnt_t[base + threadIdx.x * NB + blk_local];
    lc[threadIdx.x] = 0;
  }
  __syncthreads();
  const int* task = (e == 0) ? tr : (e == 1) ? td : tl;
  const int* mod = (e == 0) ? mr : (e == 1) ? md : ml;
  const float* s = (e == 0) ? s_ret : (e == 1) ? s_dram : s_link;
  unsigned long long* bkt = (e == 0) ? trec_ret : (e == 1) ? trec_dram : trec_link;
  int CAP = (e == 0) ? CAP_RET : (e == 1) ? CAP_DRAM : CAP_LINK;
  int i = blk_local * 256 + threadIdx.x;
  if (i < E0) {
    int t = task[i];
    int b = t / R_PART;
    unsigned r = (unsigned)(t - b * R_PART);
    unsigned u = ford(s[mod[i]]);
    int slot = lbase[b] + atomicAdd(&lc[b], 1);
    if (slot < CAP)
      bkt[(long)b * CAP + slot] = ((unsigned long long)u << 32) | r;
  }
}

__global__ __launch_bounds__(256) void k_passb(
    const unsigned long long* __restrict__ trec_ret,
    const unsigned long long* __restrict__ trec_dram,
    const unsigned long long* __restrict__ trec_link,
    const int* __restrict__ bcnt, unsigned* __restrict__ partials) {
  __shared__ unsigned lmax[R_PART];
  __shared__ unsigned lmin[R_PART];
  int blk = blockIdx.x;
  int e, b, sub, Nb, PB, CAP;
  const unsigned long long* bkt;
  if (blk < 16 * SUB_RET) {
    e = 0; b = blk >> 2; sub = blk & 3; Nb = SUB_RET; PB = PB_RET; CAP = CAP_RET; bkt = trec_ret;
  } else if (blk < 16 * (SUB_RET + SUB_DRAM)) {
    int q = blk - 16 * SUB_RET;
    e = 1; b = q; sub = 0; Nb = SUB_DRAM; PB = PB_DRAM; CAP = CAP_DRAM; bkt = trec_dram;
  } else {
    int q = blk - 16 * (SUB_RET + SUB_DRAM);
    e = 2; b = q >> 3; sub = q & 7; Nb = SUB_LINK; PB = PB_LINK; CAP = CAP_LINK; bkt = trec_link;
  }
  for (int idx = threadIdx.x; idx < R_PART; idx += 256) {
    lmax[idx] = 0u;
    lmin[idx] = 0xFFFFFFFFu;
  }
  __syncthreads();
  int count = bcnt[e * 16 + b];
  if (count > CAP) count = CAP;
  int chunk = (count + Nb - 1) / Nb;
  int s0 = sub * chunk;
  int s1 = s0 + chunk; if (s1 > count) s1 = count;
  const unsigned long long* p = bkt + (long)b * CAP;
  for (int i = s0 + threadIdx.x; i < s1; i += 256) {
    unsigned long long rec = p[i];
    unsigned r = (unsigned)rec;
    unsigned u = (unsigned)(rec >> 32);
    atomicMax(&lmax[r], u);
    atomicMin(&lmin[r], u);
  }
  __syncthreads();
  unsigned gbase = PB + (unsigned)(b * Nb + sub) * R_PART;
  for (int idx = threadIdx.x; idx < R_PART; idx += 256) {
    partials[gbase + idx] = lmax[idx];
    partials[PB_TOT + gbase + idx] = lmin[idx];
  }
}

__global__ __launch_bounds__(256) void k_mmred2(const unsigned* __restrict__ partials,
                                                unsigned* __restrict__ tmax,
                                                unsigned* __restrict__ tmin) {
  int gid = blockIdx.x * 256 + threadIdx.x;
  if (gid >= 3 * N_TASK) return;
  int e = gid / N_TASK;
  int t = gid - e * N_TASK;
  int Nb = (e == 0) ? SUB_RET : (e == 1) ? SUB_DRAM : SUB_LINK;
  int PB = (e == 0) ? PB_RET : (e == 1) ? PB_DRAM : PB_LINK;
  int b = t / R_PART;
  int r = t - b * R_PART;
  unsigned umax = 0u, umin = 0xFFFFFFFFu;
  for (int sub = 0; sub < Nb; sub++) {
    unsigned idx = PB + (unsigned)(b * Nb + sub) * R_PART + r;
    unsigned w = partials[idx];
    if (w > umax) umax = w;
    unsigned w2 = partials[PB_TOT + idx];
    if (w2 < umin) umin = w2;
  }
  tmax[gid] = umax;
  tmin[gid] = umin;
}

// =================== fallback (small ws): global-atomic path ===================

__global__ void f_segsum(const float* __restrict__ fr, const float* __restrict__ fd,
                         const float* __restrict__ fl,
                         const int* __restrict__ mr, const int* __restrict__ md,
                         const int* __restrict__ ml,
                         float* s_ret, float* s_dram, float* s_link, int* cnt) {
  int i = blockIdx.x * blockDim.x + threadIdx.x;
  const int total = E_RET + E_DRAM + E_LINK;
  if (i >= total) return;
  if (i < E_RET) {
    atomicAdd(&s_ret[mr[i]], fr[i]);
  } else if (i < E_RET + E_DRAM) {
    int j = i - E_RET;
    atomicAdd(&s_dram[md[j]], fd[j]);
  } else {
    int j = i - (E_RET + E_DRAM);
    int m = ml[j];
    atomicAdd(&s_link[m], fl[j]);
    atomicAdd(&cnt[m], 1);
  }
}

__global__ void f_minmax(const float* __restrict__ s_ret, const float* __restrict__ s_dram,
                         const float* __restrict__ s_link,
                         const int* __restrict__ tr, const int* __restrict__ mr,
                         const int* __restrict__ td, const int* __restrict__ md,
                         const int* __restrict__ tl, const int* __restrict__ ml,
                         unsigned* tmax, unsigned* tmin) {
  int i = blockIdx.x * blockDim.x + threadIdx.x;
  const int total = E_RET + E_DRAM + E_LINK;
  if (i >= total) return;
  int e, task; unsigned u;
  if (i < E_RET) {
    u = ford(s_ret[mr[i]]); task = tr[i]; e = 0;
  } else if (i < E_RET + E_DRAM) {
    int j = i - E_RET;
    u = ford(s_dram[md[j]]); task = td[j]; e = 1;
  } else {
    int j = i - (E_RET + E_DRAM);
    u = ford(s_link[ml[j]]); task = tl[j]; e = 2;
  }
  atomicMax(&tmax[e * N_TASK + task], u);
  atomicMin(&tmin[e * N_TASK + task], u);
}

__global__ void f_part(const int* __restrict__ cnt, int* part) {
  __shared__ int sm[256];
  int i = blockIdx.x * 256 + threadIdx.x;
  sm[threadIdx.x] = (i < N_LINK) ? cnt[i] : 0;
  __syncthreads();
  for (int s = 128; s > 0; s >>= 1) {
    if (threadIdx.x < s) sm[threadIdx.x] += sm[threadIdx.x + s];
    __syncthreads();
  }
  if (threadIdx.x == 0) part[blockIdx.x] = sm[0];
}

__global__ void f_scanpart(const int* __restrict__ part, int* partx, int npart) {
  __shared__ int sm[512];
  int t = threadIdx.x;
  int v = (t < npart) ? part[t] : 0;
  sm[t] = v;
  __syncthreads();
  for (int d = 1; d < 512; d <<= 1) {
    int x = (t >= d) ? sm[t - d] : 0;
    __syncthreads();
    sm[t] += x;
    __syncthreads();
  }
  if (t < npart) partx[t] = sm[t] - v;
}

__global__ void f_offs(const int* __restrict__ cnt, const int* __restrict__ partx,
                       int* offs, int* cursor) {
  __shared__ int sm[256];
  int i = blockIdx.x * 256 + threadIdx.x;
  int t = threadIdx.x;
  int v = (i < N_LINK) ? cnt[i] : 0;
  sm[t] = v;
  __syncthreads();
  for (int d = 1; d < 256; d <<= 1) {
    int x = (t >= d) ? sm[t - d] : 0;
    __syncthreads();
    sm[t] += x;
    __syncthreads();
  }
  if (i < N_LINK) {
    int o = partx[blockIdx.x] + sm[t] - v;
    offs[i] = o;
    cursor[i] = o;
  }
}

__global__ void f_scatter(const int* __restrict__ tl, const int* __restrict__ ml,
                          int* cursor, int* csr) {
  int i = blockIdx.x * blockDim.x + threadIdx.x;
  if (i >= E_LINK) return;
  int pos = atomicAdd(&cursor[ml[i]], 1);
  csr[pos] = tl[i];
}

// =================== shared tail: task GEMM + link mean ===================

__global__ __launch_bounds__(64) void k_task(
    const float* __restrict__ W_ret, const float* __restrict__ b_ret,
    const float* __restrict__ W_dram, const float* __restrict__ b_dram,
    const float* __restrict__ W_link, const float* __restrict__ b_link,
    const float* __restrict__ W_task, const float* __restrict__ b_task,
    const unsigned* __restrict__ tmax, const unsigned* __restrict__ tmin,
    unsigned short* __restrict__ h_task) {
  __shared__ __attribute__((aligned(16))) float hcS[64 * 64];
  __shared__ __attribute__((aligned(16))) float wtS[64 * 64];
  int tid = threadIdx.x;
  int tx = tid & 7, ty = tid >> 3;
  int o0 = tx * 8;
  int tile0 = blockIdx.x * 64;

  float acc[8][8];
#pragma unroll
  for (int i = 0; i < 8; i++)
#pragma unroll
    for (int j = 0; j < 8; j++) acc[i][j] = 0.f;

  const float* We[3] = {W_ret, W_dram, W_link};
  const float* be[3] = {b_ret, b_dram, b_link};

  for (int e = 0; e < 3; e++) {
    for (int idx = tid; idx < 4096; idx += 64) {
      int k = idx >> 6, o = idx & 63;
      wtS[idx] = W_task[o * 192 + e * 64 + k];
    }
    for (int idx = tid; idx < 4096; idx += 64) {
      int t_l = idx >> 6, k = idx & 63;
      int t = tile0 + t_l;
      float hc = 0.f;
      if (t < N_TASK) {
        unsigned um = tmax[e * N_TASK + t];
        if (um != 0u) {
          float smax = funord(um);
          float smin = funord(tmin[e * N_TASK + t]);
          float w = We[e][k];
          float ssel = (w >= 0.f) ? smax : smin;
          hc = tanhf(fmaf(ssel, w, be[e][k]));
        }
      }
      hcS[idx] = hc;
    }
    __syncthreads();
#pragma unroll
    for (int k4 = 0; k4 < 16; k4++) {
      int k = k4 * 4;
      float4 hv[8];
#pragma unroll
      for (int i = 0; i < 8; i++) hv[i] = *(const float4*)&hcS[(ty * 8 + i) * 64 + k];
      float wv[4][8];
#pragma unroll
      for (int dk = 0; dk < 4; dk++) {
        float4 a = *(const float4*)&wtS[(k + dk) * 64 + o0];
        float4 b = *(const float4*)&wtS[(k + dk) * 64 + o0 + 4];
        wv[dk][0] = a.x; wv[dk][1] = a.y; wv[dk][2] = a.z; wv[dk][3] = a.w;
        wv[dk][4] = b.x; wv[dk][5] = b.y; wv[dk][6] = b.z; wv[dk][7] = b.w;
      }
#pragma unroll
      for (int i = 0; i < 8; i++) {
        float hvv[4] = {hv[i].x, hv[i].y, hv[i].z, hv[i].w};
#pragma unroll
        for (int dk = 0; dk < 4; dk++)
#pragma unroll
          for (int j = 0; j < 8; j++)
            acc[i][j] = fmaf(hvv[dk], wv[dk][j], acc[i][j]);
      }
    }
    __syncthreads();
  }

#pragma unroll
  for (int i = 0; i < 8; i++) {
    int t = tile0 + ty * 8 + i;
    if (t < N_TASK) {
#pragma unroll
      for (int g = 0; g < 2; g++) {
        ushort4 r;
        unsigned short rr[4];
#pragma unroll
        for (int j = 0; j < 4; j++) {
          float v = tanhf(acc[i][g * 4 + j] + b_task[o0 + g * 4 + j]);
          unsigned u = __float_as_uint(v);
          rr[j] = (unsigned short)((u + 0x7fffu + ((u >> 16) & 1u)) >> 16);
        }
        r.x = rr[0]; r.y = rr[1]; r.z = rr[2]; r.w = rr[3];
        *(ushort4*)&h_task[t * 64 + o0 + g * 4] = r;
      }
    }
  }
}

__global__ __launch_bounds__(256) void k_link(const unsigned short* __restrict__ h_task,
                                              const int* __restrict__ offs,
                                              const int* __restrict__ cnt,
                                              const int* __restrict__ csr,
                                              float* __restrict__ out) {
  int wid = threadIdx.x >> 6, lane = threadIdx.x & 63;
  int l = blockIdx.x * 4 + wid;  // 25000*4 == N_LINK
  int start = offs[l];
  int c = cnt[l];
  float acc = 0.f;
  int tnext = (c > 0) ? csr[start] : 0;
  for (int q = 0; q < c; q++) {
    int task = tnext;
    if (q + 1 < c) tnext = csr[start + q + 1];
    unsigned hs = h_task[task * 64 + lane];
    acc += __uint_as_float(hs << 16);
  }
  out[l * 64 + lane] = (c > 0) ? acc / (float)c : 0.f;
}

extern "C" void kernel_launch(void* const* d_in, const int* in_sizes, int n_in,
                              void* d_out, int out_size, void* d_ws, size_t ws_size,
                              hipStream_t stream) {
  const float* feat_ret  = (const float*)d_in[0];
  const float* feat_dram = (const float*)d_in[1];
  const float* feat_link = (const float*)d_in[2];
  const float* W_ret  = (const float*)d_in[3];
  const float* b_ret  = (const float*)d_in[4];
  const float* W_dram = (const float*)d_in[5];
  const float* b_dram = (const float*)d_in[6];
  const float* W_link = (const float*)d_in[7];
  const float* b_link = (const float*)d_in[8];
  const float* W_task = (const float*)d_in[9];
  const float* b_task = (const float*)d_in[10];
  const int* task_ret  = (const int*)d_in[11];
  const int* mod_ret   = (const int*)d_in[12];
  const int* task_dram = (const int*)d_in[13];
  const int* mod_dram  = (const int*)d_in[14];
  const int* task_link = (const int*)d_in[15];
  const int* mod_link  = (const int*)d_in[16];
  float* out = (float*)d_out;

  char* ws = (char*)d_ws;
  float* s_ret  = (float*)(ws + WS_SRET);
  float* s_dram = (float*)(ws + WS_SDRAM);
  float* s_link = (float*)(ws + WS_SLINK);
  int*   cnt    = (int*)(ws + WS_CNT);
  int*   offs   = (int*)(ws + WS_OFFS);
  unsigned* tmax = (unsigned*)(ws + WS_TMAX);
  unsigned* tmin = (unsigned*)(ws + WS_TMIN);
  int* bcnt = (int*)(ws + WS_BCNT);
  int* rcnt = (int*)(ws + WS_RCNT);
  int* csr  = (int*)(ws + WS_CSR);
  int* blkcnt_m = (int*)(ws + WS_BLKM);
  int* blkcnt_t = (int*)(ws + WS_BLKT);
  unsigned* partials = (unsigned*)(ws + WS_PARTIALS);
  unsigned long long* mrec_ret  = (unsigned long long*)(ws + WS_MREC_RET);
  unsigned long long* mrec_dram = (unsigned long long*)(ws + WS_MREC_DRAM);
  unsigned long long* mrec_link = (unsigned long long*)(ws + WS_MREC_LINK);
  unsigned long long* trec_ret  = (unsigned long long*)(ws + WS_TREC_RET);
  unsigned long long* trec_dram = (unsigned long long*)(ws + WS_TREC_DRAM);
  unsigned long long* trec_link = (unsigned long long*)(ws + WS_TREC_LINK);
  unsigned short* h_task = (unsigned short*)(ws + WS_HTASK);

  if (ws_size >= (size_t)WS_NEED) {
    // ---- atomic-free main path ----
    k_m0<<<NBM_TOT, 256, 0, stream>>>(mod_ret, mod_dram, mod_link, blkcnt_m);
    k_mscan<<<MR_RET + MR_DRAM + MR_LINK, 1024, 0, stream>>>(blkcnt_m, rcnt);
    k_mscatter<<<NBM_TOT, 256, 0, stream>>>(mod_ret, mod_dram, mod_link, task_link,
                                            feat_ret, feat_dram, feat_link, blkcnt_m,
                                            mrec_ret, mrec_dram, mrec_link);
    k_msum<<<MR_RET + MR_DRAM + MR_LINK, 256, 0, stream>>>(
        mrec_ret, mrec_dram, mrec_link, rcnt, s_ret, s_dram, s_link, cnt, offs, csr);
    const int nblkT = NB_RET + NB_DRAM + NB_LINK;  // 12697
    k_a0<<<nblkT, 256, 0, stream>>>(task_ret, task_dram, task_link, blkcnt_t);
    k_ascan<<<48, 1024, 0, stream>>>(blkcnt_t, bcnt);
    k_ascatter<<<nblkT, 256, 0, stream>>>(task_ret, mod_ret, task_dram, mod_dram,
                                          task_link, mod_link, s_ret, s_dram, s_link,
                                          blkcnt_t, trec_ret, trec_dram, trec_link);
    k_passb<<<16 * (SUB_RET + SUB_DRAM + SUB_LINK), 256, 0, stream>>>(
        trec_ret, trec_dram, trec_link, bcnt, partials);
    k_mmred2<<<(3 * N_TASK + 255) / 256, 256, 0, stream>>>(partials, tmax, tmin);
  } else {
    // ---- fallback: global-atomic path ----
    int* part   = (int*)(ws + WS_BLKM);
    int* partx  = (int*)(ws + WS_BLKM + 4096);
    int* cursor = (int*)(ws + WS_BLKT);
    hipMemsetAsync(ws, 0, 1900000, stream);                 // s/cnt/offs/tmax
    hipMemsetAsync(ws + WS_TMIN, 0xFF, 600000, stream);     // tmin
    const int totalE = E_RET + E_DRAM + E_LINK;
    int nblk_e = (totalE + 255) / 256;
    f_segsum<<<nblk_e, 256, 0, stream>>>(feat_ret, feat_dram, feat_link,
                                         mod_ret, mod_dram, mod_link,
                                         s_ret, s_dram, s_link, cnt);
    f_minmax<<<nblk_e, 256, 0, stream>>>(s_ret, s_dram, s_link,
                                         task_ret, mod_ret, task_dram, mod_dram,
                                         task_link, mod_link, tmax, tmin);
    const int npart = (N_LINK + 255) / 256;  // 391
    f_part<<<npart, 256, 0, stream>>>(cnt, part);
    f_scanpart<<<1, 512, 0, stream>>>(part, partx, npart);
    f_offs<<<npart, 256, 0, stream>>>(cnt, partx, offs, cursor);
    f_scatter<<<(E_LINK + 255) / 256, 256, 0, stream>>>(task_link, mod_link, cursor, csr);
  }

  k_task<<<(N_TASK + 63) / 64, 64, 0, stream>>>(W_ret, b_ret, W_dram, b_dram,
                                                W_link, b_link, W_task, b_task,
                                                tmax, tmin, h_task);
  k_link<<<N_LINK / 4, 256, 0, stream>>>(h_task, offs, cnt, csr, out);
}

// Round 5
// 463.523 us; speedup vs baseline: 2.6848x; 1.0618x over previous
//
#include <hip/hip_runtime.h>
#include <stdint.h>

#define N_TASK 50000
#define N_RET 20000
#define N_DRAM 5000
#define N_LINK 100000
#define E_RET 1000000
#define E_DRAM 250000
#define E_LINK 2000000

// ---- module-range bucketing (segment sums + CSR, zero global atomics) ----
#define MBE 1024                // edges per m-block
#define NBM_RET 977
#define NBM_DRAM 245
#define NBM_LINK 1954
#define NBM_TOT (NBM_RET + NBM_DRAM + NBM_LINK)   // 3176
#define MR_RET 64
#define RSZ_RET 313             // 64*313 = 20032 >= 20000
#define MR_DRAM 16
#define RSZ_DRAM 313            // 16*313 = 5008 >= 5000
#define MR_LINK 256
#define RSZ_LINK 391            // 256*391 = 100096 >= 100000
#define RECIP313 107203u        // ceil(2^25/313); exact div for m < 313k
#define RECIP391 85817u         // ceil(2^25/391); exact div for m < 2.2M
#define CAPM_RET 16250          // mean 15625, +5σ
#define CAPM_DRAM 16250
#define CAPM_LINK 8255          // mean 7813, +5σ
#define BM_RET 0                // blkcnt_m element offsets
#define BM_DRAM (MR_RET * NBM_RET)                  // 62528
#define BM_LINK (BM_DRAM + MR_DRAM * NBM_DRAM)      // 66448
#define BM_TOT (BM_LINK + MR_LINK * NBM_LINK)       // 566672

// ---- task-range bucketing (per-task min/max) ----
#define R_PART 3125             // 16*3125 == N_TASK
#define NB_RET 3907             // 256-edge blocks
#define NB_DRAM 977
#define NB_LINK 7813
#define CAP_RET 63800           // mean 62500, +5σ
#define CAP_DRAM 16300
#define CAP_LINK 126800
#define SUB_RET 4
#define SUB_DRAM 1
#define SUB_LINK 8
#define PB_RET 0
#define PB_DRAM (16 * SUB_RET * R_PART)             // 200000
#define PB_LINK (PB_DRAM + 16 * SUB_DRAM * R_PART)  // 250000
#define PB_TOT (PB_LINK + 16 * SUB_LINK * R_PART)   // 650000 words per plane

// ---- workspace byte offsets ----
#define WS_SRET 0               // 20000 f
#define WS_SDRAM 80000          // 5000 f
#define WS_SLINK 100000         // 100000 f
#define WS_CNT 500000           // 100000 i
#define WS_OFFS 900000          // 100000 i
#define WS_TMAX 1300000         // 150000 u
#define WS_TMIN 1900000         // 150000 u
#define WS_BCNT 2500000         // 48 i
#define WS_RCNT 2500192         // 336 i
#define WS_CSR 2501536          // 2M i -> ends 10501536
// counts region [10501536, 15701536): blkcnt_m, blkcnt_t, then partials
#define WS_BLKM 10501536        // 566672 i (dead after k_mscatter)
#define WS_BLKT 12768224        // 203152 i (dead after k_ascatter)
#define WS_PARTIALS 10501536    // 2*650000 u (written by k_passb, after both dead)
// records union [15701536, 43007776):
#define WS_MREC_RET 15701536    // 64*16250*8  -> 24021536
#define WS_MREC_DRAM 24021536   // 16*16250*8  -> 26101536
#define WS_MREC_LINK 26101536   // 256*8255*8  -> 43007776
#define WS_TREC_RET 15701536    // 16*63800*8  -> 23867936 (after mrec dead)
#define WS_TREC_DRAM 23867936   // 16*16300*8  -> 25954336
#define WS_TREC_LINK 25954336   // 16*126800*8 -> 42184736
// h_task split into two feature planes (3.2MB each, < 4MB per-XCD L2)
#define WS_HPL0 15701536        // 50000*32 u16 -> 18901536 (after trec dead)
#define WS_HPL1 18901536        // 50000*32 u16 -> 22101536
#define WS_NEED 43007776

// ---- order-preserving float<->uint (min/max as uint); 0 / 0xFFFFFFFF unreachable ----
__device__ __forceinline__ unsigned ford(float f) {
  unsigned u = __float_as_uint(f);
  return (u & 0x80000000u) ? ~u : (u | 0x80000000u);
}
__device__ __forceinline__ float funord(unsigned t) {
  unsigned u = (t & 0x80000000u) ? (t & 0x7fffffffu) : ~t;
  return __uint_as_float(u);
}

// =================== module-bucket pipeline ===================

__device__ __forceinline__ void decode_mblk(int bx, int& e, int& blk, int& E0, int& NB,
                                            int& NR, unsigned& RECIP, int& RSZ, int& base) {
  if (bx < NBM_RET) {
    e = 0; blk = bx; E0 = E_RET; NB = NBM_RET; NR = MR_RET; RECIP = RECIP313; RSZ = RSZ_RET; base = BM_RET;
  } else if (bx < NBM_RET + NBM_DRAM) {
    e = 1; blk = bx - NBM_RET; E0 = E_DRAM; NB = NBM_DRAM; NR = MR_DRAM; RECIP = RECIP313; RSZ = RSZ_DRAM; base = BM_DRAM;
  } else {
    e = 2; blk = bx - NBM_RET - NBM_DRAM; E0 = E_LINK; NB = NBM_LINK; NR = MR_LINK; RECIP = RECIP391; RSZ = RSZ_LINK; base = BM_LINK;
  }
}

// count per (m-block, module-range)
__global__ __launch_bounds__(256) void k_m0(const int* __restrict__ mr, const int* __restrict__ md,
                                            const int* __restrict__ ml, int* __restrict__ blkcnt_m) {
  __shared__ int c[256];
  int e, blk, E0, NB, NR, RSZ, base; unsigned RECIP;
  decode_mblk(blockIdx.x, e, blk, E0, NB, NR, RECIP, RSZ, base);
  const int* mod = (e == 0) ? mr : (e == 1) ? md : ml;
  c[threadIdx.x] = 0;
  __syncthreads();
  int i0 = blk * MBE;
#pragma unroll
  for (int q = 0; q < 4; q++) {
    int i = i0 + q * 256 + threadIdx.x;
    if (i < E0) {
      int m = mod[i];
      int r = (int)(((unsigned long long)(unsigned)m * RECIP) >> 25);
      atomicAdd(&c[r], 1);
    }
  }
  __syncthreads();
  for (int r = threadIdx.x; r < NR; r += 256)
    blkcnt_m[base + r * NB + blk] = c[r];
}

// exclusive scan per range over m-blocks (in place); totals -> rcnt[336]
__global__ __launch_bounds__(1024) void k_mscan(int* __restrict__ blkcnt_m, int* __restrict__ rcnt) {
  __shared__ int sm[1024];
  int gb = blockIdx.x;
  int NB, base, rl;
  if (gb < MR_RET) { rl = gb; NB = NBM_RET; base = BM_RET; }
  else if (gb < MR_RET + MR_DRAM) { rl = gb - MR_RET; NB = NBM_DRAM; base = BM_DRAM; }
  else { rl = gb - MR_RET - MR_DRAM; NB = NBM_LINK; base = BM_LINK; }
  int* arr = blkcnt_m + base + rl * NB;
  int carry = 0;
  for (int t0 = 0; t0 < NB; t0 += 1024) {
    int i = t0 + threadIdx.x;
    int v = (i < NB) ? arr[i] : 0;
    sm[threadIdx.x] = v;
    __syncthreads();
    for (int d = 1; d < 1024; d <<= 1) {
      int x = (threadIdx.x >= d) ? sm[threadIdx.x - d] : 0;
      __syncthreads();
      sm[threadIdx.x] += x;
      __syncthreads();
    }
    if (i < NB) arr[i] = carry + sm[threadIdx.x] - v;
    int tot = sm[1023];
    __syncthreads();
    carry += tot;
  }
  if (threadIdx.x == 0) rcnt[gb] = carry;
}

// scatter records (feat32|task16|mloc16) to exact module-bucket slots
__global__ __launch_bounds__(256) void k_mscatter(
    const int* __restrict__ mr, const int* __restrict__ md, const int* __restrict__ ml,
    const int* __restrict__ tl,
    const float* __restrict__ fr, const float* __restrict__ fd, const float* __restrict__ fl,
    const int* __restrict__ blkcnt_m,
    unsigned long long* __restrict__ mrec_ret, unsigned long long* __restrict__ mrec_dram,
    unsigned long long* __restrict__ mrec_link) {
  __shared__ int lb[256];
  __shared__ int lc[256];
  int e, blk, E0, NB, NR, RSZ, base; unsigned RECIP;
  decode_mblk(blockIdx.x, e, blk, E0, NB, NR, RECIP, RSZ, base);
  const int* mod = (e == 0) ? mr : (e == 1) ? md : ml;
  const float* feat = (e == 0) ? fr : (e == 1) ? fd : fl;
  unsigned long long* out = (e == 0) ? mrec_ret : (e == 1) ? mrec_dram : mrec_link;
  int CAP = (e == 0) ? CAPM_RET : (e == 1) ? CAPM_DRAM : CAPM_LINK;
  for (int r = threadIdx.x; r < NR; r += 256) {
    lb[r] = blkcnt_m[base + r * NB + blk];
    lc[r] = 0;
  }
  __syncthreads();
  int i0 = blk * MBE;
#pragma unroll
  for (int q = 0; q < 4; q++) {
    int i = i0 + q * 256 + threadIdx.x;
    if (i < E0) {
      int m = mod[i];
      int r = (int)(((unsigned long long)(unsigned)m * RECIP) >> 25);
      unsigned mloc = (unsigned)(m - r * RSZ);
      unsigned task = (e == 2) ? (unsigned)tl[i] : 0u;
      unsigned fu = __float_as_uint(feat[i]);
      int slot = lb[r] + atomicAdd(&lc[r], 1);
      if (slot < CAP)
        out[(long)r * CAP + slot] = ((unsigned long long)fu << 32) | (task << 16) | mloc;
    }
  }
}

// per-range: LDS sums -> s_*; link also cnt/offs/CSR. No global atomics anywhere.
__global__ __launch_bounds__(256) void k_msum(
    const unsigned long long* __restrict__ mrec_ret,
    const unsigned long long* __restrict__ mrec_dram,
    const unsigned long long* __restrict__ mrec_link,
    const int* __restrict__ rcnt,
    float* __restrict__ s_ret, float* __restrict__ s_dram, float* __restrict__ s_link,
    int* __restrict__ cnt, int* __restrict__ offs, int* __restrict__ csr) {
  __shared__ float ssum[RSZ_LINK];
  __shared__ int scnt[RSZ_LINK];
  __shared__ int soff[RSZ_LINK + 1];
  __shared__ int red[256];
  int gb = blockIdx.x, tid = threadIdx.x;
  int e, rl, RSZ, CAP, Ntot;
  const unsigned long long* p;
  float* sout;
  if (gb < MR_RET) {
    e = 0; rl = gb; p = mrec_ret + (long)rl * CAPM_RET; sout = s_ret;
    RSZ = RSZ_RET; CAP = CAPM_RET; Ntot = N_RET;
  } else if (gb < MR_RET + MR_DRAM) {
    e = 1; rl = gb - MR_RET; p = mrec_dram + (long)rl * CAPM_DRAM; sout = s_dram;
    RSZ = RSZ_DRAM; CAP = CAPM_DRAM; Ntot = N_DRAM;
  } else {
    e = 2; rl = gb - MR_RET - MR_DRAM; p = mrec_link + (long)rl * CAPM_LINK; sout = s_link;
    RSZ = RSZ_LINK; CAP = CAPM_LINK; Ntot = N_LINK;
  }
  int m0 = rl * RSZ;
  int nmod = Ntot - m0; if (nmod > RSZ) nmod = RSZ;
  for (int j = tid; j < RSZ; j += 256) { ssum[j] = 0.f; scnt[j] = 0; }
  __syncthreads();
  int count = rcnt[gb]; if (count > CAP) count = CAP;
  for (int i = tid; i < count; i += 256) {
    unsigned long long rec = p[i];
    int mloc = (int)(rec & 0xFFFFull);
    atomicAdd(&ssum[mloc], __uint_as_float((unsigned)(rec >> 32)));
    if (e == 2) atomicAdd(&scnt[mloc], 1);
  }
  __syncthreads();
  for (int j = tid; j < nmod; j += 256) sout[m0 + j] = ssum[j];
  if (e != 2) return;
  // global range base = sum of preceding link-range totals (gb-80 <= 255)
  int partial = (80 + tid < gb) ? rcnt[80 + tid] : 0;
  red[tid] = partial;
  __syncthreads();
  for (int s = 128; s > 0; s >>= 1) {
    if (tid < s) red[tid] += red[tid + s];
    __syncthreads();
  }
  int rb = red[0];
  __syncthreads();
  // exclusive scan of scnt[0..nmod) -> soff (2 elems/thread)
  int a0 = (2 * tid < nmod) ? scnt[2 * tid] : 0;
  int a1 = (2 * tid + 1 < nmod) ? scnt[2 * tid + 1] : 0;
  red[tid] = a0 + a1;
  __syncthreads();
  for (int d = 1; d < 256; d <<= 1) {
    int x = (tid >= d) ? red[tid - d] : 0;
    __syncthreads();
    red[tid] += x;
    __syncthreads();
  }
  int excl = red[tid] - (a0 + a1);
  if (2 * tid < RSZ_LINK) soff[2 * tid] = excl;
  if (2 * tid + 1 < RSZ_LINK) soff[2 * tid + 1] = excl + a0;
  __syncthreads();
  for (int j = tid; j < nmod; j += 256) {
    cnt[m0 + j] = scnt[j];
    offs[m0 + j] = rb + soff[j];
  }
  __syncthreads();
  // CSR emission via LDS cursors (soff becomes cursor)
  for (int i = tid; i < count; i += 256) {
    unsigned long long rec = p[i];
    int mloc = (int)(rec & 0xFFFFull);
    int task = (int)((rec >> 16) & 0xFFFFull);
    int lp = atomicAdd(&soff[mloc], 1);
    csr[rb + lp] = task;
  }
}

// =================== task-bucket min/max pipeline ===================

__device__ __forceinline__ void decode_tblk(int blk, int& e, int& blk_local, int& E0, int& NB) {
  if (blk < NB_RET) { e = 0; blk_local = blk; E0 = E_RET; NB = NB_RET; }
  else if (blk < NB_RET + NB_DRAM) { e = 1; blk_local = blk - NB_RET; E0 = E_DRAM; NB = NB_DRAM; }
  else { e = 2; blk_local = blk - NB_RET - NB_DRAM; E0 = E_LINK; NB = NB_LINK; }
}

__global__ __launch_bounds__(256) void k_a0(const int* __restrict__ tr,
                                            const int* __restrict__ td,
                                            const int* __restrict__ tl,
                                            int* __restrict__ blkcnt_t) {
  __shared__ int c[16];
  if (threadIdx.x < 16) c[threadIdx.x] = 0;
  __syncthreads();
  int e, blk_local, E0, NB;
  decode_tblk(blockIdx.x, e, blk_local, E0, NB);
  const int* task = (e == 0) ? tr : (e == 1) ? td : tl;
  int i = blk_local * 256 + threadIdx.x;
  if (i < E0) {
    int b = task[i] / R_PART;
    atomicAdd(&c[b], 1);
  }
  __syncthreads();
  int base = (e == 0) ? 0 : (e == 1) ? 16 * NB_RET : 16 * (NB_RET + NB_DRAM);
  if (threadIdx.x < 16) blkcnt_t[base + threadIdx.x * NB + blk_local] = c[threadIdx.x];
}

__global__ __launch_bounds__(1024) void k_ascan(int* __restrict__ blkcnt_t, int* __restrict__ bcnt) {
  __shared__ int sm[1024];
  int gb = blockIdx.x;  // 0..47
  int e = gb >> 4, b = gb & 15;
  int NB = (e == 0) ? NB_RET : (e == 1) ? NB_DRAM : NB_LINK;
  int base = (e == 0) ? 0 : (e == 1) ? 16 * NB_RET : 16 * (NB_RET + NB_DRAM);
  int* arr = blkcnt_t + base + b * NB;
  int carry = 0;
  for (int t0 = 0; t0 < NB; t0 += 1024) {
    int i = t0 + threadIdx.x;
    int v = (i < NB) ? arr[i] : 0;
    sm[threadIdx.x] = v;
    __syncthreads();
    for (int d = 1; d < 1024; d <<= 1) {
      int x = (threadIdx.x >= d) ? sm[threadIdx.x - d] : 0;
      __syncthreads();
      sm[threadIdx.x] += x;
      __syncthreads();
    }
    if (i < NB) arr[i] = carry + sm[threadIdx.x] - v;
    int tot = sm[1023];
    __syncthreads();
    carry += tot;
  }
  if (threadIdx.x == 0) bcnt[gb] = carry;
}

__global__ __launch_bounds__(256) void k_ascatter(
    const int* __restrict__ tr, const int* __restrict__ mr,
    const int* __restrict__ td, const int* __restrict__ md,
    const int* __restrict__ tl, const int* __restrict__ ml,
    const float* __restrict__ s_ret, const float* __restrict__ s_dram,
    const float* __restrict__ s_link, const int* __restrict__ blkcnt_t,
    unsigned long long* __restrict__ trec_ret, unsigned long long* __restrict__ trec_dram,
    unsigned long long* __restrict__ trec_link) {
  __shared__ int lbase[16];
  __shared__ int lc[16];
  int e, blk_local, E0, NB;
  decode_tblk(blockIdx.x, e, blk_local, E0, NB);
  int base = (e == 0) ? 0 : (e == 1) ? 16 * NB_RET : 16 * (NB_RET + NB_DRAM);
  if (threadIdx.x < 16) {
    lbase[threadIdx.x] = blkcnt_t[base + threadIdx.x * NB + blk_local];
    lc[threadIdx.x] = 0;
  }
  __syncthreads();
  const int* task = (e == 0) ? tr : (e == 1) ? td : tl;
  const int* mod = (e == 0) ? mr : (e == 1) ? md : ml;
  const float* s = (e == 0) ? s_ret : (e == 1) ? s_dram : s_link;
  unsigned long long* bkt = (e == 0) ? trec_ret : (e == 1) ? trec_dram : trec_link;
  int CAP = (e == 0) ? CAP_RET : (e == 1) ? CAP_DRAM : CAP_LINK;
  int i = blk_local * 256 + threadIdx.x;
  if (i < E0) {
    int t = task[i];
    int b = t / R_PART;
    unsigned r = (unsigned)(t - b * R_PART);
    unsigned u = ford(s[mod[i]]);
    int slot = lbase[b] + atomicAdd(&lc[b], 1);
    if (slot < CAP)
      bkt[(long)b * CAP + slot] = ((unsigned long long)u << 32) | r;
  }
}

__global__ __launch_bounds__(256) void k_passb(
    const unsigned long long* __restrict__ trec_ret,
    const unsigned long long* __restrict__ trec_dram,
    const unsigned long long* __restrict__ trec_link,
    const int* __restrict__ bcnt, unsigned* __restrict__ partials) {
  __shared__ unsigned lmax[R_PART];
  __shared__ unsigned lmin[R_PART];
  int blk = blockIdx.x;
  int e, b, sub, Nb, PB, CAP;
  const unsigned long long* bkt;
  if (blk < 16 * SUB_RET) {
    e = 0; b = blk >> 2; sub = blk & 3; Nb = SUB_RET; PB = PB_RET; CAP = CAP_RET; bkt = trec_ret;
  } else if (blk < 16 * (SUB_RET + SUB_DRAM)) {
    int q = blk - 16 * SUB_RET;
    e = 1; b = q; sub = 0; Nb = SUB_DRAM; PB = PB_DRAM; CAP = CAP_DRAM; bkt = trec_dram;
  } else {
    int q = blk - 16 * (SUB_RET + SUB_DRAM);
    e = 2; b = q >> 3; sub = q & 7; Nb = SUB_LINK; PB = PB_LINK; CAP = CAP_LINK; bkt = trec_link;
  }
  for (int idx = threadIdx.x; idx < R_PART; idx += 256) {
    lmax[idx] = 0u;
    lmin[idx] = 0xFFFFFFFFu;
  }
  __syncthreads();
  int count = bcnt[e * 16 + b];
  if (count > CAP) count = CAP;
  int chunk = (count + Nb - 1) / Nb;
  int s0 = sub * chunk;
  int s1 = s0 + chunk; if (s1 > count) s1 = count;
  const unsigned long long* p = bkt + (long)b * CAP;
  for (int i = s0 + threadIdx.x; i < s1; i += 256) {
    unsigned long long rec = p[i];
    unsigned r = (unsigned)rec;
    unsigned u = (unsigned)(rec >> 32);
    atomicMax(&lmax[r], u);
    atomicMin(&lmin[r], u);
  }
  __syncthreads();
  unsigned gbase = PB + (unsigned)(b * Nb + sub) * R_PART;
  for (int idx = threadIdx.x; idx < R_PART; idx += 256) {
    partials[gbase + idx] = lmax[idx];
    partials[PB_TOT + gbase + idx] = lmin[idx];
  }
}

__global__ __launch_bounds__(256) void k_mmred2(const unsigned* __restrict__ partials,
                                                unsigned* __restrict__ tmax,
                                                unsigned* __restrict__ tmin) {
  int gid = blockIdx.x * 256 + threadIdx.x;
  if (gid >= 3 * N_TASK) return;
  int e = gid / N_TASK;
  int t = gid - e * N_TASK;
  int Nb = (e == 0) ? SUB_RET : (e == 1) ? SUB_DRAM : SUB_LINK;
  int PB = (e == 0) ? PB_RET : (e == 1) ? PB_DRAM : PB_LINK;
  int b = t / R_PART;
  int r = t - b * R_PART;
  unsigned umax = 0u, umin = 0xFFFFFFFFu;
  for (int sub = 0; sub < Nb; sub++) {
    unsigned idx = PB + (unsigned)(b * Nb + sub) * R_PART + r;
    unsigned w = partials[idx];
    if (w > umax) umax = w;
    unsigned w2 = partials[PB_TOT + idx];
    if (w2 < umin) umin = w2;
  }
  tmax[gid] = umax;
  tmin[gid] = umin;
}

// =================== fallback (small ws): global-atomic path ===================

__global__ void f_segsum(const float* __restrict__ fr, const float* __restrict__ fd,
                         const float* __restrict__ fl,
                         const int* __restrict__ mr, const int* __restrict__ md,
                         const int* __restrict__ ml,
                         float* s_ret, float* s_dram, float* s_link, int* cnt) {
  int i = blockIdx.x * blockDim.x + threadIdx.x;
  const int total = E_RET + E_DRAM + E_LINK;
  if (i >= total) return;
  if (i < E_RET) {
    atomicAdd(&s_ret[mr[i]], fr[i]);
  } else if (i < E_RET + E_DRAM) {
    int j = i - E_RET;
    atomicAdd(&s_dram[md[j]], fd[j]);
  } else {
    int j = i - (E_RET + E_DRAM);
    int m = ml[j];
    atomicAdd(&s_link[m], fl[j]);
    atomicAdd(&cnt[m], 1);
  }
}

__global__ void f_minmax(const float* __restrict__ s_ret, const float* __restrict__ s_dram,
                         const float* __restrict__ s_link,
                         const int* __restrict__ tr, const int* __restrict__ mr,
                         const int* __restrict__ td, const int* __restrict__ md,
                         const int* __restrict__ tl, const int* __restrict__ ml,
                         unsigned* tmax, unsigned* tmin) {
  int i = blockIdx.x * blockDim.x + threadIdx.x;
  const int total = E_RET + E_DRAM + E_LINK;
  if (i >= total) return;
  int e, task; unsigned u;
  if (i < E_RET) {
    u = ford(s_ret[mr[i]]); task = tr[i]; e = 0;
  } else if (i < E_RET + E_DRAM) {
    int j = i - E_RET;
    u = ford(s_dram[md[j]]); task = td[j]; e = 1;
  } else {
    int j = i - (E_RET + E_DRAM);
    u = ford(s_link[ml[j]]); task = tl[j]; e = 2;
  }
  atomicMax(&tmax[e * N_TASK + task], u);
  atomicMin(&tmin[e * N_TASK + task], u);
}

__global__ void f_part(const int* __restrict__ cnt, int* part) {
  __shared__ int sm[256];
  int i = blockIdx.x * 256 + threadIdx.x;
  sm[threadIdx.x] = (i < N_LINK) ? cnt[i] : 0;
  __syncthreads();
  for (int s = 128; s > 0; s >>= 1) {
    if (threadIdx.x < s) sm[threadIdx.x] += sm[threadIdx.x + s];
    __syncthreads();
  }
  if (threadIdx.x == 0) part[blockIdx.x] = sm[0];
}

__global__ void f_scanpart(const int* __restrict__ part, int* partx, int npart) {
  __shared__ int sm[512];
  int t = threadIdx.x;
  int v = (t < npart) ? part[t] : 0;
  sm[t] = v;
  __syncthreads();
  for (int d = 1; d < 512; d <<= 1) {
    int x = (t >= d) ? sm[t - d] : 0;
    __syncthreads();
    sm[t] += x;
    __syncthreads();
  }
  if (t < npart) partx[t] = sm[t] - v;
}

__global__ void f_offs(const int* __restrict__ cnt, const int* __restrict__ partx,
                       int* offs, int* cursor) {
  __shared__ int sm[256];
  int i = blockIdx.x * 256 + threadIdx.x;
  int t = threadIdx.x;
  int v = (i < N_LINK) ? cnt[i] : 0;
  sm[t] = v;
  __syncthreads();
  for (int d = 1; d < 256; d <<= 1) {
    int x = (t >= d) ? sm[t - d] : 0;
    __syncthreads();
    sm[t] += x;
    __syncthreads();
  }
  if (i < N_LINK) {
    int o = partx[blockIdx.x] + sm[t] - v;
    offs[i] = o;
    cursor[i] = o;
  }
}

__global__ void f_scatter(const int* __restrict__ tl, const int* __restrict__ ml,
                          int* cursor, int* csr) {
  int i = blockIdx.x * blockDim.x + threadIdx.x;
  if (i >= E_LINK) return;
  int pos = atomicAdd(&cursor[ml[i]], 1);
  csr[pos] = tl[i];
}

// =================== shared tail: task GEMM + link mean ===================

__global__ __launch_bounds__(64) void k_task(
    const float* __restrict__ W_ret, const float* __restrict__ b_ret,
    const float* __restrict__ W_dram, const float* __restrict__ b_dram,
    const float* __restrict__ W_link, const float* __restrict__ b_link,
    const float* __restrict__ W_task, const float* __restrict__ b_task,
    const unsigned* __restrict__ tmax, const unsigned* __restrict__ tmin,
    unsigned short* __restrict__ hp0, unsigned short* __restrict__ hp1) {
  __shared__ __attribute__((aligned(16))) float hcS[64 * 64];
  __shared__ __attribute__((aligned(16))) float wtS[64 * 64];
  int tid = threadIdx.x;
  int tx = tid & 7, ty = tid >> 3;
  int o0 = tx * 8;
  int tile0 = blockIdx.x * 64;

  float acc[8][8];
#pragma unroll
  for (int i = 0; i < 8; i++)
#pragma unroll
    for (int j = 0; j < 8; j++) acc[i][j] = 0.f;

  const float* We[3] = {W_ret, W_dram, W_link};
  const float* be[3] = {b_ret, b_dram, b_link};

  for (int e = 0; e < 3; e++) {
    for (int idx = tid; idx < 4096; idx += 64) {
      int k = idx >> 6, o = idx & 63;
      wtS[idx] = W_task[o * 192 + e * 64 + k];
    }
    for (int idx = tid; idx < 4096; idx += 64) {
      int t_l = idx >> 6, k = idx & 63;
      int t = tile0 + t_l;
      float hc = 0.f;
      if (t < N_TASK) {
        unsigned um = tmax[e * N_TASK + t];
        if (um != 0u) {
          float smax = funord(um);
          float smin = funord(tmin[e * N_TASK + t]);
          float w = We[e][k];
          float ssel = (w >= 0.f) ? smax : smin;
          hc = tanhf(fmaf(ssel, w, be[e][k]));
        }
      }
      hcS[idx] = hc;
    }
    __syncthreads();
#pragma unroll
    for (int k4 = 0; k4 < 16; k4++) {
      int k = k4 * 4;
      float4 hv[8];
#pragma unroll
      for (int i = 0; i < 8; i++) hv[i] = *(const float4*)&hcS[(ty * 8 + i) * 64 + k];
      float wv[4][8];
#pragma unroll
      for (int dk = 0; dk < 4; dk++) {
        float4 a = *(const float4*)&wtS[(k + dk) * 64 + o0];
        float4 b = *(const float4*)&wtS[(k + dk) * 64 + o0 + 4];
        wv[dk][0] = a.x; wv[dk][1] = a.y; wv[dk][2] = a.z; wv[dk][3] = a.w;
        wv[dk][4] = b.x; wv[dk][5] = b.y; wv[dk][6] = b.z; wv[dk][7] = b.w;
      }
#pragma unroll
      for (int i = 0; i < 8; i++) {
        float hvv[4] = {hv[i].x, hv[i].y, hv[i].z, hv[i].w};
#pragma unroll
        for (int dk = 0; dk < 4; dk++)
#pragma unroll
          for (int j = 0; j < 8; j++)
            acc[i][j] = fmaf(hvv[dk], wv[dk][j], acc[i][j]);
      }
    }
    __syncthreads();
  }

  // epilogue: tanh + bf16, write to feature planes (o0 multiple of 8 -> single plane)
  unsigned short* hp = (o0 < 32) ? hp0 : hp1;
  int f0 = o0 & 31;
#pragma unroll
  for (int i = 0; i < 8; i++) {
    int t = tile0 + ty * 8 + i;
    if (t < N_TASK) {
#pragma unroll
      for (int g = 0; g < 2; g++) {
        ushort4 r;
        unsigned short rr[4];
#pragma unroll
        for (int j = 0; j < 4; j++) {
          float v = tanhf(acc[i][g * 4 + j] + b_task[o0 + g * 4 + j]);
          unsigned u = __float_as_uint(v);
          rr[j] = (unsigned short)((u + 0x7fffu + ((u >> 16) & 1u)) >> 16);
        }
        r.x = rr[0]; r.y = rr[1]; r.z = rr[2]; r.w = rr[3];
        *(ushort4*)&hp[t * 32 + f0 + g * 4] = r;
      }
    }
  }
}

// per-link mean over one 32-feature plane; half-wave per link, 4-way MLP unroll.
// Plane = 3.2MB < 4MB per-XCD L2 -> gather becomes L2-resident.
__global__ __launch_bounds__(256) void k_link2(const unsigned short* __restrict__ hp,
                                               const int* __restrict__ offs,
                                               const int* __restrict__ cnt,
                                               const int* __restrict__ csr,
                                               float* __restrict__ out, int plane) {
  int l = blockIdx.x * 8 + (threadIdx.x >> 5);  // 12500*8 == N_LINK
  int f = threadIdx.x & 31;
  int start = offs[l];
  int c = cnt[l];
  float acc = 0.f;
  for (int q = 0; q < c; q += 4) {
    int i1 = (q + 1 < c) ? q + 1 : c - 1;
    int i2 = (q + 2 < c) ? q + 2 : c - 1;
    int i3 = (q + 3 < c) ? q + 3 : c - 1;
    int t0 = csr[start + q];
    int t1 = csr[start + i1];
    int t2 = csr[start + i2];
    int t3 = csr[start + i3];
    unsigned v0 = hp[t0 * 32 + f];
    unsigned v1 = hp[t1 * 32 + f];
    unsigned v2 = hp[t2 * 32 + f];
    unsigned v3 = hp[t3 * 32 + f];
    acc += __uint_as_float(v0 << 16);
    if (q + 1 < c) acc += __uint_as_float(v1 << 16);
    if (q + 2 < c) acc += __uint_as_float(v2 << 16);
    if (q + 3 < c) acc += __uint_as_float(v3 << 16);
  }
  out[l * 64 + plane * 32 + f] = (c > 0) ? acc / (float)c : 0.f;
}

extern "C" void kernel_launch(void* const* d_in, const int* in_sizes, int n_in,
                              void* d_out, int out_size, void* d_ws, size_t ws_size,
                              hipStream_t stream) {
  const float* feat_ret  = (const float*)d_in[0];
  const float* feat_dram = (const float*)d_in[1];
  const float* feat_link = (const float*)d_in[2];
  const float* W_ret  = (const float*)d_in[3];
  const float* b_ret  = (const float*)d_in[4];
  const float* W_dram = (const float*)d_in[5];
  const float* b_dram = (const float*)d_in[6];
  const float* W_link = (const float*)d_in[7];
  const float* b_link = (const float*)d_in[8];
  const float* W_task = (const float*)d_in[9];
  const float* b_task = (const float*)d_in[10];
  const int* task_ret  = (const int*)d_in[11];
  const int* mod_ret   = (const int*)d_in[12];
  const int* task_dram = (const int*)d_in[13];
  const int* mod_dram  = (const int*)d_in[14];
  const int* task_link = (const int*)d_in[15];
  const int* mod_link  = (const int*)d_in[16];
  float* out = (float*)d_out;

  char* ws = (char*)d_ws;
  float* s_ret  = (float*)(ws + WS_SRET);
  float* s_dram = (float*)(ws + WS_SDRAM);
  float* s_link = (float*)(ws + WS_SLINK);
  int*   cnt    = (int*)(ws + WS_CNT);
  int*   offs   = (int*)(ws + WS_OFFS);
  unsigned* tmax = (unsigned*)(ws + WS_TMAX);
  unsigned* tmin = (unsigned*)(ws + WS_TMIN);
  int* bcnt = (int*)(ws + WS_BCNT);
  int* rcnt = (int*)(ws + WS_RCNT);
  int* csr  = (int*)(ws + WS_CSR);
  int* blkcnt_m = (int*)(ws + WS_BLKM);
  int* blkcnt_t = (int*)(ws + WS_BLKT);
  unsigned* partials = (unsigned*)(ws + WS_PARTIALS);
  unsigned long long* mrec_ret  = (unsigned long long*)(ws + WS_MREC_RET);
  unsigned long long* mrec_dram = (unsigned long long*)(ws + WS_MREC_DRAM);
  unsigned long long* mrec_link = (unsigned long long*)(ws + WS_MREC_LINK);
  unsigned long long* trec_ret  = (unsigned long long*)(ws + WS_TREC_RET);
  unsigned long long* trec_dram = (unsigned long long*)(ws + WS_TREC_DRAM);
  unsigned long long* trec_link = (unsigned long long*)(ws + WS_TREC_LINK);
  unsigned short* hp0 = (unsigned short*)(ws + WS_HPL0);
  unsigned short* hp1 = (unsigned short*)(ws + WS_HPL1);

  if (ws_size >= (size_t)WS_NEED) {
    // ---- atomic-free main path ----
    k_m0<<<NBM_TOT, 256, 0, stream>>>(mod_ret, mod_dram, mod_link, blkcnt_m);
    k_mscan<<<MR_RET + MR_DRAM + MR_LINK, 1024, 0, stream>>>(blkcnt_m, rcnt);
    k_mscatter<<<NBM_TOT, 256, 0, stream>>>(mod_ret, mod_dram, mod_link, task_link,
                                            feat_ret, feat_dram, feat_link, blkcnt_m,
                                            mrec_ret, mrec_dram, mrec_link);
    k_msum<<<MR_RET + MR_DRAM + MR_LINK, 256, 0, stream>>>(
        mrec_ret, mrec_dram, mrec_link, rcnt, s_ret, s_dram, s_link, cnt, offs, csr);
    const int nblkT = NB_RET + NB_DRAM + NB_LINK;  // 12697
    k_a0<<<nblkT, 256, 0, stream>>>(task_ret, task_dram, task_link, blkcnt_t);
    k_ascan<<<48, 1024, 0, stream>>>(blkcnt_t, bcnt);
    k_ascatter<<<nblkT, 256, 0, stream>>>(task_ret, mod_ret, task_dram, mod_dram,
                                          task_link, mod_link, s_ret, s_dram, s_link,
                                          blkcnt_t, trec_ret, trec_dram, trec_link);
    k_passb<<<16 * (SUB_RET + SUB_DRAM + SUB_LINK), 256, 0, stream>>>(
        trec_ret, trec_dram, trec_link, bcnt, partials);
    k_mmred2<<<(3 * N_TASK + 255) / 256, 256, 0, stream>>>(partials, tmax, tmin);
  } else {
    // ---- fallback: global-atomic path ----
    int* part   = (int*)(ws + WS_BLKM);
    int* partx  = (int*)(ws + WS_BLKM + 4096);
    int* cursor = (int*)(ws + WS_BLKT);
    hipMemsetAsync(ws, 0, 1900000, stream);                 // s/cnt/offs/tmax
    hipMemsetAsync(ws + WS_TMIN, 0xFF, 600000, stream);     // tmin
    const int totalE = E_RET + E_DRAM + E_LINK;
    int nblk_e = (totalE + 255) / 256;
    f_segsum<<<nblk_e, 256, 0, stream>>>(feat_ret, feat_dram, feat_link,
                                         mod_ret, mod_dram, mod_link,
                                         s_ret, s_dram, s_link, cnt);
    f_minmax<<<nblk_e, 256, 0, stream>>>(s_ret, s_dram, s_link,
                                         task_ret, mod_ret, task_dram, mod_dram,
                                         task_link, mod_link, tmax, tmin);
    const int npart = (N_LINK + 255) / 256;  // 391
    f_part<<<npart, 256, 0, stream>>>(cnt, part);
    f_scanpart<<<1, 512, 0, stream>>>(part, partx, npart);
    f_offs<<<npart, 256, 0, stream>>>(cnt, partx, offs, cursor);
    f_scatter<<<(E_LINK + 255) / 256, 256, 0, stream>>>(task_link, mod_link, cursor, csr);
  }

  k_task<<<(N_TASK + 63) / 64, 64, 0, stream>>>(W_ret, b_ret, W_dram, b_dram,
                                                W_link, b_link, W_task, b_task,
                                                tmax, tmin, hp0, hp1);
  k_link2<<<N_LINK / 8, 256, 0, stream>>>(hp0, offs, cnt, csr, out, 0);
  k_link2<<<N_LINK / 8, 256, 0, stream>>>(hp1, offs, cnt, csr, out, 1);
}

// Round 6
// 378.055 us; speedup vs baseline: 3.2918x; 1.2261x over previous
//
#include <hip/hip_runtime.h>
#include <stdint.h>

#define N_TASK 50000
#define N_RET 20000
#define N_DRAM 5000
#define N_LINK 100000
#define E_RET 1000000
#define E_DRAM 250000
#define E_LINK 2000000

// ---- module-range bucketing (segment sums + CSR, zero global atomics) ----
#define MBE 1024                // edges per m-block
#define NBM_RET 977
#define NBM_DRAM 245
#define NBM_LINK 1954
#define NBM_TOT (NBM_RET + NBM_DRAM + NBM_LINK)   // 3176
#define MR_RET 64
#define RSZ_RET 313             // 64*313 = 20032 >= 20000
#define MR_DRAM 16
#define RSZ_DRAM 313            // 16*313 = 5008 >= 5000
#define MR_LINK 256
#define RSZ_LINK 391            // 256*391 = 100096 >= 100000
#define RECIP313 107203u        // ceil(2^25/313); exact div for m < 313k
#define RECIP391 85817u         // ceil(2^25/391); exact div for m < 2.2M
#define CAPM_RET 16250          // mean 15625, +5σ
#define CAPM_DRAM 16250
#define CAPM_LINK 8255          // mean 7813, +5σ
#define BM_RET 0                // blkcnt_m element offsets
#define BM_DRAM (MR_RET * NBM_RET)                  // 62528
#define BM_LINK (BM_DRAM + MR_DRAM * NBM_DRAM)      // 66448
#define BM_TOT (BM_LINK + MR_LINK * NBM_LINK)       // 566672

// ---- task-range bucketing (per-task min/max) ----
#define R_PART 3125             // 16*3125 == N_TASK
#define NB_RET 3907             // 256-edge blocks
#define NB_DRAM 977
#define NB_LINK 7813
#define CAP_RET 63800           // mean 62500, +5σ
#define CAP_DRAM 16300
#define CAP_LINK 126800
#define SUB_RET 4
#define SUB_DRAM 1
#define SUB_LINK 8
#define PB_RET 0
#define PB_DRAM (16 * SUB_RET * R_PART)             // 200000
#define PB_LINK (PB_DRAM + 16 * SUB_DRAM * R_PART)  // 250000
#define PB_TOT (PB_LINK + 16 * SUB_LINK * R_PART)   // 650000 words per plane

// ---- workspace byte offsets ----
#define WS_SRET 0               // 20000 f
#define WS_SDRAM 80000          // 5000 f
#define WS_SLINK 100000         // 100000 f
#define WS_CNT 500000           // 100000 i
#define WS_OFFS 900000          // 100000 i
#define WS_TMAX 1300000         // 150000 u
#define WS_TMIN 1900000         // 150000 u
#define WS_BCNT 2500000         // 48 i
#define WS_RCNT 2500192         // 336 i
#define WS_CSR 2501536          // 2M i -> ends 10501536
// counts region [10501536, 15701536): blkcnt_m, blkcnt_t, then partials
#define WS_BLKM 10501536        // 566672 i (dead after k_mscatter)
#define WS_BLKT 12768224        // 203152 i (dead after k_ascatter)
#define WS_PARTIALS 10501536    // 2*650000 u (written by k_passb, after both dead)
// records union [15701536, 43007776):
#define WS_MREC_RET 15701536    // 64*16250*8  -> 24021536
#define WS_MREC_DRAM 24021536   // 16*16250*8  -> 26101536
#define WS_MREC_LINK 26101536   // 256*8255*8  -> 43007776
#define WS_TREC_RET 15701536    // 16*63800*8  -> 23867936 (after mrec dead)
#define WS_TREC_DRAM 23867936   // 16*16300*8  -> 25954336
#define WS_TREC_LINK 25954336   // 16*126800*8 -> 42184736
// h_task split into two feature planes (3.2MB each, < 4MB per-XCD L2)
#define WS_HPL0 15701536        // 50000*32 u16 -> 18901536 (after trec dead)
#define WS_HPL1 18901536        // 50000*32 u16 -> 22101536
#define WS_WTB  22101536        // 12288 u16 bf16 W_task (written after trec dead)
#define WS_NEED 43007776

typedef __attribute__((ext_vector_type(8))) short bf16x8;
typedef __attribute__((ext_vector_type(4))) float f32x4;

// ---- order-preserving float<->uint (min/max as uint); 0 / 0xFFFFFFFF unreachable ----
__device__ __forceinline__ unsigned ford(float f) {
  unsigned u = __float_as_uint(f);
  return (u & 0x80000000u) ? ~u : (u | 0x80000000u);
}
__device__ __forceinline__ float funord(unsigned t) {
  unsigned u = (t & 0x80000000u) ? (t & 0x7fffffffu) : ~t;
  return __uint_as_float(u);
}
__device__ __forceinline__ unsigned short bf16rne(float f) {
  unsigned u = __float_as_uint(f);
  return (unsigned short)((u + 0x7fffu + ((u >> 16) & 1u)) >> 16);
}

// =================== module-bucket pipeline ===================

__device__ __forceinline__ void decode_mblk(int bx, int& e, int& blk, int& E0, int& NB,
                                            int& NR, unsigned& RECIP, int& RSZ, int& base) {
  if (bx < NBM_RET) {
    e = 0; blk = bx; E0 = E_RET; NB = NBM_RET; NR = MR_RET; RECIP = RECIP313; RSZ = RSZ_RET; base = BM_RET;
  } else if (bx < NBM_RET + NBM_DRAM) {
    e = 1; blk = bx - NBM_RET; E0 = E_DRAM; NB = NBM_DRAM; NR = MR_DRAM; RECIP = RECIP313; RSZ = RSZ_DRAM; base = BM_DRAM;
  } else {
    e = 2; blk = bx - NBM_RET - NBM_DRAM; E0 = E_LINK; NB = NBM_LINK; NR = MR_LINK; RECIP = RECIP391; RSZ = RSZ_LINK; base = BM_LINK;
  }
}

// count per (m-block, module-range)
__global__ __launch_bounds__(256) void k_m0(const int* __restrict__ mr, const int* __restrict__ md,
                                            const int* __restrict__ ml, int* __restrict__ blkcnt_m) {
  __shared__ int c[256];
  int e, blk, E0, NB, NR, RSZ, base; unsigned RECIP;
  decode_mblk(blockIdx.x, e, blk, E0, NB, NR, RECIP, RSZ, base);
  const int* mod = (e == 0) ? mr : (e == 1) ? md : ml;
  c[threadIdx.x] = 0;
  __syncthreads();
  int i0 = blk * MBE;
#pragma unroll
  for (int q = 0; q < 4; q++) {
    int i = i0 + q * 256 + threadIdx.x;
    if (i < E0) {
      int m = mod[i];
      int r = (int)(((unsigned long long)(unsigned)m * RECIP) >> 25);
      atomicAdd(&c[r], 1);
    }
  }
  __syncthreads();
  for (int r = threadIdx.x; r < NR; r += 256)
    blkcnt_m[base + r * NB + blk] = c[r];
}

// exclusive scan per range over m-blocks (in place); totals -> rcnt[336]
__global__ __launch_bounds__(1024) void k_mscan(int* __restrict__ blkcnt_m, int* __restrict__ rcnt) {
  __shared__ int sm[1024];
  int gb = blockIdx.x;
  int NB, base, rl;
  if (gb < MR_RET) { rl = gb; NB = NBM_RET; base = BM_RET; }
  else if (gb < MR_RET + MR_DRAM) { rl = gb - MR_RET; NB = NBM_DRAM; base = BM_DRAM; }
  else { rl = gb - MR_RET - MR_DRAM; NB = NBM_LINK; base = BM_LINK; }
  int* arr = blkcnt_m + base + rl * NB;
  int carry = 0;
  for (int t0 = 0; t0 < NB; t0 += 1024) {
    int i = t0 + threadIdx.x;
    int v = (i < NB) ? arr[i] : 0;
    sm[threadIdx.x] = v;
    __syncthreads();
    for (int d = 1; d < 1024; d <<= 1) {
      int x = (threadIdx.x >= d) ? sm[threadIdx.x - d] : 0;
      __syncthreads();
      sm[threadIdx.x] += x;
      __syncthreads();
    }
    if (i < NB) arr[i] = carry + sm[threadIdx.x] - v;
    int tot = sm[1023];
    __syncthreads();
    carry += tot;
  }
  if (threadIdx.x == 0) rcnt[gb] = carry;
}

// scatter records (feat32|task16|mloc16) to exact module-bucket slots
__global__ __launch_bounds__(256) void k_mscatter(
    const int* __restrict__ mr, const int* __restrict__ md, const int* __restrict__ ml,
    const int* __restrict__ tl,
    const float* __restrict__ fr, const float* __restrict__ fd, const float* __restrict__ fl,
    const int* __restrict__ blkcnt_m,
    unsigned long long* __restrict__ mrec_ret, unsigned long long* __restrict__ mrec_dram,
    unsigned long long* __restrict__ mrec_link) {
  __shared__ int lb[256];
  __shared__ int lc[256];
  int e, blk, E0, NB, NR, RSZ, base; unsigned RECIP;
  decode_mblk(blockIdx.x, e, blk, E0, NB, NR, RECIP, RSZ, base);
  const int* mod = (e == 0) ? mr : (e == 1) ? md : ml;
  const float* feat = (e == 0) ? fr : (e == 1) ? fd : fl;
  unsigned long long* out = (e == 0) ? mrec_ret : (e == 1) ? mrec_dram : mrec_link;
  int CAP = (e == 0) ? CAPM_RET : (e == 1) ? CAPM_DRAM : CAPM_LINK;
  for (int r = threadIdx.x; r < NR; r += 256) {
    lb[r] = blkcnt_m[base + r * NB + blk];
    lc[r] = 0;
  }
  __syncthreads();
  int i0 = blk * MBE;
#pragma unroll
  for (int q = 0; q < 4; q++) {
    int i = i0 + q * 256 + threadIdx.x;
    if (i < E0) {
      int m = mod[i];
      int r = (int)(((unsigned long long)(unsigned)m * RECIP) >> 25);
      unsigned mloc = (unsigned)(m - r * RSZ);
      unsigned task = (e == 2) ? (unsigned)tl[i] : 0u;
      unsigned fu = __float_as_uint(feat[i]);
      int slot = lb[r] + atomicAdd(&lc[r], 1);
      if (slot < CAP)
        out[(long)r * CAP + slot] = ((unsigned long long)fu << 32) | (task << 16) | mloc;
    }
  }
}

// per-range: LDS sums -> s_*; link also cnt/offs/CSR. No global atomics anywhere.
__global__ __launch_bounds__(256) void k_msum(
    const unsigned long long* __restrict__ mrec_ret,
    const unsigned long long* __restrict__ mrec_dram,
    const unsigned long long* __restrict__ mrec_link,
    const int* __restrict__ rcnt,
    float* __restrict__ s_ret, float* __restrict__ s_dram, float* __restrict__ s_link,
    int* __restrict__ cnt, int* __restrict__ offs, int* __restrict__ csr) {
  __shared__ float ssum[RSZ_LINK];
  __shared__ int scnt[RSZ_LINK];
  __shared__ int soff[RSZ_LINK + 1];
  __shared__ int red[256];
  int gb = blockIdx.x, tid = threadIdx.x;
  int e, rl, RSZ, CAP, Ntot;
  const unsigned long long* p;
  float* sout;
  if (gb < MR_RET) {
    e = 0; rl = gb; p = mrec_ret + (long)rl * CAPM_RET; sout = s_ret;
    RSZ = RSZ_RET; CAP = CAPM_RET; Ntot = N_RET;
  } else if (gb < MR_RET + MR_DRAM) {
    e = 1; rl = gb - MR_RET; p = mrec_dram + (long)rl * CAPM_DRAM; sout = s_dram;
    RSZ = RSZ_DRAM; CAP = CAPM_DRAM; Ntot = N_DRAM;
  } else {
    e = 2; rl = gb - MR_RET - MR_DRAM; p = mrec_link + (long)rl * CAPM_LINK; sout = s_link;
    RSZ = RSZ_LINK; CAP = CAPM_LINK; Ntot = N_LINK;
  }
  int m0 = rl * RSZ;
  int nmod = Ntot - m0; if (nmod > RSZ) nmod = RSZ;
  for (int j = tid; j < RSZ; j += 256) { ssum[j] = 0.f; scnt[j] = 0; }
  __syncthreads();
  int count = rcnt[gb]; if (count > CAP) count = CAP;
  for (int i = tid; i < count; i += 256) {
    unsigned long long rec = p[i];
    int mloc = (int)(rec & 0xFFFFull);
    atomicAdd(&ssum[mloc], __uint_as_float((unsigned)(rec >> 32)));
    if (e == 2) atomicAdd(&scnt[mloc], 1);
  }
  __syncthreads();
  for (int j = tid; j < nmod; j += 256) sout[m0 + j] = ssum[j];
  if (e != 2) return;
  // global range base = sum of preceding link-range totals (gb-80 <= 255)
  int partial = (80 + tid < gb) ? rcnt[80 + tid] : 0;
  red[tid] = partial;
  __syncthreads();
  for (int s = 128; s > 0; s >>= 1) {
    if (tid < s) red[tid] += red[tid + s];
    __syncthreads();
  }
  int rb = red[0];
  __syncthreads();
  // exclusive scan of scnt[0..nmod) -> soff (2 elems/thread)
  int a0 = (2 * tid < nmod) ? scnt[2 * tid] : 0;
  int a1 = (2 * tid + 1 < nmod) ? scnt[2 * tid + 1] : 0;
  red[tid] = a0 + a1;
  __syncthreads();
  for (int d = 1; d < 256; d <<= 1) {
    int x = (tid >= d) ? red[tid - d] : 0;
    __syncthreads();
    red[tid] += x;
    __syncthreads();
  }
  int excl = red[tid] - (a0 + a1);
  if (2 * tid < RSZ_LINK) soff[2 * tid] = excl;
  if (2 * tid + 1 < RSZ_LINK) soff[2 * tid + 1] = excl + a0;
  __syncthreads();
  for (int j = tid; j < nmod; j += 256) {
    cnt[m0 + j] = scnt[j];
    offs[m0 + j] = rb + soff[j];
  }
  __syncthreads();
  // CSR emission via LDS cursors (soff becomes cursor)
  for (int i = tid; i < count; i += 256) {
    unsigned long long rec = p[i];
    int mloc = (int)(rec & 0xFFFFull);
    int task = (int)((rec >> 16) & 0xFFFFull);
    int lp = atomicAdd(&soff[mloc], 1);
    csr[rb + lp] = task;
  }
}

// =================== task-bucket min/max pipeline ===================

__device__ __forceinline__ void decode_tblk(int blk, int& e, int& blk_local, int& E0, int& NB) {
  if (blk < NB_RET) { e = 0; blk_local = blk; E0 = E_RET; NB = NB_RET; }
  else if (blk < NB_RET + NB_DRAM) { e = 1; blk_local = blk - NB_RET; E0 = E_DRAM; NB = NB_DRAM; }
  else { e = 2; blk_local = blk - NB_RET - NB_DRAM; E0 = E_LINK; NB = NB_LINK; }
}

__global__ __launch_bounds__(256) void k_a0(const int* __restrict__ tr,
                                            const int* __restrict__ td,
                                            const int* __restrict__ tl,
                                            int* __restrict__ blkcnt_t) {
  __shared__ int c[16];
  if (threadIdx.x < 16) c[threadIdx.x] = 0;
  __syncthreads();
  int e, blk_local, E0, NB;
  decode_tblk(blockIdx.x, e, blk_local, E0, NB);
  const int* task = (e == 0) ? tr : (e == 1) ? td : tl;
  int i = blk_local * 256 + threadIdx.x;
  if (i < E0) {
    int b = task[i] / R_PART;
    atomicAdd(&c[b], 1);
  }
  __syncthreads();
  int base = (e == 0) ? 0 : (e == 1) ? 16 * NB_RET : 16 * (NB_RET + NB_DRAM);
  if (threadIdx.x < 16) blkcnt_t[base + threadIdx.x * NB + blk_local] = c[threadIdx.x];
}

__global__ __launch_bounds__(1024) void k_ascan(int* __restrict__ blkcnt_t, int* __restrict__ bcnt) {
  __shared__ int sm[1024];
  int gb = blockIdx.x;  // 0..47
  int e = gb >> 4, b = gb & 15;
  int NB = (e == 0) ? NB_RET : (e == 1) ? NB_DRAM : NB_LINK;
  int base = (e == 0) ? 0 : (e == 1) ? 16 * NB_RET : 16 * (NB_RET + NB_DRAM);
  int* arr = blkcnt_t + base + b * NB;
  int carry = 0;
  for (int t0 = 0; t0 < NB; t0 += 1024) {
    int i = t0 + threadIdx.x;
    int v = (i < NB) ? arr[i] : 0;
    sm[threadIdx.x] = v;
    __syncthreads();
    for (int d = 1; d < 1024; d <<= 1) {
      int x = (threadIdx.x >= d) ? sm[threadIdx.x - d] : 0;
      __syncthreads();
      sm[threadIdx.x] += x;
      __syncthreads();
    }
    if (i < NB) arr[i] = carry + sm[threadIdx.x] - v;
    int tot = sm[1023];
    __syncthreads();
    carry += tot;
  }
  if (threadIdx.x == 0) bcnt[gb] = carry;
}

__global__ __launch_bounds__(256) void k_ascatter(
    const int* __restrict__ tr, const int* __restrict__ mr,
    const int* __restrict__ td, const int* __restrict__ md,
    const int* __restrict__ tl, const int* __restrict__ ml,
    const float* __restrict__ s_ret, const float* __restrict__ s_dram,
    const float* __restrict__ s_link, const int* __restrict__ blkcnt_t,
    unsigned long long* __restrict__ trec_ret, unsigned long long* __restrict__ trec_dram,
    unsigned long long* __restrict__ trec_link) {
  __shared__ int lbase[16];
  __shared__ int lc[16];
  int e, blk_local, E0, NB;
  decode_tblk(blockIdx.x, e, blk_local, E0, NB);
  int base = (e == 0) ? 0 : (e == 1) ? 16 * NB_RET : 16 * (NB_RET + NB_DRAM);
  if (threadIdx.x < 16) {
    lbase[threadIdx.x] = blkcnt_t[base + threadIdx.x * NB + blk_local];
    lc[threadIdx.x] = 0;
  }
  __syncthreads();
  const int* task = (e == 0) ? tr : (e == 1) ? td : tl;
  const int* mod = (e == 0) ? mr : (e == 1) ? md : ml;
  const float* s = (e == 0) ? s_ret : (e == 1) ? s_dram : s_link;
  unsigned long long* bkt = (e == 0) ? trec_ret : (e == 1) ? trec_dram : trec_link;
  int CAP = (e == 0) ? CAP_RET : (e == 1) ? CAP_DRAM : CAP_LINK;
  int i = blk_local * 256 + threadIdx.x;
  if (i < E0) {
    int t = task[i];
    int b = t / R_PART;
    unsigned r = (unsigned)(t - b * R_PART);
    unsigned u = ford(s[mod[i]]);
    int slot = lbase[b] + atomicAdd(&lc[b], 1);
    if (slot < CAP)
      bkt[(long)b * CAP + slot] = ((unsigned long long)u << 32) | r;
  }
}

__global__ __launch_bounds__(256) void k_passb(
    const unsigned long long* __restrict__ trec_ret,
    const unsigned long long* __restrict__ trec_dram,
    const unsigned long long* __restrict__ trec_link,
    const int* __restrict__ bcnt, unsigned* __restrict__ partials) {
  __shared__ unsigned lmax[R_PART];
  __shared__ unsigned lmin[R_PART];
  int blk = blockIdx.x;
  int e, b, sub, Nb, PB, CAP;
  const unsigned long long* bkt;
  if (blk < 16 * SUB_RET) {
    e = 0; b = blk >> 2; sub = blk & 3; Nb = SUB_RET; PB = PB_RET; CAP = CAP_RET; bkt = trec_ret;
  } else if (blk < 16 * (SUB_RET + SUB_DRAM)) {
    int q = blk - 16 * SUB_RET;
    e = 1; b = q; sub = 0; Nb = SUB_DRAM; PB = PB_DRAM; CAP = CAP_DRAM; bkt = trec_dram;
  } else {
    int q = blk - 16 * (SUB_RET + SUB_DRAM);
    e = 2; b = q >> 3; sub = q & 7; Nb = SUB_LINK; PB = PB_LINK; CAP = CAP_LINK; bkt = trec_link;
  }
  for (int idx = threadIdx.x; idx < R_PART; idx += 256) {
    lmax[idx] = 0u;
    lmin[idx] = 0xFFFFFFFFu;
  }
  __syncthreads();
  int count = bcnt[e * 16 + b];
  if (count > CAP) count = CAP;
  int chunk = (count + Nb - 1) / Nb;
  int s0 = sub * chunk;
  int s1 = s0 + chunk; if (s1 > count) s1 = count;
  const unsigned long long* p = bkt + (long)b * CAP;
  for (int i = s0 + threadIdx.x; i < s1; i += 256) {
    unsigned long long rec = p[i];
    unsigned r = (unsigned)rec;
    unsigned u = (unsigned)(rec >> 32);
    atomicMax(&lmax[r], u);
    atomicMin(&lmin[r], u);
  }
  __syncthreads();
  unsigned gbase = PB + (unsigned)(b * Nb + sub) * R_PART;
  for (int idx = threadIdx.x; idx < R_PART; idx += 256) {
    partials[gbase + idx] = lmax[idx];
    partials[PB_TOT + gbase + idx] = lmin[idx];
  }
}

__global__ __launch_bounds__(256) void k_mmred2(const unsigned* __restrict__ partials,
                                                unsigned* __restrict__ tmax,
                                                unsigned* __restrict__ tmin) {
  int gid = blockIdx.x * 256 + threadIdx.x;
  if (gid >= 3 * N_TASK) return;
  int e = gid / N_TASK;
  int t = gid - e * N_TASK;
  int Nb = (e == 0) ? SUB_RET : (e == 1) ? SUB_DRAM : SUB_LINK;
  int PB = (e == 0) ? PB_RET : (e == 1) ? PB_DRAM : PB_LINK;
  int b = t / R_PART;
  int r = t - b * R_PART;
  unsigned umax = 0u, umin = 0xFFFFFFFFu;
  for (int sub = 0; sub < Nb; sub++) {
    unsigned idx = PB + (unsigned)(b * Nb + sub) * R_PART + r;
    unsigned w = partials[idx];
    if (w > umax) umax = w;
    unsigned w2 = partials[PB_TOT + idx];
    if (w2 < umin) umin = w2;
  }
  tmax[gid] = umax;
  tmin[gid] = umin;
}

// =================== fallback (small ws): global-atomic path ===================

__global__ void f_segsum(const float* __restrict__ fr, const float* __restrict__ fd,
                         const float* __restrict__ fl,
                         const int* __restrict__ mr, const int* __restrict__ md,
                         const int* __restrict__ ml,
                         float* s_ret, float* s_dram, float* s_link, int* cnt) {
  int i = blockIdx.x * blockDim.x + threadIdx.x;
  const int total = E_RET + E_DRAM + E_LINK;
  if (i >= total) return;
  if (i < E_RET) {
    atomicAdd(&s_ret[mr[i]], fr[i]);
  } else if (i < E_RET + E_DRAM) {
    int j = i - E_RET;
    atomicAdd(&s_dram[md[j]], fd[j]);
  } else {
    int j = i - (E_RET + E_DRAM);
    int m = ml[j];
    atomicAdd(&s_link[m], fl[j]);
    atomicAdd(&cnt[m], 1);
  }
}

__global__ void f_minmax(const float* __restrict__ s_ret, const float* __restrict__ s_dram,
                         const float* __restrict__ s_link,
                         const int* __restrict__ tr, const int* __restrict__ mr,
                         const int* __restrict__ td, const int* __restrict__ md,
                         const int* __restrict__ tl, const int* __restrict__ ml,
                         unsigned* tmax, unsigned* tmin) {
  int i = blockIdx.x * blockDim.x + threadIdx.x;
  const int total = E_RET + E_DRAM + E_LINK;
  if (i >= total) return;
  int e, task; unsigned u;
  if (i < E_RET) {
    u = ford(s_ret[mr[i]]); task = tr[i]; e = 0;
  } else if (i < E_RET + E_DRAM) {
    int j = i - E_RET;
    u = ford(s_dram[md[j]]); task = td[j]; e = 1;
  } else {
    int j = i - (E_RET + E_DRAM);
    u = ford(s_link[ml[j]]); task = tl[j]; e = 2;
  }
  atomicMax(&tmax[e * N_TASK + task], u);
  atomicMin(&tmin[e * N_TASK + task], u);
}

__global__ void f_part(const int* __restrict__ cnt, int* part) {
  __shared__ int sm[256];
  int i = blockIdx.x * 256 + threadIdx.x;
  sm[threadIdx.x] = (i < N_LINK) ? cnt[i] : 0;
  __syncthreads();
  for (int s = 128; s > 0; s >>= 1) {
    if (threadIdx.x < s) sm[threadIdx.x] += sm[threadIdx.x + s];
    __syncthreads();
  }
  if (threadIdx.x == 0) part[blockIdx.x] = sm[0];
}

__global__ void f_scanpart(const int* __restrict__ part, int* partx, int npart) {
  __shared__ int sm[512];
  int t = threadIdx.x;
  int v = (t < npart) ? part[t] : 0;
  sm[t] = v;
  __syncthreads();
  for (int d = 1; d < 512; d <<= 1) {
    int x = (t >= d) ? sm[t - d] : 0;
    __syncthreads();
    sm[t] += x;
    __syncthreads();
  }
  if (t < npart) partx[t] = sm[t] - v;
}

__global__ void f_offs(const int* __restrict__ cnt, const int* __restrict__ partx,
                       int* offs, int* cursor) {
  __shared__ int sm[256];
  int i = blockIdx.x * 256 + threadIdx.x;
  int t = threadIdx.x;
  int v = (i < N_LINK) ? cnt[i] : 0;
  sm[t] = v;
  __syncthreads();
  for (int d = 1; d < 256; d <<= 1) {
    int x = (t >= d) ? sm[t - d] : 0;
    __syncthreads();
    sm[t] += x;
    __syncthreads();
  }
  if (i < N_LINK) {
    int o = partx[blockIdx.x] + sm[t] - v;
    offs[i] = o;
    cursor[i] = o;
  }
}

__global__ void f_scatter(const int* __restrict__ tl, const int* __restrict__ ml,
                          int* cursor, int* csr) {
  int i = blockIdx.x * blockDim.x + threadIdx.x;
  if (i >= E_LINK) return;
  int pos = atomicAdd(&cursor[ml[i]], 1);
  csr[pos] = tl[i];
}

// =================== shared tail: task GEMM (MFMA) + link mean ===================

// W_task fp32 [64][192] -> bf16 [64][192]
__global__ void k_wprep(const float* __restrict__ W_task, unsigned short* __restrict__ wtb) {
  int i = blockIdx.x * 256 + threadIdx.x;
  if (i < 64 * 192) wtb[i] = bf16rne(W_task[i]);
}

// One wave per 16 tasks; 4 MFMA n-frags (64 outs), K=192 via 6 x mfma 16x16x32 bf16.
// A-fragments built in registers from (smax,smin) scalars — no LDS anywhere.
// A layout: A[m=lane&15][k=(lane>>4)*8+j]; B: B[k][n], n=lane&15, same k split.
// C/D: col(n)=lane&15, row(m)=(lane>>4)*4+reg.  [m89/m120 verified mappings]
__global__ __launch_bounds__(256) void k_taskm(
    const float* __restrict__ W_ret, const float* __restrict__ b_ret,
    const float* __restrict__ W_dram, const float* __restrict__ b_dram,
    const float* __restrict__ W_link, const float* __restrict__ b_link,
    const unsigned short* __restrict__ wtb, const float* __restrict__ b_task,
    const unsigned* __restrict__ tmax, const unsigned* __restrict__ tmin,
    unsigned short* __restrict__ hp0, unsigned short* __restrict__ hp1) {
  int wave = threadIdx.x >> 6;
  int lane = threadIdx.x & 63;
  int tile = blockIdx.x * 4 + wave;
  if (tile >= N_TASK / 16) return;  // 3125 tiles
  int t0 = tile * 16;
  int l16 = lane & 15;
  int quad = lane >> 4;
  int t = t0 + l16;

  f32x4 acc[4];
#pragma unroll
  for (int nf = 0; nf < 4; nf++) acc[nf] = (f32x4){0.f, 0.f, 0.f, 0.f};

  const float* We[3] = {W_ret, W_dram, W_link};
  const float* be[3] = {b_ret, b_dram, b_link};

  for (int e = 0; e < 3; e++) {
    unsigned um = tmax[e * N_TASK + t];
    float smax = funord(um);
    float smin = funord(tmin[e * N_TASK + t]);
    bool live = (um != 0u);
#pragma unroll
    for (int h = 0; h < 2; h++) {
      int kb = h * 32 + quad * 8;  // k within e-chunk for this lane's 8 elems
      float4 w0 = *(const float4*)&We[e][kb];
      float4 w1 = *(const float4*)&We[e][kb + 4];
      float4 b0 = *(const float4*)&be[e][kb];
      float4 b1 = *(const float4*)&be[e][kb + 4];
      float wv[8] = {w0.x, w0.y, w0.z, w0.w, w1.x, w1.y, w1.z, w1.w};
      float bv[8] = {b0.x, b0.y, b0.z, b0.w, b1.x, b1.y, b1.z, b1.w};
      bf16x8 afrag;
#pragma unroll
      for (int j = 0; j < 8; j++) {
        float wj = wv[j];
        float ss = (wj >= 0.f) ? smax : smin;  // monotone tanh: extreme s by sign(w)
        float hc = live ? tanhf(fmaf(ss, wj, bv[j])) : 0.f;
        afrag[j] = (short)bf16rne(hc);
      }
      int kk = e * 64 + h * 32 + quad * 8;  // absolute k
#pragma unroll
      for (int nf = 0; nf < 4; nf++) {
        int o = nf * 16 + l16;
        bf16x8 bfrag = *(const bf16x8*)&wtb[o * 192 + kk];
        acc[nf] = __builtin_amdgcn_mfma_f32_16x16x32_bf16(afrag, bfrag, acc[nf], 0, 0, 0);
      }
    }
  }

  // epilogue: tanh(acc + b_task), bf16, write feature planes
#pragma unroll
  for (int nf = 0; nf < 4; nf++) {
    int n = nf * 16 + l16;
    float bt = b_task[n];
    unsigned short* hp = (n < 32) ? hp0 : hp1;
    int f = n & 31;
#pragma unroll
    for (int r = 0; r < 4; r++) {
      int m = quad * 4 + r;
      float v = tanhf(acc[nf][r] + bt);
      hp[(t0 + m) * 32 + f] = bf16rne(v);
    }
  }
}

// per-link mean over one 32-feature plane; half-wave per link, 4-way MLP unroll.
// Plane = 3.2MB < 4MB per-XCD L2 -> gather becomes L2-resident.
__global__ __launch_bounds__(256) void k_link2(const unsigned short* __restrict__ hp,
                                               const int* __restrict__ offs,
                                               const int* __restrict__ cnt,
                                               const int* __restrict__ csr,
                                               float* __restrict__ out, int plane) {
  int l = blockIdx.x * 8 + (threadIdx.x >> 5);  // 12500*8 == N_LINK
  int f = threadIdx.x & 31;
  int start = offs[l];
  int c = cnt[l];
  float acc = 0.f;
  for (int q = 0; q < c; q += 4) {
    int i1 = (q + 1 < c) ? q + 1 : c - 1;
    int i2 = (q + 2 < c) ? q + 2 : c - 1;
    int i3 = (q + 3 < c) ? q + 3 : c - 1;
    int t0 = csr[start + q];
    int t1 = csr[start + i1];
    int t2 = csr[start + i2];
    int t3 = csr[start + i3];
    unsigned v0 = hp[t0 * 32 + f];
    unsigned v1 = hp[t1 * 32 + f];
    unsigned v2 = hp[t2 * 32 + f];
    unsigned v3 = hp[t3 * 32 + f];
    acc += __uint_as_float(v0 << 16);
    if (q + 1 < c) acc += __uint_as_float(v1 << 16);
    if (q + 2 < c) acc += __uint_as_float(v2 << 16);
    if (q + 3 < c) acc += __uint_as_float(v3 << 16);
  }
  out[l * 64 + plane * 32 + f] = (c > 0) ? acc / (float)c : 0.f;
}

extern "C" void kernel_launch(void* const* d_in, const int* in_sizes, int n_in,
                              void* d_out, int out_size, void* d_ws, size_t ws_size,
                              hipStream_t stream) {
  const float* feat_ret  = (const float*)d_in[0];
  const float* feat_dram = (const float*)d_in[1];
  const float* feat_link = (const float*)d_in[2];
  const float* W_ret  = (const float*)d_in[3];
  const float* b_ret  = (const float*)d_in[4];
  const float* W_dram = (const float*)d_in[5];
  const float* b_dram = (const float*)d_in[6];
  const float* W_link = (const float*)d_in[7];
  const float* b_link = (const float*)d_in[8];
  const float* W_task = (const float*)d_in[9];
  const float* b_task = (const float*)d_in[10];
  const int* task_ret  = (const int*)d_in[11];
  const int* mod_ret   = (const int*)d_in[12];
  const int* task_dram = (const int*)d_in[13];
  const int* mod_dram  = (const int*)d_in[14];
  const int* task_link = (const int*)d_in[15];
  const int* mod_link  = (const int*)d_in[16];
  float* out = (float*)d_out;

  char* ws = (char*)d_ws;
  float* s_ret  = (float*)(ws + WS_SRET);
  float* s_dram = (float*)(ws + WS_SDRAM);
  float* s_link = (float*)(ws + WS_SLINK);
  int*   cnt    = (int*)(ws + WS_CNT);
  int*   offs   = (int*)(ws + WS_OFFS);
  unsigned* tmax = (unsigned*)(ws + WS_TMAX);
  unsigned* tmin = (unsigned*)(ws + WS_TMIN);
  int* bcnt = (int*)(ws + WS_BCNT);
  int* rcnt = (int*)(ws + WS_RCNT);
  int* csr  = (int*)(ws + WS_CSR);
  int* blkcnt_m = (int*)(ws + WS_BLKM);
  int* blkcnt_t = (int*)(ws + WS_BLKT);
  unsigned* partials = (unsigned*)(ws + WS_PARTIALS);
  unsigned long long* mrec_ret  = (unsigned long long*)(ws + WS_MREC_RET);
  unsigned long long* mrec_dram = (unsigned long long*)(ws + WS_MREC_DRAM);
  unsigned long long* mrec_link = (unsigned long long*)(ws + WS_MREC_LINK);
  unsigned long long* trec_ret  = (unsigned long long*)(ws + WS_TREC_RET);
  unsigned long long* trec_dram = (unsigned long long*)(ws + WS_TREC_DRAM);
  unsigned long long* trec_link = (unsigned long long*)(ws + WS_TREC_LINK);
  unsigned short* hp0 = (unsigned short*)(ws + WS_HPL0);
  unsigned short* hp1 = (unsigned short*)(ws + WS_HPL1);
  unsigned short* wtb = (unsigned short*)(ws + WS_WTB);

  if (ws_size >= (size_t)WS_NEED) {
    // ---- atomic-free main path ----
    k_m0<<<NBM_TOT, 256, 0, stream>>>(mod_ret, mod_dram, mod_link, blkcnt_m);
    k_mscan<<<MR_RET + MR_DRAM + MR_LINK, 1024, 0, stream>>>(blkcnt_m, rcnt);
    k_mscatter<<<NBM_TOT, 256, 0, stream>>>(mod_ret, mod_dram, mod_link, task_link,
                                            feat_ret, feat_dram, feat_link, blkcnt_m,
                                            mrec_ret, mrec_dram, mrec_link);
    k_msum<<<MR_RET + MR_DRAM + MR_LINK, 256, 0, stream>>>(
        mrec_ret, mrec_dram, mrec_link, rcnt, s_ret, s_dram, s_link, cnt, offs, csr);
    const int nblkT = NB_RET + NB_DRAM + NB_LINK;  // 12697
    k_a0<<<nblkT, 256, 0, stream>>>(task_ret, task_dram, task_link, blkcnt_t);
    k_ascan<<<48, 1024, 0, stream>>>(blkcnt_t, bcnt);
    k_ascatter<<<nblkT, 256, 0, stream>>>(task_ret, mod_ret, task_dram, mod_dram,
                                          task_link, mod_link, s_ret, s_dram, s_link,
                                          blkcnt_t, trec_ret, trec_dram, trec_link);
    k_passb<<<16 * (SUB_RET + SUB_DRAM + SUB_LINK), 256, 0, stream>>>(
        trec_ret, trec_dram, trec_link, bcnt, partials);
    k_mmred2<<<(3 * N_TASK + 255) / 256, 256, 0, stream>>>(partials, tmax, tmin);
  } else {
    // ---- fallback: global-atomic path ----
    int* part   = (int*)(ws + WS_BLKM);
    int* partx  = (int*)(ws + WS_BLKM + 4096);
    int* cursor = (int*)(ws + WS_BLKT);
    hipMemsetAsync(ws, 0, 1900000, stream);                 // s/cnt/offs/tmax
    hipMemsetAsync(ws + WS_TMIN, 0xFF, 600000, stream);     // tmin
    const int totalE = E_RET + E_DRAM + E_LINK;
    int nblk_e = (totalE + 255) / 256;
    f_segsum<<<nblk_e, 256, 0, stream>>>(feat_ret, feat_dram, feat_link,
                                         mod_ret, mod_dram, mod_link,
                                         s_ret, s_dram, s_link, cnt);
    f_minmax<<<nblk_e, 256, 0, stream>>>(s_ret, s_dram, s_link,
                                         task_ret, mod_ret, task_dram, mod_dram,
                                         task_link, mod_link, tmax, tmin);
    const int npart = (N_LINK + 255) / 256;  // 391
    f_part<<<npart, 256, 0, stream>>>(cnt, part);
    f_scanpart<<<1, 512, 0, stream>>>(part, partx, npart);
    f_offs<<<npart, 256, 0, stream>>>(cnt, partx, offs, cursor);
    f_scatter<<<(E_LINK + 255) / 256, 256, 0, stream>>>(task_link, mod_link, cursor, csr);
  }

  // task update: W prep (bf16) + MFMA GEMM, no LDS
  k_wprep<<<48, 256, 0, stream>>>(W_task, wtb);
  k_taskm<<<(N_TASK / 16 + 3) / 4, 256, 0, stream>>>(W_ret, b_ret, W_dram, b_dram,
                                                     W_link, b_link, wtb, b_task,
                                                     tmax, tmin, hp0, hp1);
  k_link2<<<N_LINK / 8, 256, 0, stream>>>(hp0, offs, cnt, csr, out, 0);
  k_link2<<<N_LINK / 8, 256, 0, stream>>>(hp1, offs, cnt, csr, out, 1);
}

// Round 7
// 359.644 us; speedup vs baseline: 3.4603x; 1.0512x over previous
//
#include <hip/hip_runtime.h>
#include <stdint.h>

#define N_TASK 50000
#define N_RET 20000
#define N_DRAM 5000
#define N_LINK 100000
#define E_RET 1000000
#define E_DRAM 250000
#define E_LINK 2000000

// ---- module-range bucketing ----
#define SBE 4096                // edges per scatter/count block
#define NS_RET 245              // ceil(1e6/4096)
#define NS_DRAM 62
#define NS_LINK 489
#define NS_TOT (NS_RET + NS_DRAM + NS_LINK)   // 796
#define MR_RET 64
#define RSZ_RET 313             // 64*313 = 20032 >= 20000
#define MR_DRAM 16
#define RSZ_DRAM 313
#define MR_LINK 256
#define RSZ_LINK 391            // 256*391 = 100096 >= 100000
#define RECIP313 107203u        // validated rounds 4-6
#define RECIP391 85817u
#define CAPM_RET 16250
#define CAPM_DRAM 16250
#define CAPM_LINK 8255
// m-blkcnt element offsets
#define BM4_RET 0
#define BM4_DRAM (MR_RET * NS_RET)                 // 15680
#define BM4_LINK (BM4_DRAM + MR_DRAM * NS_DRAM)    // 16672
#define BM4_TOT (BM4_LINK + MR_LINK * NS_LINK)     // 141856
// t-blkcnt element offsets
#define BT_RET 0
#define BT_DRAM (16 * NS_RET)                      // 3920
#define BT_LINK (BT_DRAM + 16 * NS_DRAM)           // 4912
#define BT_TOT (BT_LINK + 16 * NS_LINK)            // 12736

// ---- task-range bucketing (per-task min/max) ----
#define R_PART 3125             // 16*3125 == N_TASK
#define CAP_RET 63800
#define CAP_DRAM 16300
#define CAP_LINK 126800
#define SUB_RET 4
#define SUB_DRAM 1
#define SUB_LINK 8
#define PB_RET 0
#define PB_DRAM (16 * SUB_RET * R_PART)             // 200000
#define PB_LINK (PB_DRAM + 16 * SUB_DRAM * R_PART)  // 250000
#define PB_TOT (PB_LINK + 16 * SUB_LINK * R_PART)   // 650000 words per plane

// ---- workspace byte offsets ----
#define WS_SRET 0               // 20000 f
#define WS_SDRAM 80000          // 5000 f
#define WS_SLINK 100000         // 100000 f
#define WS_CNT 500000           // 100000 i
#define WS_OFFS 900000          // 100000 i
#define WS_TMAX 1300000         // 150000 u
#define WS_TMIN 1900000         // 150000 u
#define WS_BCNT 2500000         // 48 i
#define WS_RCNT 2500192         // 336 i
#define WS_CSR 2501536          // 2M i -> ends 10501536
// counts region [10501536, 15701536): blkcnt_m, blkcnt_t, then partials
#define WS_BLKM 10501536        // 141856 i -> 11068960 (dead after k_mscatter2)
#define WS_BLKT 11068960        // 12736 i  -> 11119904 (dead after k_ascatter2)
#define WS_PARTIALS 10501536    // 2*650000 u (written by k_passb, after both dead)
// records union [15701536, 43007776):
#define WS_MREC_RET 15701536    // 64*16250*8  -> 24021536
#define WS_MREC_DRAM 24021536   // 16*16250*8  -> 26101536
#define WS_MREC_LINK 26101536   // 256*8255*8  -> 43007776
#define WS_TREC_RET 15701536    // 16*63800*8  -> 23867936 (after mrec dead)
#define WS_TREC_DRAM 23867936   // 16*16300*8  -> 25954336
#define WS_TREC_LINK 25954336   // 16*126800*8 -> 42184736
// h_task planes (3.2MB each, < 4MB per-XCD L2)
#define WS_HPL0 15701536        // 50000*32 u16 (after trec dead)
#define WS_HPL1 18901536
#define WS_WTB  43007776        // 12288 u16 — dedicated, written early by k_count
#define WS_NEED 43032352

typedef __attribute__((ext_vector_type(8))) short bf16x8;
typedef __attribute__((ext_vector_type(4))) float f32x4;

__device__ __forceinline__ unsigned ford(float f) {
  unsigned u = __float_as_uint(f);
  return (u & 0x80000000u) ? ~u : (u | 0x80000000u);
}
__device__ __forceinline__ float funord(unsigned t) {
  unsigned u = (t & 0x80000000u) ? (t & 0x7fffffffu) : ~t;
  return __uint_as_float(u);
}
__device__ __forceinline__ unsigned short bf16rne(float f) {
  unsigned u = __float_as_uint(f);
  return (unsigned short)((u + 0x7fffu + ((u >> 16) & 1u)) >> 16);
}

// ---- block decode (4096-edge blocks) ----
__device__ __forceinline__ void decode_sblk(int bx, int& e, int& blk, int& E0, int& NB,
                                            int& NR, unsigned& RECIP, int& RSZ, int& base) {
  if (bx < NS_RET) {
    e = 0; blk = bx; E0 = E_RET; NB = NS_RET; NR = MR_RET; RECIP = RECIP313; RSZ = RSZ_RET; base = BM4_RET;
  } else if (bx < NS_RET + NS_DRAM) {
    e = 1; blk = bx - NS_RET; E0 = E_DRAM; NB = NS_DRAM; NR = MR_DRAM; RECIP = RECIP313; RSZ = RSZ_DRAM; base = BM4_DRAM;
  } else {
    e = 2; blk = bx - NS_RET - NS_DRAM; E0 = E_LINK; NB = NS_LINK; NR = MR_LINK; RECIP = RECIP391; RSZ = RSZ_LINK; base = BM4_LINK;
  }
}
__device__ __forceinline__ void decode_stblk(int bx, int& e, int& blk, int& E0, int& NB,
                                             int& baset) {
  if (bx < NS_RET) { e = 0; blk = bx; E0 = E_RET; NB = NS_RET; baset = BT_RET; }
  else if (bx < NS_RET + NS_DRAM) { e = 1; blk = bx - NS_RET; E0 = E_DRAM; NB = NS_DRAM; baset = BT_DRAM; }
  else { e = 2; blk = bx - NS_RET - NS_DRAM; E0 = E_LINK; NB = NS_LINK; baset = BT_LINK; }
}

// ---- fused counts: m-counts [0,796), t-counts [796,1592), wprep [1592,1640) ----
__global__ __launch_bounds__(256) void k_count(
    const int* __restrict__ mr, const int* __restrict__ md, const int* __restrict__ ml,
    const int* __restrict__ tr, const int* __restrict__ td, const int* __restrict__ tl,
    const float* __restrict__ W_task, unsigned short* __restrict__ wtb,
    int* __restrict__ blkcnt_m, int* __restrict__ blkcnt_t) {
  int bx = blockIdx.x, tid = threadIdx.x;
  if (bx >= 2 * NS_TOT) {
    int i = (bx - 2 * NS_TOT) * 256 + tid;
    if (i < 64 * 192) wtb[i] = bf16rne(W_task[i]);
    return;
  }
  __shared__ int c[256];
  c[tid] = 0;
  __syncthreads();
  if (bx < NS_TOT) {
    int e, blk, E0, NB, NR, RSZ, base; unsigned RECIP;
    decode_sblk(bx, e, blk, E0, NB, NR, RECIP, RSZ, base);
    const int* mod = (e == 0) ? mr : (e == 1) ? md : ml;
    int i0 = blk * SBE;
#pragma unroll
    for (int q = 0; q < 16; q++) {
      int i = i0 + q * 256 + tid;
      if (i < E0) {
        int m = mod[i];
        int r = (int)(((unsigned long long)(unsigned)m * RECIP) >> 25);
        atomicAdd(&c[r], 1);
      }
    }
    __syncthreads();
    for (int r = tid; r < NR; r += 256)
      blkcnt_m[base + r * NB + blk] = c[r];
  } else {
    int e, blk, E0, NB, baset;
    decode_stblk(bx - NS_TOT, e, blk, E0, NB, baset);
    const int* task = (e == 0) ? tr : (e == 1) ? td : tl;
    int i0 = blk * SBE;
#pragma unroll
    for (int q = 0; q < 16; q++) {
      int i = i0 + q * 256 + tid;
      if (i < E0) atomicAdd(&c[task[i] / R_PART], 1);
    }
    __syncthreads();
    if (tid < 16) blkcnt_t[baset + tid * NB + blk] = c[tid];
  }
}

// ---- fused scans: m [0,336), t [336,384). NB <= 489 < 512 -> single pass ----
__global__ __launch_bounds__(512) void k_scan(int* __restrict__ blkcnt_m,
                                              int* __restrict__ blkcnt_t,
                                              int* __restrict__ rcnt, int* __restrict__ bcnt) {
  __shared__ int sm[512];
  int gb = blockIdx.x, tid = threadIdx.x;
  int* arr; int NB; int* outp;
  if (gb < 336) {
    int off;
    if (gb < 64) { NB = NS_RET; off = BM4_RET + gb * NS_RET; }
    else if (gb < 80) { NB = NS_DRAM; off = BM4_DRAM + (gb - 64) * NS_DRAM; }
    else { NB = NS_LINK; off = BM4_LINK + (gb - 80) * NS_LINK; }
    arr = blkcnt_m + off; outp = rcnt + gb;
  } else {
    int g = gb - 336; int e = g >> 4, b = g & 15;
    int NBe = (e == 0) ? NS_RET : (e == 1) ? NS_DRAM : NS_LINK;
    int baset = (e == 0) ? BT_RET : (e == 1) ? BT_DRAM : BT_LINK;
    NB = NBe; arr = blkcnt_t + baset + b * NBe; outp = bcnt + g;
  }
  int v = (tid < NB) ? arr[tid] : 0;
  sm[tid] = v;
  __syncthreads();
  for (int d = 1; d < 512; d <<= 1) {
    int x = (tid >= d) ? sm[tid - d] : 0;
    __syncthreads();
    sm[tid] += x;
    __syncthreads();
  }
  if (tid < NB) arr[tid] = sm[tid] - v;  // exclusive
  if (tid == 511) *outp = sm[511];
}

// ---- staged m-scatter: counting-sort in LDS, coalesced global runs ----
__global__ __launch_bounds__(256) void k_mscatter2(
    const int* __restrict__ mr, const int* __restrict__ md, const int* __restrict__ ml,
    const int* __restrict__ tl,
    const float* __restrict__ fr, const float* __restrict__ fd, const float* __restrict__ fl,
    const int* __restrict__ blkcnt_m,
    unsigned long long* __restrict__ mrec_ret, unsigned long long* __restrict__ mrec_dram,
    unsigned long long* __restrict__ mrec_link) {
  __shared__ int lcur[256];
  __shared__ int pdelta[256];
  __shared__ int sscan[256];
  __shared__ unsigned long long srec[SBE];
  __shared__ int sdelta[SBE];
  int tid = threadIdx.x;
  int e, blk, E0, NB, NR, RSZ, base; unsigned RECIP;
  decode_sblk(blockIdx.x, e, blk, E0, NB, NR, RECIP, RSZ, base);
  const int* mod = (e == 0) ? mr : (e == 1) ? md : ml;
  const float* feat = (e == 0) ? fr : (e == 1) ? fd : fl;
  unsigned long long* out = (e == 0) ? mrec_ret : (e == 1) ? mrec_dram : mrec_link;
  int CAP = (e == 0) ? CAPM_RET : (e == 1) ? CAPM_DRAM : CAPM_LINK;
  lcur[tid] = 0;
  __syncthreads();
  int i0 = blk * SBE;
#pragma unroll
  for (int q = 0; q < 16; q++) {
    int i = i0 + q * 256 + tid;
    if (i < E0) {
      int m = mod[i];
      int r = (int)(((unsigned long long)(unsigned)m * RECIP) >> 25);
      atomicAdd(&lcur[r], 1);
    }
  }
  __syncthreads();
  int v = lcur[tid];
  sscan[tid] = v;
  __syncthreads();
  for (int d = 1; d < 256; d <<= 1) {
    int x = (tid >= d) ? sscan[tid - d] : 0;
    __syncthreads();
    sscan[tid] += x;
    __syncthreads();
  }
  int excl = sscan[tid] - v;
  int total = sscan[255];
  int gbv = (tid < NR) ? blkcnt_m[base + tid * NB + blk] : 0;
  __syncthreads();
  lcur[tid] = excl;
  pdelta[tid] = tid * CAP + gbv - excl;
  __syncthreads();
#pragma unroll
  for (int q = 0; q < 16; q++) {
    int i = i0 + q * 256 + tid;
    if (i < E0) {
      int m = mod[i];
      int r = (int)(((unsigned long long)(unsigned)m * RECIP) >> 25);
      unsigned mloc = (unsigned)(m - r * RSZ);
      unsigned task = (e == 2) ? (unsigned)tl[i] : 0u;
      unsigned fu = __float_as_uint(feat[i]);
      int slot = atomicAdd(&lcur[r], 1);
      srec[slot] = ((unsigned long long)fu << 32) | (task << 16) | mloc;
      int gpos = pdelta[r] + slot - r * CAP;  // position within bucket
      sdelta[slot] = (gpos < CAP) ? pdelta[r] : (int)0x80000000;
    }
  }
  __syncthreads();
  for (int s = tid; s < total; s += 256) {
    int d = sdelta[s];
    if (d != (int)0x80000000) out[d + s] = srec[s];
  }
}

// ---- per-range: LDS sums -> s_*; link also cnt/offs/CSR. No global atomics ----
__global__ __launch_bounds__(256) void k_msum(
    const unsigned long long* __restrict__ mrec_ret,
    const unsigned long long* __restrict__ mrec_dram,
    const unsigned long long* __restrict__ mrec_link,
    const int* __restrict__ rcnt,
    float* __restrict__ s_ret, float* __restrict__ s_dram, float* __restrict__ s_link,
    int* __restrict__ cnt, int* __restrict__ offs, int* __restrict__ csr) {
  __shared__ float ssum[RSZ_LINK];
  __shared__ int scnt[RSZ_LINK];
  __shared__ int soff[RSZ_LINK + 1];
  __shared__ int red[256];
  int gb = blockIdx.x, tid = threadIdx.x;
  int e, rl, RSZ, CAP, Ntot;
  const unsigned long long* p;
  float* sout;
  if (gb < MR_RET) {
    e = 0; rl = gb; p = mrec_ret + (long)rl * CAPM_RET; sout = s_ret;
    RSZ = RSZ_RET; CAP = CAPM_RET; Ntot = N_RET;
  } else if (gb < MR_RET + MR_DRAM) {
    e = 1; rl = gb - MR_RET; p = mrec_dram + (long)rl * CAPM_DRAM; sout = s_dram;
    RSZ = RSZ_DRAM; CAP = CAPM_DRAM; Ntot = N_DRAM;
  } else {
    e = 2; rl = gb - MR_RET - MR_DRAM; p = mrec_link + (long)rl * CAPM_LINK; sout = s_link;
    RSZ = RSZ_LINK; CAP = CAPM_LINK; Ntot = N_LINK;
  }
  int m0 = rl * RSZ;
  int nmod = Ntot - m0; if (nmod > RSZ) nmod = RSZ;
  for (int j = tid; j < RSZ; j += 256) { ssum[j] = 0.f; scnt[j] = 0; }
  __syncthreads();
  int count = rcnt[gb]; if (count > CAP) count = CAP;
  for (int i = tid; i < count; i += 256) {
    unsigned long long rec = p[i];
    int mloc = (int)(rec & 0xFFFFull);
    atomicAdd(&ssum[mloc], __uint_as_float((unsigned)(rec >> 32)));
    if (e == 2) atomicAdd(&scnt[mloc], 1);
  }
  __syncthreads();
  for (int j = tid; j < nmod; j += 256) sout[m0 + j] = ssum[j];
  if (e != 2) return;
  int partial = (80 + tid < gb) ? rcnt[80 + tid] : 0;
  red[tid] = partial;
  __syncthreads();
  for (int s = 128; s > 0; s >>= 1) {
    if (tid < s) red[tid] += red[tid + s];
    __syncthreads();
  }
  int rb = red[0];
  __syncthreads();
  int a0 = (2 * tid < nmod) ? scnt[2 * tid] : 0;
  int a1 = (2 * tid + 1 < nmod) ? scnt[2 * tid + 1] : 0;
  red[tid] = a0 + a1;
  __syncthreads();
  for (int d = 1; d < 256; d <<= 1) {
    int x = (tid >= d) ? red[tid - d] : 0;
    __syncthreads();
    red[tid] += x;
    __syncthreads();
  }
  int excl = red[tid] - (a0 + a1);
  if (2 * tid < RSZ_LINK) soff[2 * tid] = excl;
  if (2 * tid + 1 < RSZ_LINK) soff[2 * tid + 1] = excl + a0;
  __syncthreads();
  for (int j = tid; j < nmod; j += 256) {
    cnt[m0 + j] = scnt[j];
    offs[m0 + j] = rb + soff[j];
  }
  __syncthreads();
  for (int i = tid; i < count; i += 256) {
    unsigned long long rec = p[i];
    int mloc = (int)(rec & 0xFFFFull);
    int task = (int)((rec >> 16) & 0xFFFFull);
    int lp = atomicAdd(&soff[mloc], 1);
    csr[rb + lp] = task;
  }
}

// ---- staged t-scatter (per-task min/max records), same counting-sort trick ----
__global__ __launch_bounds__(256) void k_ascatter2(
    const int* __restrict__ tr, const int* __restrict__ mr,
    const int* __restrict__ td, const int* __restrict__ md,
    const int* __restrict__ tl, const int* __restrict__ ml,
    const float* __restrict__ s_ret, const float* __restrict__ s_dram,
    const float* __restrict__ s_link, const int* __restrict__ blkcnt_t,
    unsigned long long* __restrict__ trec_ret, unsigned long long* __restrict__ trec_dram,
    unsigned long long* __restrict__ trec_link) {
  __shared__ int lcur[256];
  __shared__ int pdelta[256];
  __shared__ int sscan[256];
  __shared__ unsigned long long srec[SBE];
  __shared__ int sdelta[SBE];
  int tid = threadIdx.x;
  int e, blk, E0, NB, baset;
  decode_stblk(blockIdx.x, e, blk, E0, NB, baset);
  const int* task = (e == 0) ? tr : (e == 1) ? td : tl;
  const int* mod = (e == 0) ? mr : (e == 1) ? md : ml;
  const float* s = (e == 0) ? s_ret : (e == 1) ? s_dram : s_link;
  unsigned long long* out = (e == 0) ? trec_ret : (e == 1) ? trec_dram : trec_link;
  int CAP = (e == 0) ? CAP_RET : (e == 1) ? CAP_DRAM : CAP_LINK;
  lcur[tid] = 0;
  __syncthreads();
  int i0 = blk * SBE;
#pragma unroll
  for (int q = 0; q < 16; q++) {
    int i = i0 + q * 256 + tid;
    if (i < E0) atomicAdd(&lcur[task[i] / R_PART], 1);
  }
  __syncthreads();
  int v = lcur[tid];
  sscan[tid] = v;
  __syncthreads();
  for (int d = 1; d < 256; d <<= 1) {
    int x = (tid >= d) ? sscan[tid - d] : 0;
    __syncthreads();
    sscan[tid] += x;
    __syncthreads();
  }
  int excl = sscan[tid] - v;
  int total = sscan[255];
  int gbv = (tid < 16) ? blkcnt_t[baset + tid * NB + blk] : 0;
  __syncthreads();
  lcur[tid] = excl;
  pdelta[tid] = tid * CAP + gbv - excl;
  __syncthreads();
#pragma unroll
  for (int q = 0; q < 16; q++) {
    int i = i0 + q * 256 + tid;
    if (i < E0) {
      int t = task[i];
      int r = t / R_PART;
      unsigned rloc = (unsigned)(t - r * R_PART);
      unsigned u = ford(s[mod[i]]);
      int slot = atomicAdd(&lcur[r], 1);
      srec[slot] = ((unsigned long long)u << 32) | rloc;
      int gpos = pdelta[r] + slot - r * CAP;
      sdelta[slot] = (gpos < CAP) ? pdelta[r] : (int)0x80000000;
    }
  }
  __syncthreads();
  for (int sidx = tid; sidx < total; sidx += 256) {
    int d = sdelta[sidx];
    if (d != (int)0x80000000) out[d + sidx] = srec[sidx];
  }
}

__global__ __launch_bounds__(256) void k_passb(
    const unsigned long long* __restrict__ trec_ret,
    const unsigned long long* __restrict__ trec_dram,
    const unsigned long long* __restrict__ trec_link,
    const int* __restrict__ bcnt, unsigned* __restrict__ partials) {
  __shared__ unsigned lmax[R_PART];
  __shared__ unsigned lmin[R_PART];
  int blk = blockIdx.x;
  int e, b, sub, Nb, PB, CAP;
  const unsigned long long* bkt;
  if (blk < 16 * SUB_RET) {
    e = 0; b = blk >> 2; sub = blk & 3; Nb = SUB_RET; PB = PB_RET; CAP = CAP_RET; bkt = trec_ret;
  } else if (blk < 16 * (SUB_RET + SUB_DRAM)) {
    int q = blk - 16 * SUB_RET;
    e = 1; b = q; sub = 0; Nb = SUB_DRAM; PB = PB_DRAM; CAP = CAP_DRAM; bkt = trec_dram;
  } else {
    int q = blk - 16 * (SUB_RET + SUB_DRAM);
    e = 2; b = q >> 3; sub = q & 7; Nb = SUB_LINK; PB = PB_LINK; CAP = CAP_LINK; bkt = trec_link;
  }
  for (int idx = threadIdx.x; idx < R_PART; idx += 256) {
    lmax[idx] = 0u;
    lmin[idx] = 0xFFFFFFFFu;
  }
  __syncthreads();
  int count = bcnt[e * 16 + b];
  if (count > CAP) count = CAP;
  int chunk = (count + Nb - 1) / Nb;
  int s0 = sub * chunk;
  int s1 = s0 + chunk; if (s1 > count) s1 = count;
  const unsigned long long* p = bkt + (long)b * CAP;
  for (int i = s0 + threadIdx.x; i < s1; i += 256) {
    unsigned long long rec = p[i];
    unsigned r = (unsigned)rec;
    unsigned u = (unsigned)(rec >> 32);
    atomicMax(&lmax[r], u);
    atomicMin(&lmin[r], u);
  }
  __syncthreads();
  unsigned gbase = PB + (unsigned)(b * Nb + sub) * R_PART;
  for (int idx = threadIdx.x; idx < R_PART; idx += 256) {
    partials[gbase + idx] = lmax[idx];
    partials[PB_TOT + gbase + idx] = lmin[idx];
  }
}

__global__ __launch_bounds__(256) void k_mmred2(const unsigned* __restrict__ partials,
                                                unsigned* __restrict__ tmax,
                                                unsigned* __restrict__ tmin) {
  int gid = blockIdx.x * 256 + threadIdx.x;
  if (gid >= 3 * N_TASK) return;
  int e = gid / N_TASK;
  int t = gid - e * N_TASK;
  int Nb = (e == 0) ? SUB_RET : (e == 1) ? SUB_DRAM : SUB_LINK;
  int PB = (e == 0) ? PB_RET : (e == 1) ? PB_DRAM : PB_LINK;
  int b = t / R_PART;
  int r = t - b * R_PART;
  unsigned umax = 0u, umin = 0xFFFFFFFFu;
  for (int sub = 0; sub < Nb; sub++) {
    unsigned idx = PB + (unsigned)(b * Nb + sub) * R_PART + r;
    unsigned w = partials[idx];
    if (w > umax) umax = w;
    unsigned w2 = partials[PB_TOT + idx];
    if (w2 < umin) umin = w2;
  }
  tmax[gid] = umax;
  tmin[gid] = umin;
}

// =================== fallback (small ws): global-atomic path ===================

__global__ void k_wprep(const float* __restrict__ W_task, unsigned short* __restrict__ wtb) {
  int i = blockIdx.x * 256 + threadIdx.x;
  if (i < 64 * 192) wtb[i] = bf16rne(W_task[i]);
}

__global__ void f_segsum(const float* __restrict__ fr, const float* __restrict__ fd,
                         const float* __restrict__ fl,
                         const int* __restrict__ mr, const int* __restrict__ md,
                         const int* __restrict__ ml,
                         float* s_ret, float* s_dram, float* s_link, int* cnt) {
  int i = blockIdx.x * blockDim.x + threadIdx.x;
  const int total = E_RET + E_DRAM + E_LINK;
  if (i >= total) return;
  if (i < E_RET) {
    atomicAdd(&s_ret[mr[i]], fr[i]);
  } else if (i < E_RET + E_DRAM) {
    int j = i - E_RET;
    atomicAdd(&s_dram[md[j]], fd[j]);
  } else {
    int j = i - (E_RET + E_DRAM);
    int m = ml[j];
    atomicAdd(&s_link[m], fl[j]);
    atomicAdd(&cnt[m], 1);
  }
}

__global__ void f_minmax(const float* __restrict__ s_ret, const float* __restrict__ s_dram,
                         const float* __restrict__ s_link,
                         const int* __restrict__ tr, const int* __restrict__ mr,
                         const int* __restrict__ td, const int* __restrict__ md,
                         const int* __restrict__ tl, const int* __restrict__ ml,
                         unsigned* tmax, unsigned* tmin) {
  int i = blockIdx.x * blockDim.x + threadIdx.x;
  const int total = E_RET + E_DRAM + E_LINK;
  if (i >= total) return;
  int e, task; unsigned u;
  if (i < E_RET) {
    u = ford(s_ret[mr[i]]); task = tr[i]; e = 0;
  } else if (i < E_RET + E_DRAM) {
    int j = i - E_RET;
    u = ford(s_dram[md[j]]); task = td[j]; e = 1;
  } else {
    int j = i - (E_RET + E_DRAM);
    u = ford(s_link[ml[j]]); task = tl[j]; e = 2;
  }
  atomicMax(&tmax[e * N_TASK + task], u);
  atomicMin(&tmin[e * N_TASK + task], u);
}

__global__ void f_part(const int* __restrict__ cnt, int* part) {
  __shared__ int sm[256];
  int i = blockIdx.x * 256 + threadIdx.x;
  sm[threadIdx.x] = (i < N_LINK) ? cnt[i] : 0;
  __syncthreads();
  for (int s = 128; s > 0; s >>= 1) {
    if (threadIdx.x < s) sm[threadIdx.x] += sm[threadIdx.x + s];
    __syncthreads();
  }
  if (threadIdx.x == 0) part[blockIdx.x] = sm[0];
}

__global__ void f_scanpart(const int* __restrict__ part, int* partx, int npart) {
  __shared__ int sm[512];
  int t = threadIdx.x;
  int v = (t < npart) ? part[t] : 0;
  sm[t] = v;
  __syncthreads();
  for (int d = 1; d < 512; d <<= 1) {
    int x = (t >= d) ? sm[t - d] : 0;
    __syncthreads();
    sm[t] += x;
    __syncthreads();
  }
  if (t < npart) partx[t] = sm[t] - v;
}

__global__ void f_offs(const int* __restrict__ cnt, const int* __restrict__ partx,
                       int* offs, int* cursor) {
  __shared__ int sm[256];
  int i = blockIdx.x * 256 + threadIdx.x;
  int t = threadIdx.x;
  int v = (i < N_LINK) ? cnt[i] : 0;
  sm[t] = v;
  __syncthreads();
  for (int d = 1; d < 256; d <<= 1) {
    int x = (t >= d) ? sm[t - d] : 0;
    __syncthreads();
    sm[t] += x;
    __syncthreads();
  }
  if (i < N_LINK) {
    int o = partx[blockIdx.x] + sm[t] - v;
    offs[i] = o;
    cursor[i] = o;
  }
}

__global__ void f_scatter(const int* __restrict__ tl, const int* __restrict__ ml,
                          int* cursor, int* csr) {
  int i = blockIdx.x * blockDim.x + threadIdx.x;
  if (i >= E_LINK) return;
  int pos = atomicAdd(&cursor[ml[i]], 1);
  csr[pos] = tl[i];
}

// =================== shared tail: task GEMM (MFMA) + link mean ===================

__global__ __launch_bounds__(256) void k_taskm(
    const float* __restrict__ W_ret, const float* __restrict__ b_ret,
    const float* __restrict__ W_dram, const float* __restrict__ b_dram,
    const float* __restrict__ W_link, const float* __restrict__ b_link,
    const unsigned short* __restrict__ wtb, const float* __restrict__ b_task,
    const unsigned* __restrict__ tmax, const unsigned* __restrict__ tmin,
    unsigned short* __restrict__ hp0, unsigned short* __restrict__ hp1) {
  int wave = threadIdx.x >> 6;
  int lane = threadIdx.x & 63;
  int tile = blockIdx.x * 4 + wave;
  if (tile >= N_TASK / 16) return;  // 3125 tiles
  int t0 = tile * 16;
  int l16 = lane & 15;
  int quad = lane >> 4;
  int t = t0 + l16;

  f32x4 acc[4];
#pragma unroll
  for (int nf = 0; nf < 4; nf++) acc[nf] = (f32x4){0.f, 0.f, 0.f, 0.f};

  const float* We[3] = {W_ret, W_dram, W_link};
  const float* be[3] = {b_ret, b_dram, b_link};

  for (int e = 0; e < 3; e++) {
    unsigned um = tmax[e * N_TASK + t];
    float smax = funord(um);
    float smin = funord(tmin[e * N_TASK + t]);
    bool live = (um != 0u);
#pragma unroll
    for (int h = 0; h < 2; h++) {
      int kb = h * 32 + quad * 8;
      float4 w0 = *(const float4*)&We[e][kb];
      float4 w1 = *(const float4*)&We[e][kb + 4];
      float4 b0 = *(const float4*)&be[e][kb];
      float4 b1 = *(const float4*)&be[e][kb + 4];
      float wv[8] = {w0.x, w0.y, w0.z, w0.w, w1.x, w1.y, w1.z, w1.w};
      float bv[8] = {b0.x, b0.y, b0.z, b0.w, b1.x, b1.y, b1.z, b1.w};
      bf16x8 afrag;
#pragma unroll
      for (int j = 0; j < 8; j++) {
        float wj = wv[j];
        float ss = (wj >= 0.f) ? smax : smin;
        float hc = live ? tanhf(fmaf(ss, wj, bv[j])) : 0.f;
        afrag[j] = (short)bf16rne(hc);
      }
      int kk = e * 64 + h * 32 + quad * 8;
#pragma unroll
      for (int nf = 0; nf < 4; nf++) {
        int o = nf * 16 + l16;
        bf16x8 bfrag = *(const bf16x8*)&wtb[o * 192 + kk];
        acc[nf] = __builtin_amdgcn_mfma_f32_16x16x32_bf16(afrag, bfrag, acc[nf], 0, 0, 0);
      }
    }
  }

#pragma unroll
  for (int nf = 0; nf < 4; nf++) {
    int n = nf * 16 + l16;
    float bt = b_task[n];
    unsigned short* hp = (n < 32) ? hp0 : hp1;
    int f = n & 31;
#pragma unroll
    for (int r = 0; r < 4; r++) {
      int m = quad * 4 + r;
      float v = tanhf(acc[nf][r] + bt);
      hp[(t0 + m) * 32 + f] = bf16rne(v);
    }
  }
}

__global__ __launch_bounds__(256) void k_link2(const unsigned short* __restrict__ hp,
                                               const int* __restrict__ offs,
                                               const int* __restrict__ cnt,
                                               const int* __restrict__ csr,
                                               float* __restrict__ out, int plane) {
  int l = blockIdx.x * 8 + (threadIdx.x >> 5);  // 12500*8 == N_LINK
  int f = threadIdx.x & 31;
  int start = offs[l];
  int c = cnt[l];
  float acc = 0.f;
  for (int q = 0; q < c; q += 4) {
    int i1 = (q + 1 < c) ? q + 1 : c - 1;
    int i2 = (q + 2 < c) ? q + 2 : c - 1;
    int i3 = (q + 3 < c) ? q + 3 : c - 1;
    int t0 = csr[start + q];
    int t1 = csr[start + i1];
    int t2 = csr[start + i2];
    int t3 = csr[start + i3];
    unsigned v0 = hp[t0 * 32 + f];
    unsigned v1 = hp[t1 * 32 + f];
    unsigned v2 = hp[t2 * 32 + f];
    unsigned v3 = hp[t3 * 32 + f];
    acc += __uint_as_float(v0 << 16);
    if (q + 1 < c) acc += __uint_as_float(v1 << 16);
    if (q + 2 < c) acc += __uint_as_float(v2 << 16);
    if (q + 3 < c) acc += __uint_as_float(v3 << 16);
  }
  out[l * 64 + plane * 32 + f] = (c > 0) ? acc / (float)c : 0.f;
}

extern "C" void kernel_launch(void* const* d_in, const int* in_sizes, int n_in,
                              void* d_out, int out_size, void* d_ws, size_t ws_size,
                              hipStream_t stream) {
  const float* feat_ret  = (const float*)d_in[0];
  const float* feat_dram = (const float*)d_in[1];
  const float* feat_link = (const float*)d_in[2];
  const float* W_ret  = (const float*)d_in[3];
  const float* b_ret  = (const float*)d_in[4];
  const float* W_dram = (const float*)d_in[5];
  const float* b_dram = (const float*)d_in[6];
  const float* W_link = (const float*)d_in[7];
  const float* b_link = (const float*)d_in[8];
  const float* W_task = (const float*)d_in[9];
  const float* b_task = (const float*)d_in[10];
  const int* task_ret  = (const int*)d_in[11];
  const int* mod_ret   = (const int*)d_in[12];
  const int* task_dram = (const int*)d_in[13];
  const int* mod_dram  = (const int*)d_in[14];
  const int* task_link = (const int*)d_in[15];
  const int* mod_link  = (const int*)d_in[16];
  float* out = (float*)d_out;

  char* ws = (char*)d_ws;
  float* s_ret  = (float*)(ws + WS_SRET);
  float* s_dram = (float*)(ws + WS_SDRAM);
  float* s_link = (float*)(ws + WS_SLINK);
  int*   cnt    = (int*)(ws + WS_CNT);
  int*   offs   = (int*)(ws + WS_OFFS);
  unsigned* tmax = (unsigned*)(ws + WS_TMAX);
  unsigned* tmin = (unsigned*)(ws + WS_TMIN);
  int* bcnt = (int*)(ws + WS_BCNT);
  int* rcnt = (int*)(ws + WS_RCNT);
  int* csr  = (int*)(ws + WS_CSR);
  int* blkcnt_m = (int*)(ws + WS_BLKM);
  int* blkcnt_t = (int*)(ws + WS_BLKT);
  unsigned* partials = (unsigned*)(ws + WS_PARTIALS);
  unsigned long long* mrec_ret  = (unsigned long long*)(ws + WS_MREC_RET);
  unsigned long long* mrec_dram = (unsigned long long*)(ws + WS_MREC_DRAM);
  unsigned long long* mrec_link = (unsigned long long*)(ws + WS_MREC_LINK);
  unsigned long long* trec_ret  = (unsigned long long*)(ws + WS_TREC_RET);
  unsigned long long* trec_dram = (unsigned long long*)(ws + WS_TREC_DRAM);
  unsigned long long* trec_link = (unsigned long long*)(ws + WS_TREC_LINK);
  unsigned short* hp0 = (unsigned short*)(ws + WS_HPL0);
  unsigned short* hp1 = (unsigned short*)(ws + WS_HPL1);
  unsigned short* wtb = (unsigned short*)(ws + WS_WTB);

  if (ws_size >= (size_t)WS_NEED) {
    // ---- atomic-free main path (10 launches) ----
    k_count<<<2 * NS_TOT + 48, 256, 0, stream>>>(mod_ret, mod_dram, mod_link,
                                                 task_ret, task_dram, task_link,
                                                 W_task, wtb, blkcnt_m, blkcnt_t);
    k_scan<<<384, 512, 0, stream>>>(blkcnt_m, blkcnt_t, rcnt, bcnt);
    k_mscatter2<<<NS_TOT, 256, 0, stream>>>(mod_ret, mod_dram, mod_link, task_link,
                                            feat_ret, feat_dram, feat_link, blkcnt_m,
                                            mrec_ret, mrec_dram, mrec_link);
    k_msum<<<MR_RET + MR_DRAM + MR_LINK, 256, 0, stream>>>(
        mrec_ret, mrec_dram, mrec_link, rcnt, s_ret, s_dram, s_link, cnt, offs, csr);
    k_ascatter2<<<NS_TOT, 256, 0, stream>>>(task_ret, mod_ret, task_dram, mod_dram,
                                            task_link, mod_link, s_ret, s_dram, s_link,
                                            blkcnt_t, trec_ret, trec_dram, trec_link);
    k_passb<<<16 * (SUB_RET + SUB_DRAM + SUB_LINK), 256, 0, stream>>>(
        trec_ret, trec_dram, trec_link, bcnt, partials);
    k_mmred2<<<(3 * N_TASK + 255) / 256, 256, 0, stream>>>(partials, tmax, tmin);
  } else {
    // ---- fallback: global-atomic path ----
    int* part   = (int*)(ws + WS_BLKM);
    int* partx  = (int*)(ws + WS_BLKM + 4096);
    int* cursor = (int*)(ws + WS_BLKT);
    hipMemsetAsync(ws, 0, 1900000, stream);                 // s/cnt/offs/tmax
    hipMemsetAsync(ws + WS_TMIN, 0xFF, 600000, stream);     // tmin
    const int totalE = E_RET + E_DRAM + E_LINK;
    int nblk_e = (totalE + 255) / 256;
    f_segsum<<<nblk_e, 256, 0, stream>>>(feat_ret, feat_dram, feat_link,
                                         mod_ret, mod_dram, mod_link,
                                         s_ret, s_dram, s_link, cnt);
    f_minmax<<<nblk_e, 256, 0, stream>>>(s_ret, s_dram, s_link,
                                         task_ret, mod_ret, task_dram, mod_dram,
                                         task_link, mod_link, tmax, tmin);
    const int npart = (N_LINK + 255) / 256;  // 391
    f_part<<<npart, 256, 0, stream>>>(cnt, part);
    f_scanpart<<<1, 512, 0, stream>>>(part, partx, npart);
    f_offs<<<npart, 256, 0, stream>>>(cnt, partx, offs, cursor);
    f_scatter<<<(E_LINK + 255) / 256, 256, 0, stream>>>(task_link, mod_link, cursor, csr);
    k_wprep<<<48, 256, 0, stream>>>(W_task, wtb);
  }

  k_taskm<<<(N_TASK / 16 + 3) / 4, 256, 0, stream>>>(W_ret, b_ret, W_dram, b_dram,
                                                     W_link, b_link, wtb, b_task,
                                                     tmax, tmin, hp0, hp1);
  k_link2<<<N_LINK / 8, 256, 0, stream>>>(hp0, offs, cnt, csr, out, 0);
  k_link2<<<N_LINK / 8, 256, 0, stream>>>(hp1, offs, cnt, csr, out, 1);
}

// Round 8
// 348.762 us; speedup vs baseline: 3.5682x; 1.0312x over previous
//
#include <hip/hip_runtime.h>
#include <stdint.h>

#define N_TASK 50000
#define N_RET 20000
#define N_DRAM 5000
#define N_LINK 100000
#define E_RET 1000000
#define E_DRAM 250000
#define E_LINK 2000000

// ---- module-range bucketing ----
#define SBE 4096                // edges per scatter/count block
#define NS_RET 245              // ceil(1e6/4096)
#define NS_DRAM 62
#define NS_LINK 489
#define NS_TOT (NS_RET + NS_DRAM + NS_LINK)   // 796
#define MR_RET 64
#define RSZ_RET 313             // 64*313 = 20032 >= 20000
#define MR_DRAM 16
#define RSZ_DRAM 313
#define MR_LINK 256
#define RSZ_LINK 391            // 256*391 = 100096 >= 100000
#define RECIP313 107203u        // validated rounds 4-7
#define RECIP391 85817u
#define CAPM_RET 16250
#define CAPM_DRAM 16250
#define CAPM_LINK 8255
// m-blkcnt element offsets
#define BM4_RET 0
#define BM4_DRAM (MR_RET * NS_RET)                 // 15680
#define BM4_LINK (BM4_DRAM + MR_DRAM * NS_DRAM)    // 16672
#define BM4_TOT (BM4_LINK + MR_LINK * NS_LINK)     // 141856
// t-blkcnt element offsets (tier-2 only)
#define BT_RET 0
#define BT_DRAM (16 * NS_RET)
#define BT_LINK (BT_DRAM + 16 * NS_DRAM)
#define BT_TOT (BT_LINK + 16 * NS_LINK)

// ---- task-range bucketing (per-task min/max) ----
#define R_PART 3125             // 16*3125 == N_TASK
#define CAP_RET 63800
#define CAP_DRAM 16300
#define CAP_LINK 126800
#define SUB_RET 4
#define SUB_DRAM 1
#define SUB_LINK 8
#define PB_RET 0
#define PB_DRAM (16 * SUB_RET * R_PART)             // 200000
#define PB_LINK (PB_DRAM + 16 * SUB_DRAM * R_PART)  // 250000
#define PB_TOT (PB_LINK + 16 * SUB_LINK * R_PART)   // 650000 words per plane

// ---- workspace byte offsets (shared) ----
#define WS_SRET 0
#define WS_SDRAM 80000
#define WS_SLINK 100000
#define WS_CNT 500000           // 100000 i
#define WS_OFFS 900000          // 100000 i
#define WS_TMAX 1300000         // 150000 u
#define WS_TMIN 1900000         // 150000 u
#define WS_BCNT 2500000         // 48 i (t cursors in tier-1)
#define WS_RCNT 2500192         // 336 i
#define WS_CSR 2501536          // 2M i -> ends 10501536
#define WS_BLKM 10501536        // 141856 i counts -> 11068960
#define WS_BLKB 11068960        // 141856 i bases (tier-1) / blkcnt_t (tier-2)
// mrec region
#define WS_MREC_RET 15701536    // 64*16250*8  -> 24021536
#define WS_MREC_DRAM 24021536   // 16*16250*8  -> 26101536
#define WS_MREC_LINK 26101536   // 256*8255*8  -> 43007776
// ---- tier-1 layout ----
#define WS_PART1 15701536       // partials (5.2MB) alias mrec after msum3
#define WS_HPL0_1 20901536
#define WS_HPL1_1 24101536
#define WS_TREC32_RET 43007776  // 16*63800*4  -> 47090976
#define WS_TREC32_DRAM 47090976 // 16*16300*4  -> 48134176
#define WS_TREC32_LINK 48134176 // 16*126800*4 -> 56249376
#define WS_WTB_1 56249376       // 24576 B
#define WS_NEED1 56273952
// ---- tier-2 (R7) layout ----
#define WS_PART2 10501536
#define WS_TREC_RET 15701536
#define WS_TREC_DRAM 23867936
#define WS_TREC_LINK 25954336
#define WS_HPL0_2 15701536
#define WS_HPL1_2 18901536
#define WS_WTB_2 43007776
#define WS_NEED2 43032352

typedef __attribute__((ext_vector_type(8))) short bf16x8;
typedef __attribute__((ext_vector_type(4))) float f32x4;
typedef unsigned long long u64;

__device__ __forceinline__ unsigned ford(float f) {
  unsigned u = __float_as_uint(f);
  return (u & 0x80000000u) ? ~u : (u | 0x80000000u);
}
__device__ __forceinline__ float funord(unsigned t) {
  unsigned u = (t & 0x80000000u) ? (t & 0x7fffffffu) : ~t;
  return __uint_as_float(u);
}
__device__ __forceinline__ unsigned short bf16rne(float f) {
  unsigned u = __float_as_uint(f);
  return (unsigned short)((u + 0x7fffu + ((u >> 16) & 1u)) >> 16);
}

__device__ __forceinline__ void decode_sblk(int bx, int& e, int& blk, int& E0, int& NB,
                                            int& NR, unsigned& RECIP, int& RSZ, int& base) {
  if (bx < NS_RET) {
    e = 0; blk = bx; E0 = E_RET; NB = NS_RET; NR = MR_RET; RECIP = RECIP313; RSZ = RSZ_RET; base = BM4_RET;
  } else if (bx < NS_RET + NS_DRAM) {
    e = 1; blk = bx - NS_RET; E0 = E_DRAM; NB = NS_DRAM; NR = MR_DRAM; RECIP = RECIP313; RSZ = RSZ_DRAM; base = BM4_DRAM;
  } else {
    e = 2; blk = bx - NS_RET - NS_DRAM; E0 = E_LINK; NB = NS_LINK; NR = MR_LINK; RECIP = RECIP391; RSZ = RSZ_LINK; base = BM4_LINK;
  }
}
__device__ __forceinline__ void decode_stblk(int bx, int& e, int& blk, int& E0, int& NB,
                                             int& baset) {
  if (bx < NS_RET) { e = 0; blk = bx; E0 = E_RET; NB = NS_RET; baset = BT_RET; }
  else if (bx < NS_RET + NS_DRAM) { e = 1; blk = bx - NS_RET; E0 = E_DRAM; NB = NS_DRAM; baset = BT_DRAM; }
  else { e = 2; blk = bx - NS_RET - NS_DRAM; E0 = E_LINK; NB = NS_LINK; baset = BT_LINK; }
}

// =================== TIER-1 kernels ===================

// m-counts [0,796) + wprep [796,844) + tcur zero [844]
__global__ __launch_bounds__(256) void k_count3(
    const int* __restrict__ mr, const int* __restrict__ md, const int* __restrict__ ml,
    const float* __restrict__ W_task, unsigned short* __restrict__ wtb,
    int* __restrict__ blkcnt_m, int* __restrict__ tcur) {
  int bx = blockIdx.x, tid = threadIdx.x;
  if (bx == NS_TOT + 48) {
    if (tid < 48) tcur[tid] = 0;
    return;
  }
  if (bx >= NS_TOT) {
    int i = (bx - NS_TOT) * 256 + tid;
    if (i < 64 * 192) wtb[i] = bf16rne(W_task[i]);
    return;
  }
  __shared__ int c[256];
  int e, blk, E0, NB, NR, RSZ, base; unsigned RECIP;
  decode_sblk(bx, e, blk, E0, NB, NR, RECIP, RSZ, base);
  const int* mod = (e == 0) ? mr : (e == 1) ? md : ml;
  c[tid] = 0;
  __syncthreads();
  int i0 = blk * SBE;
#pragma unroll
  for (int q = 0; q < 16; q++) {
    int i = i0 + q * 256 + tid;
    if (i < E0) {
      int m = mod[i];
      int r = (int)(((u64)(unsigned)m * RECIP) >> 25);
      atomicAdd(&c[r], 1);
    }
  }
  __syncthreads();
  for (int r = tid; r < NR; r += 256)
    blkcnt_m[base + r * NB + blk] = c[r];
}

// scan counts -> blkbase (exclusive), counts preserved; totals -> rcnt
__global__ __launch_bounds__(512) void k_scan3(const int* __restrict__ blkcnt_m,
                                               int* __restrict__ blkbase_m,
                                               int* __restrict__ rcnt) {
  __shared__ int sm[512];
  int gb = blockIdx.x, tid = threadIdx.x;
  int NB, off;
  if (gb < 64) { NB = NS_RET; off = BM4_RET + gb * NS_RET; }
  else if (gb < 80) { NB = NS_DRAM; off = BM4_DRAM + (gb - 64) * NS_DRAM; }
  else { NB = NS_LINK; off = BM4_LINK + (gb - 80) * NS_LINK; }
  int v = (tid < NB) ? blkcnt_m[off + tid] : 0;
  sm[tid] = v;
  __syncthreads();
  for (int d = 1; d < 512; d <<= 1) {
    int x = (tid >= d) ? sm[tid - d] : 0;
    __syncthreads();
    sm[tid] += x;
    __syncthreads();
  }
  if (tid < NB) blkbase_m[off + tid] = sm[tid] - v;
  if (tid == 511) rcnt[gb] = sm[511];
}

// single-pass staged m-scatter (no recount); embeds task for ALL etypes
__global__ __launch_bounds__(256) void k_mscatter3(
    const int* __restrict__ mr, const int* __restrict__ md, const int* __restrict__ ml,
    const int* __restrict__ tr, const int* __restrict__ td, const int* __restrict__ tl,
    const float* __restrict__ fr, const float* __restrict__ fd, const float* __restrict__ fl,
    const int* __restrict__ blkcnt_m, const int* __restrict__ blkbase_m,
    u64* __restrict__ mrec_ret, u64* __restrict__ mrec_dram, u64* __restrict__ mrec_link) {
  __shared__ int lcur[256];
  __shared__ int pdelta[256];
  __shared__ int sscan[256];
  __shared__ u64 srec[SBE];
  __shared__ int sdelta[SBE];
  int tid = threadIdx.x;
  int e, blk, E0, NB, NR, RSZ, base; unsigned RECIP;
  decode_sblk(blockIdx.x, e, blk, E0, NB, NR, RECIP, RSZ, base);
  const int* mod = (e == 0) ? mr : (e == 1) ? md : ml;
  const int* task = (e == 0) ? tr : (e == 1) ? td : tl;
  const float* feat = (e == 0) ? fr : (e == 1) ? fd : fl;
  u64* out = (e == 0) ? mrec_ret : (e == 1) ? mrec_dram : mrec_link;
  int CAP = (e == 0) ? CAPM_RET : (e == 1) ? CAPM_DRAM : CAPM_LINK;
  int cnt_r = (tid < NR) ? blkcnt_m[base + tid * NB + blk] : 0;
  int base_r = (tid < NR) ? blkbase_m[base + tid * NB + blk] : 0;
  sscan[tid] = cnt_r;
  __syncthreads();
  for (int d = 1; d < 256; d <<= 1) {
    int x = (tid >= d) ? sscan[tid - d] : 0;
    __syncthreads();
    sscan[tid] += x;
    __syncthreads();
  }
  int excl = sscan[tid] - cnt_r;
  lcur[tid] = excl;
  pdelta[tid] = tid * CAP + base_r - excl;
  __syncthreads();
  int i0 = blk * SBE;
#pragma unroll
  for (int q = 0; q < 16; q++) {
    int i = i0 + q * 256 + tid;
    if (i < E0) {
      int m = mod[i];
      int r = (int)(((u64)(unsigned)m * RECIP) >> 25);
      unsigned mloc = (unsigned)(m - r * RSZ);
      unsigned tk = (unsigned)task[i];
      unsigned fu = __float_as_uint(feat[i]);
      int slot = atomicAdd(&lcur[r], 1);
      srec[slot] = ((u64)fu << 32) | (tk << 16) | mloc;
      int gpos = pdelta[r] + slot - r * CAP;
      sdelta[slot] = (gpos < CAP) ? pdelta[r] : (int)0x80000000;
    }
  }
  __syncthreads();
  int total = E0 - i0; if (total > SBE) total = SBE;
  for (int s = tid; s < total; s += 256) {
    int d = sdelta[s];
    if (d != (int)0x80000000) out[d + s] = srec[s];
  }
}

// sums (LDS) + link cnt/offs/CSR + direct trec32 emission (deletes ascatter)
__global__ __launch_bounds__(256) void k_msum3(
    const u64* __restrict__ mrec_ret, const u64* __restrict__ mrec_dram,
    const u64* __restrict__ mrec_link, const int* __restrict__ rcnt,
    int* __restrict__ cnt, int* __restrict__ offs, int* __restrict__ csr,
    int* __restrict__ tcur,
    unsigned* __restrict__ trec_ret, unsigned* __restrict__ trec_dram,
    unsigned* __restrict__ trec_link) {
  __shared__ float ssum[RSZ_LINK];
  __shared__ int scnt[RSZ_LINK];
  __shared__ int soff[RSZ_LINK + 1];
  __shared__ int red[256];
  __shared__ int tcnt16[4][16];   // per-wave replicas (contention /4)
  __shared__ int tbase16[4][16];
  int gb = blockIdx.x, tid = threadIdx.x;
  int w = tid >> 6;
  int e, rl, RSZ, CAPM, Ntot, CAPT;
  const u64* p;
  unsigned* trec;
  if (gb < MR_RET) {
    e = 0; rl = gb; p = mrec_ret + (long)rl * CAPM_RET;
    RSZ = RSZ_RET; CAPM = CAPM_RET; Ntot = N_RET; CAPT = CAP_RET; trec = trec_ret;
  } else if (gb < MR_RET + MR_DRAM) {
    e = 1; rl = gb - MR_RET; p = mrec_dram + (long)rl * CAPM_DRAM;
    RSZ = RSZ_DRAM; CAPM = CAPM_DRAM; Ntot = N_DRAM; CAPT = CAP_DRAM; trec = trec_dram;
  } else {
    e = 2; rl = gb - MR_RET - MR_DRAM; p = mrec_link + (long)rl * CAPM_LINK;
    RSZ = RSZ_LINK; CAPM = CAPM_LINK; Ntot = N_LINK; CAPT = CAP_LINK; trec = trec_link;
  }
  int m0 = rl * RSZ;
  int nmod = Ntot - m0; if (nmod > RSZ) nmod = RSZ;
  for (int j = tid; j < RSZ; j += 256) { ssum[j] = 0.f; scnt[j] = 0; }
  if (tid < 64) tcnt16[tid >> 4][tid & 15] = 0;
  __syncthreads();
  int count = rcnt[gb]; if (count > CAPM) count = CAPM;
  for (int i = tid; i < count; i += 256) {
    u64 rec = p[i];
    int mloc = (int)(rec & 0xFFFFull);
    int task = (int)((rec >> 16) & 0xFFFFull);
    atomicAdd(&ssum[mloc], __uint_as_float((unsigned)(rec >> 32)));
    if (e == 2) atomicAdd(&scnt[mloc], 1);
    atomicAdd(&tcnt16[w][task / R_PART], 1);
  }
  __syncthreads();
  if (tid < 64) {
    int w2 = tid >> 4, b2 = tid & 15;
    tbase16[w2][b2] = atomicAdd(&tcur[e * 16 + b2], tcnt16[w2][b2]);
    tcnt16[w2][b2] = 0;  // becomes per-wave cursor
  }
  if (e == 2) {
    // rb = sum of preceding link-range totals
    int partial = (80 + tid < gb) ? rcnt[80 + tid] : 0;
    red[tid] = partial;
    __syncthreads();
    for (int s = 128; s > 0; s >>= 1) {
      if (tid < s) red[tid] += red[tid + s];
      __syncthreads();
    }
    int rb = red[0];
    __syncthreads();
    int a0 = (2 * tid < nmod) ? scnt[2 * tid] : 0;
    int a1 = (2 * tid + 1 < nmod) ? scnt[2 * tid + 1] : 0;
    red[tid] = a0 + a1;
    __syncthreads();
    for (int d = 1; d < 256; d <<= 1) {
      int x = (tid >= d) ? red[tid - d] : 0;
      __syncthreads();
      red[tid] += x;
      __syncthreads();
    }
    int excl = red[tid] - (a0 + a1);
    if (2 * tid < RSZ_LINK) soff[2 * tid] = excl;
    if (2 * tid + 1 < RSZ_LINK) soff[2 * tid + 1] = excl + a0;
    __syncthreads();
    for (int j = tid; j < nmod; j += 256) {
      cnt[m0 + j] = scnt[j];
      offs[m0 + j] = rb + soff[j];
    }
    __syncthreads();
    for (int i = tid; i < count; i += 256) {
      u64 rec = p[i];
      int mloc = (int)(rec & 0xFFFFull);
      int task = (int)((rec >> 16) & 0xFFFFull);
      int lp = atomicAdd(&soff[mloc], 1);
      csr[rb + lp] = task;
    }
  }
  __syncthreads();
  // trec32 emission: (ford(s) & ~0xFFF) | taskLocal12 — truncation is monotone,
  // so bucket max/min of truncated == truncated true max/min (err <= 2^-11 rel).
  for (int i = tid; i < count; i += 256) {
    u64 rec = p[i];
    int mloc = (int)(rec & 0xFFFFull);
    int task = (int)((rec >> 16) & 0xFFFFull);
    int b = task / R_PART;
    unsigned tl12 = (unsigned)(task - b * R_PART);
    unsigned u = (ford(ssum[mloc]) & 0xFFFFF000u) | tl12;
    int local = atomicAdd(&tcnt16[w][b], 1);
    int pos = tbase16[w][b] + local;
    if (pos < CAPT) trec[(long)b * CAPT + pos] = u;
  }
}

__global__ __launch_bounds__(256) void k_passb3(
    const unsigned* __restrict__ trec_ret, const unsigned* __restrict__ trec_dram,
    const unsigned* __restrict__ trec_link,
    const int* __restrict__ tcur, unsigned* __restrict__ partials) {
  __shared__ unsigned lmax[R_PART];
  __shared__ unsigned lmin[R_PART];
  int blk = blockIdx.x;
  int e, b, sub, Nb, PB, CAP;
  const unsigned* bkt;
  if (blk < 16 * SUB_RET) {
    e = 0; b = blk >> 2; sub = blk & 3; Nb = SUB_RET; PB = PB_RET; CAP = CAP_RET; bkt = trec_ret;
  } else if (blk < 16 * (SUB_RET + SUB_DRAM)) {
    int q = blk - 16 * SUB_RET;
    e = 1; b = q; sub = 0; Nb = SUB_DRAM; PB = PB_DRAM; CAP = CAP_DRAM; bkt = trec_dram;
  } else {
    int q = blk - 16 * (SUB_RET + SUB_DRAM);
    e = 2; b = q >> 3; sub = q & 7; Nb = SUB_LINK; PB = PB_LINK; CAP = CAP_LINK; bkt = trec_link;
  }
  for (int idx = threadIdx.x; idx < R_PART; idx += 256) {
    lmax[idx] = 0u;
    lmin[idx] = 0xFFFFFFFFu;
  }
  __syncthreads();
  int count = tcur[e * 16 + b];
  if (count > CAP) count = CAP;
  int chunk = (count + Nb - 1) / Nb;
  int s0 = sub * chunk;
  int s1 = s0 + chunk; if (s1 > count) s1 = count;
  const unsigned* p = bkt + (long)b * CAP;
  for (int i = s0 + threadIdx.x; i < s1; i += 256) {
    unsigned rec = p[i];
    unsigned r = rec & 0xFFFu;  // low 12 bits constant per slot -> full-rec cmp ok
    atomicMax(&lmax[r], rec);
    atomicMin(&lmin[r], rec);
  }
  __syncthreads();
  unsigned gbase = PB + (unsigned)(b * Nb + sub) * R_PART;
  for (int idx = threadIdx.x; idx < R_PART; idx += 256) {
    partials[gbase + idx] = lmax[idx];
    partials[PB_TOT + gbase + idx] = lmin[idx];
  }
}

__global__ __launch_bounds__(256) void k_mmred3(const unsigned* __restrict__ partials,
                                                unsigned* __restrict__ tmax,
                                                unsigned* __restrict__ tmin) {
  int gid = blockIdx.x * 256 + threadIdx.x;
  if (gid >= 3 * N_TASK) return;
  int e = gid / N_TASK;
  int t = gid - e * N_TASK;
  int Nb = (e == 0) ? SUB_RET : (e == 1) ? SUB_DRAM : SUB_LINK;
  int PB = (e == 0) ? PB_RET : (e == 1) ? PB_DRAM : PB_LINK;
  int b = t / R_PART;
  int r = t - b * R_PART;
  unsigned umax = 0u, umin = 0xFFFFFFFFu;
  for (int sub = 0; sub < Nb; sub++) {
    unsigned idx = PB + (unsigned)(b * Nb + sub) * R_PART + r;
    unsigned wv = partials[idx];
    if (wv > umax) umax = wv;
    unsigned w2 = partials[PB_TOT + idx];
    if (w2 < umin) umin = w2;
  }
  tmax[gid] = umax & 0xFFFFF000u;  // 0 iff no edges (sentinel)
  tmin[gid] = umin & 0xFFFFF000u;
}

// =================== TIER-2 kernels (R7 path, unchanged) ===================

__global__ __launch_bounds__(256) void k_count(
    const int* __restrict__ mr, const int* __restrict__ md, const int* __restrict__ ml,
    const int* __restrict__ tr, const int* __restrict__ td, const int* __restrict__ tl,
    const float* __restrict__ W_task, unsigned short* __restrict__ wtb,
    int* __restrict__ blkcnt_m, int* __restrict__ blkcnt_t) {
  int bx = blockIdx.x, tid = threadIdx.x;
  if (bx >= 2 * NS_TOT) {
    int i = (bx - 2 * NS_TOT) * 256 + tid;
    if (i < 64 * 192) wtb[i] = bf16rne(W_task[i]);
    return;
  }
  __shared__ int c[256];
  c[tid] = 0;
  __syncthreads();
  if (bx < NS_TOT) {
    int e, blk, E0, NB, NR, RSZ, base; unsigned RECIP;
    decode_sblk(bx, e, blk, E0, NB, NR, RECIP, RSZ, base);
    const int* mod = (e == 0) ? mr : (e == 1) ? md : ml;
    int i0 = blk * SBE;
#pragma unroll
    for (int q = 0; q < 16; q++) {
      int i = i0 + q * 256 + tid;
      if (i < E0) {
        int m = mod[i];
        int r = (int)(((u64)(unsigned)m * RECIP) >> 25);
        atomicAdd(&c[r], 1);
      }
    }
    __syncthreads();
    for (int r = tid; r < NR; r += 256)
      blkcnt_m[base + r * NB + blk] = c[r];
  } else {
    int e, blk, E0, NB, baset;
    decode_stblk(bx - NS_TOT, e, blk, E0, NB, baset);
    const int* task = (e == 0) ? tr : (e == 1) ? td : tl;
    int i0 = blk * SBE;
#pragma unroll
    for (int q = 0; q < 16; q++) {
      int i = i0 + q * 256 + tid;
      if (i < E0) atomicAdd(&c[task[i] / R_PART], 1);
    }
    __syncthreads();
    if (tid < 16) blkcnt_t[baset + tid * NB + blk] = c[tid];
  }
}

__global__ __launch_bounds__(512) void k_scan(int* __restrict__ blkcnt_m,
                                              int* __restrict__ blkcnt_t,
                                              int* __restrict__ rcnt, int* __restrict__ bcnt) {
  __shared__ int sm[512];
  int gb = blockIdx.x, tid = threadIdx.x;
  int* arr; int NB; int* outp;
  if (gb < 336) {
    int off;
    if (gb < 64) { NB = NS_RET; off = BM4_RET + gb * NS_RET; }
    else if (gb < 80) { NB = NS_DRAM; off = BM4_DRAM + (gb - 64) * NS_DRAM; }
    else { NB = NS_LINK; off = BM4_LINK + (gb - 80) * NS_LINK; }
    arr = blkcnt_m + off; outp = rcnt + gb;
  } else {
    int g = gb - 336; int e = g >> 4, b = g & 15;
    int NBe = (e == 0) ? NS_RET : (e == 1) ? NS_DRAM : NS_LINK;
    int baset = (e == 0) ? BT_RET : (e == 1) ? BT_DRAM : BT_LINK;
    NB = NBe; arr = blkcnt_t + baset + b * NBe; outp = bcnt + g;
  }
  int v = (tid < NB) ? arr[tid] : 0;
  sm[tid] = v;
  __syncthreads();
  for (int d = 1; d < 512; d <<= 1) {
    int x = (tid >= d) ? sm[tid - d] : 0;
    __syncthreads();
    sm[tid] += x;
    __syncthreads();
  }
  if (tid < NB) arr[tid] = sm[tid] - v;
  if (tid == 511) *outp = sm[511];
}

__global__ __launch_bounds__(256) void k_mscatter2(
    const int* __restrict__ mr, const int* __restrict__ md, const int* __restrict__ ml,
    const int* __restrict__ tl,
    const float* __restrict__ fr, const float* __restrict__ fd, const float* __restrict__ fl,
    const int* __restrict__ blkcnt_m,
    u64* __restrict__ mrec_ret, u64* __restrict__ mrec_dram, u64* __restrict__ mrec_link) {
  __shared__ int lcur[256];
  __shared__ int pdelta[256];
  __shared__ int sscan[256];
  __shared__ u64 srec[SBE];
  __shared__ int sdelta[SBE];
  int tid = threadIdx.x;
  int e, blk, E0, NB, NR, RSZ, base; unsigned RECIP;
  decode_sblk(blockIdx.x, e, blk, E0, NB, NR, RECIP, RSZ, base);
  const int* mod = (e == 0) ? mr : (e == 1) ? md : ml;
  const float* feat = (e == 0) ? fr : (e == 1) ? fd : fl;
  u64* out = (e == 0) ? mrec_ret : (e == 1) ? mrec_dram : mrec_link;
  int CAP = (e == 0) ? CAPM_RET : (e == 1) ? CAPM_DRAM : CAPM_LINK;
  lcur[tid] = 0;
  __syncthreads();
  int i0 = blk * SBE;
#pragma unroll
  for (int q = 0; q < 16; q++) {
    int i = i0 + q * 256 + tid;
    if (i < E0) {
      int m = mod[i];
      int r = (int)(((u64)(unsigned)m * RECIP) >> 25);
      atomicAdd(&lcur[r], 1);
    }
  }
  __syncthreads();
  int v = lcur[tid];
  sscan[tid] = v;
  __syncthreads();
  for (int d = 1; d < 256; d <<= 1) {
    int x = (tid >= d) ? sscan[tid - d] : 0;
    __syncthreads();
    sscan[tid] += x;
    __syncthreads();
  }
  int excl = sscan[tid] - v;
  int total = sscan[255];
  int gbv = (tid < NR) ? blkcnt_m[base + tid * NB + blk] : 0;
  __syncthreads();
  lcur[tid] = excl;
  pdelta[tid] = tid * CAP + gbv - excl;
  __syncthreads();
#pragma unroll
  for (int q = 0; q < 16; q++) {
    int i = i0 + q * 256 + tid;
    if (i < E0) {
      int m = mod[i];
      int r = (int)(((u64)(unsigned)m * RECIP) >> 25);
      unsigned mloc = (unsigned)(m - r * RSZ);
      unsigned task = (e == 2) ? (unsigned)tl[i] : 0u;
      unsigned fu = __float_as_uint(feat[i]);
      int slot = atomicAdd(&lcur[r], 1);
      srec[slot] = ((u64)fu << 32) | (task << 16) | mloc;
      int gpos = pdelta[r] + slot - r * CAP;
      sdelta[slot] = (gpos < CAP) ? pdelta[r] : (int)0x80000000;
    }
  }
  __syncthreads();
  for (int s = tid; s < total; s += 256) {
    int d = sdelta[s];
    if (d != (int)0x80000000) out[d + s] = srec[s];
  }
}

__global__ __launch_bounds__(256) void k_msum(
    const u64* __restrict__ mrec_ret, const u64* __restrict__ mrec_dram,
    const u64* __restrict__ mrec_link, const int* __restrict__ rcnt,
    float* __restrict__ s_ret, float* __restrict__ s_dram, float* __restrict__ s_link,
    int* __restrict__ cnt, int* __restrict__ offs, int* __restrict__ csr) {
  __shared__ float ssum[RSZ_LINK];
  __shared__ int scnt[RSZ_LINK];
  __shared__ int soff[RSZ_LINK + 1];
  __shared__ int red[256];
  int gb = blockIdx.x, tid = threadIdx.x;
  int e, rl, RSZ, CAP, Ntot;
  const u64* p;
  float* sout;
  if (gb < MR_RET) {
    e = 0; rl = gb; p = mrec_ret + (long)rl * CAPM_RET; sout = s_ret;
    RSZ = RSZ_RET; CAP = CAPM_RET; Ntot = N_RET;
  } else if (gb < MR_RET + MR_DRAM) {
    e = 1; rl = gb - MR_RET; p = mrec_dram + (long)rl * CAPM_DRAM; sout = s_dram;
    RSZ = RSZ_DRAM; CAP = CAPM_DRAM; Ntot = N_DRAM;
  } else {
    e = 2; rl = gb - MR_RET - MR_DRAM; p = mrec_link + (long)rl * CAPM_LINK; sout = s_link;
    RSZ = RSZ_LINK; CAP = CAPM_LINK; Ntot = N_LINK;
  }
  int m0 = rl * RSZ;
  int nmod = Ntot - m0; if (nmod > RSZ) nmod = RSZ;
  for (int j = tid; j < RSZ; j += 256) { ssum[j] = 0.f; scnt[j] = 0; }
  __syncthreads();
  int count = rcnt[gb]; if (count > CAP) count = CAP;
  for (int i = tid; i < count; i += 256) {
    u64 rec = p[i];
    int mloc = (int)(rec & 0xFFFFull);
    atomicAdd(&ssum[mloc], __uint_as_float((unsigned)(rec >> 32)));
    if (e == 2) atomicAdd(&scnt[mloc], 1);
  }
  __syncthreads();
  for (int j = tid; j < nmod; j += 256) sout[m0 + j] = ssum[j];
  if (e != 2) return;
  int partial = (80 + tid < gb) ? rcnt[80 + tid] : 0;
  red[tid] = partial;
  __syncthreads();
  for (int s = 128; s > 0; s >>= 1) {
    if (tid < s) red[tid] += red[tid + s];
    __syncthreads();
  }
  int rb = red[0];
  __syncthreads();
  int a0 = (2 * tid < nmod) ? scnt[2 * tid] : 0;
  int a1 = (2 * tid + 1 < nmod) ? scnt[2 * tid + 1] : 0;
  red[tid] = a0 + a1;
  __syncthreads();
  for (int d = 1; d < 256; d <<= 1) {
    int x = (tid >= d) ? red[tid - d] : 0;
    __syncthreads();
    red[tid] += x;
    __syncthreads();
  }
  int excl = red[tid] - (a0 + a1);
  if (2 * tid < RSZ_LINK) soff[2 * tid] = excl;
  if (2 * tid + 1 < RSZ_LINK) soff[2 * tid + 1] = excl + a0;
  __syncthreads();
  for (int j = tid; j < nmod; j += 256) {
    cnt[m0 + j] = scnt[j];
    offs[m0 + j] = rb + soff[j];
  }
  __syncthreads();
  for (int i = tid; i < count; i += 256) {
    u64 rec = p[i];
    int mloc = (int)(rec & 0xFFFFull);
    int task = (int)((rec >> 16) & 0xFFFFull);
    int lp = atomicAdd(&soff[mloc], 1);
    csr[rb + lp] = task;
  }
}

__global__ __launch_bounds__(256) void k_ascatter2(
    const int* __restrict__ tr, const int* __restrict__ mr,
    const int* __restrict__ td, const int* __restrict__ md,
    const int* __restrict__ tl, const int* __restrict__ ml,
    const float* __restrict__ s_ret, const float* __restrict__ s_dram,
    const float* __restrict__ s_link, const int* __restrict__ blkcnt_t,
    u64* __restrict__ trec_ret, u64* __restrict__ trec_dram, u64* __restrict__ trec_link) {
  __shared__ int lcur[256];
  __shared__ int pdelta[256];
  __shared__ int sscan[256];
  __shared__ u64 srec[SBE];
  __shared__ int sdelta[SBE];
  int tid = threadIdx.x;
  int e, blk, E0, NB, baset;
  decode_stblk(blockIdx.x, e, blk, E0, NB, baset);
  const int* task = (e == 0) ? tr : (e == 1) ? td : tl;
  const int* mod = (e == 0) ? mr : (e == 1) ? md : ml;
  const float* s = (e == 0) ? s_ret : (e == 1) ? s_dram : s_link;
  u64* out = (e == 0) ? trec_ret : (e == 1) ? trec_dram : trec_link;
  int CAP = (e == 0) ? CAP_RET : (e == 1) ? CAP_DRAM : CAP_LINK;
  lcur[tid] = 0;
  __syncthreads();
  int i0 = blk * SBE;
#pragma unroll
  for (int q = 0; q < 16; q++) {
    int i = i0 + q * 256 + tid;
    if (i < E0) atomicAdd(&lcur[task[i] / R_PART], 1);
  }
  __syncthreads();
  int v = lcur[tid];
  sscan[tid] = v;
  __syncthreads();
  for (int d = 1; d < 256; d <<= 1) {
    int x = (tid >= d) ? sscan[tid - d] : 0;
    __syncthreads();
    sscan[tid] += x;
    __syncthreads();
  }
  int excl = sscan[tid] - v;
  int total = sscan[255];
  int gbv = (tid < 16) ? blkcnt_t[baset + tid * NB + blk] : 0;
  __syncthreads();
  lcur[tid] = excl;
  pdelta[tid] = tid * CAP + gbv - excl;
  __syncthreads();
#pragma unroll
  for (int q = 0; q < 16; q++) {
    int i = i0 + q * 256 + tid;
    if (i < E0) {
      int t = task[i];
      int r = t / R_PART;
      unsigned rloc = (unsigned)(t - r * R_PART);
      unsigned u = ford(s[mod[i]]);
      int slot = atomicAdd(&lcur[r], 1);
      srec[slot] = ((u64)u << 32) | rloc;
      int gpos = pdelta[r] + slot - r * CAP;
      sdelta[slot] = (gpos < CAP) ? pdelta[r] : (int)0x80000000;
    }
  }
  __syncthreads();
  for (int sidx = tid; sidx < total; sidx += 256) {
    int d = sdelta[sidx];
    if (d != (int)0x80000000) out[d + sidx] = srec[sidx];
  }
}

__global__ __launch_bounds__(256) void k_passb(
    const u64* __restrict__ trec_ret, const u64* __restrict__ trec_dram,
    const u64* __restrict__ trec_link,
    const int* __restrict__ bcnt, unsigned* __restrict__ partials) {
  __shared__ unsigned lmax[R_PART];
  __shared__ unsigned lmin[R_PART];
  int blk = blockIdx.x;
  int e, b, sub, Nb, PB, CAP;
  const u64* bkt;
  if (blk < 16 * SUB_RET) {
    e = 0; b = blk >> 2; sub = blk & 3; Nb = SUB_RET; PB = PB_RET; CAP = CAP_RET; bkt = trec_ret;
  } else if (blk < 16 * (SUB_RET + SUB_DRAM)) {
    int q = blk - 16 * SUB_RET;
    e = 1; b = q; sub = 0; Nb = SUB_DRAM; PB = PB_DRAM; CAP = CAP_DRAM; bkt = trec_dram;
  } else {
    int q = blk - 16 * (SUB_RET + SUB_DRAM);
    e = 2; b = q >> 3; sub = q & 7; Nb = SUB_LINK; PB = PB_LINK; CAP = CAP_LINK; bkt = trec_link;
  }
  for (int idx = threadIdx.x; idx < R_PART; idx += 256) {
    lmax[idx] = 0u;
    lmin[idx] = 0xFFFFFFFFu;
  }
  __syncthreads();
  int count = bcnt[e * 16 + b];
  if (count > CAP) count = CAP;
  int chunk = (count + Nb - 1) / Nb;
  int s0 = sub * chunk;
  int s1 = s0 + chunk; if (s1 > count) s1 = count;
  const u64* p = bkt + (long)b * CAP;
  for (int i = s0 + threadIdx.x; i < s1; i += 256) {
    u64 rec = p[i];
    unsigned r = (unsigned)rec;
    unsigned u = (unsigned)(rec >> 32);
    atomicMax(&lmax[r], u);
    atomicMin(&lmin[r], u);
  }
  __syncthreads();
  unsigned gbase = PB + (unsigned)(b * Nb + sub) * R_PART;
  for (int idx = threadIdx.x; idx < R_PART; idx += 256) {
    partials[gbase + idx] = lmax[idx];
    partials[PB_TOT + gbase + idx] = lmin[idx];
  }
}

__global__ __launch_bounds__(256) void k_mmred2(const unsigned* __restrict__ partials,
                                                unsigned* __restrict__ tmax,
                                                unsigned* __restrict__ tmin) {
  int gid = blockIdx.x * 256 + threadIdx.x;
  if (gid >= 3 * N_TASK) return;
  int e = gid / N_TASK;
  int t = gid - e * N_TASK;
  int Nb = (e == 0) ? SUB_RET : (e == 1) ? SUB_DRAM : SUB_LINK;
  int PB = (e == 0) ? PB_RET : (e == 1) ? PB_DRAM : PB_LINK;
  int b = t / R_PART;
  int r = t - b * R_PART;
  unsigned umax = 0u, umin = 0xFFFFFFFFu;
  for (int sub = 0; sub < Nb; sub++) {
    unsigned idx = PB + (unsigned)(b * Nb + sub) * R_PART + r;
    unsigned wv = partials[idx];
    if (wv > umax) umax = wv;
    unsigned w2 = partials[PB_TOT + idx];
    if (w2 < umin) umin = w2;
  }
  tmax[gid] = umax;
  tmin[gid] = umin;
}

// =================== TIER-3 fallback ===================

__global__ void k_wprep(const float* __restrict__ W_task, unsigned short* __restrict__ wtb) {
  int i = blockIdx.x * 256 + threadIdx.x;
  if (i < 64 * 192) wtb[i] = bf16rne(W_task[i]);
}

__global__ void f_segsum(const float* __restrict__ fr, const float* __restrict__ fd,
                         const float* __restrict__ fl,
                         const int* __restrict__ mr, const int* __restrict__ md,
                         const int* __restrict__ ml,
                         float* s_ret, float* s_dram, float* s_link, int* cnt) {
  int i = blockIdx.x * blockDim.x + threadIdx.x;
  const int total = E_RET + E_DRAM + E_LINK;
  if (i >= total) return;
  if (i < E_RET) {
    atomicAdd(&s_ret[mr[i]], fr[i]);
  } else if (i < E_RET + E_DRAM) {
    int j = i - E_RET;
    atomicAdd(&s_dram[md[j]], fd[j]);
  } else {
    int j = i - (E_RET + E_DRAM);
    int m = ml[j];
    atomicAdd(&s_link[m], fl[j]);
    atomicAdd(&cnt[m], 1);
  }
}

__global__ void f_minmax(const float* __restrict__ s_ret, const float* __restrict__ s_dram,
                         const float* __restrict__ s_link,
                         const int* __restrict__ tr, const int* __restrict__ mr,
                         const int* __restrict__ td, const int* __restrict__ md,
                         const int* __restrict__ tl, const int* __restrict__ ml,
                         unsigned* tmax, unsigned* tmin) {
  int i = blockIdx.x * blockDim.x + threadIdx.x;
  const int total = E_RET + E_DRAM + E_LINK;
  if (i >= total) return;
  int e, task; unsigned u;
  if (i < E_RET) {
    u = ford(s_ret[mr[i]]); task = tr[i]; e = 0;
  } else if (i < E_RET + E_DRAM) {
    int j = i - E_RET;
    u = ford(s_dram[md[j]]); task = td[j]; e = 1;
  } else {
    int j = i - (E_RET + E_DRAM);
    u = ford(s_link[ml[j]]); task = tl[j]; e = 2;
  }
  atomicMax(&tmax[e * N_TASK + task], u);
  atomicMin(&tmin[e * N_TASK + task], u);
}

__global__ void f_part(const int* __restrict__ cnt, int* part) {
  __shared__ int sm[256];
  int i = blockIdx.x * 256 + threadIdx.x;
  sm[threadIdx.x] = (i < N_LINK) ? cnt[i] : 0;
  __syncthreads();
  for (int s = 128; s > 0; s >>= 1) {
    if (threadIdx.x < s) sm[threadIdx.x] += sm[threadIdx.x + s];
    __syncthreads();
  }
  if (threadIdx.x == 0) part[blockIdx.x] = sm[0];
}

__global__ void f_scanpart(const int* __restrict__ part, int* partx, int npart) {
  __shared__ int sm[512];
  int t = threadIdx.x;
  int v = (t < npart) ? part[t] : 0;
  sm[t] = v;
  __syncthreads();
  for (int d = 1; d < 512; d <<= 1) {
    int x = (t >= d) ? sm[t - d] : 0;
    __syncthreads();
    sm[t] += x;
    __syncthreads();
  }
  if (t < npart) partx[t] = sm[t] - v;
}

__global__ void f_offs(const int* __restrict__ cnt, const int* __restrict__ partx,
                       int* offs, int* cursor) {
  __shared__ int sm[256];
  int i = blockIdx.x * 256 + threadIdx.x;
  int t = threadIdx.x;
  int v = (i < N_LINK) ? cnt[i] : 0;
  sm[t] = v;
  __syncthreads();
  for (int d = 1; d < 256; d <<= 1) {
    int x = (t >= d) ? sm[t - d] : 0;
    __syncthreads();
    sm[t] += x;
    __syncthreads();
  }
  if (i < N_LINK) {
    int o = partx[blockIdx.x] + sm[t] - v;
    offs[i] = o;
    cursor[i] = o;
  }
}

__global__ void f_scatter(const int* __restrict__ tl, const int* __restrict__ ml,
                          int* cursor, int* csr) {
  int i = blockIdx.x * blockDim.x + threadIdx.x;
  if (i >= E_LINK) return;
  int pos = atomicAdd(&cursor[ml[i]], 1);
  csr[pos] = tl[i];
}

// =================== shared tail: task GEMM (MFMA) + link mean ===================

__global__ __launch_bounds__(256) void k_taskm(
    const float* __restrict__ W_ret, const float* __restrict__ b_ret,
    const float* __restrict__ W_dram, const float* __restrict__ b_dram,
    const float* __restrict__ W_link, const float* __restrict__ b_link,
    const unsigned short* __restrict__ wtb, const float* __restrict__ b_task,
    const unsigned* __restrict__ tmax, const unsigned* __restrict__ tmin,
    unsigned short* __restrict__ hp0, unsigned short* __restrict__ hp1) {
  int wave = threadIdx.x >> 6;
  int lane = threadIdx.x & 63;
  int tile = blockIdx.x * 4 + wave;
  if (tile >= N_TASK / 16) return;
  int t0 = tile * 16;
  int l16 = lane & 15;
  int quad = lane >> 4;
  int t = t0 + l16;

  f32x4 acc[4];
#pragma unroll
  for (int nf = 0; nf < 4; nf++) acc[nf] = (f32x4){0.f, 0.f, 0.f, 0.f};

  const float* We[3] = {W_ret, W_dram, W_link};
  const float* be[3] = {b_ret, b_dram, b_link};

  for (int e = 0; e < 3; e++) {
    unsigned um = tmax[e * N_TASK + t];
    float smax = funord(um);
    float smin = funord(tmin[e * N_TASK + t]);
    bool live = (um != 0u);
#pragma unroll
    for (int h = 0; h < 2; h++) {
      int kb = h * 32 + quad * 8;
      float4 w0 = *(const float4*)&We[e][kb];
      float4 w1 = *(const float4*)&We[e][kb + 4];
      float4 b0 = *(const float4*)&be[e][kb];
      float4 b1 = *(const float4*)&be[e][kb + 4];
      float wv[8] = {w0.x, w0.y, w0.z, w0.w, w1.x, w1.y, w1.z, w1.w};
      float bv[8] = {b0.x, b0.y, b0.z, b0.w, b1.x, b1.y, b1.z, b1.w};
      bf16x8 afrag;
#pragma unroll
      for (int j = 0; j < 8; j++) {
        float wj = wv[j];
        float ss = (wj >= 0.f) ? smax : smin;
        float hc = live ? tanhf(fmaf(ss, wj, bv[j])) : 0.f;
        afrag[j] = (short)bf16rne(hc);
      }
      int kk = e * 64 + h * 32 + quad * 8;
#pragma unroll
      for (int nf = 0; nf < 4; nf++) {
        int o = nf * 16 + l16;
        bf16x8 bfrag = *(const bf16x8*)&wtb[o * 192 + kk];
        acc[nf] = __builtin_amdgcn_mfma_f32_16x16x32_bf16(afrag, bfrag, acc[nf], 0, 0, 0);
      }
    }
  }

#pragma unroll
  for (int nf = 0; nf < 4; nf++) {
    int n = nf * 16 + l16;
    float bt = b_task[n];
    unsigned short* hp = (n < 32) ? hp0 : hp1;
    int f = n & 31;
#pragma unroll
    for (int r = 0; r < 4; r++) {
      int m = quad * 4 + r;
      float v = tanhf(acc[nf][r] + bt);
      hp[(t0 + m) * 32 + f] = bf16rne(v);
    }
  }
}

__global__ __launch_bounds__(256) void k_link2(const unsigned short* __restrict__ hp,
                                               const int* __restrict__ offs,
                                               const int* __restrict__ cnt,
                                               const int* __restrict__ csr,
                                               float* __restrict__ out, int plane) {
  int l = blockIdx.x * 8 + (threadIdx.x >> 5);
  int f = threadIdx.x & 31;
  int start = offs[l];
  int c = cnt[l];
  float acc = 0.f;
  for (int q = 0; q < c; q += 4) {
    int i1 = (q + 1 < c) ? q + 1 : c - 1;
    int i2 = (q + 2 < c) ? q + 2 : c - 1;
    int i3 = (q + 3 < c) ? q + 3 : c - 1;
    int t0 = csr[start + q];
    int t1 = csr[start + i1];
    int t2 = csr[start + i2];
    int t3 = csr[start + i3];
    unsigned v0 = hp[t0 * 32 + f];
    unsigned v1 = hp[t1 * 32 + f];
    unsigned v2 = hp[t2 * 32 + f];
    unsigned v3 = hp[t3 * 32 + f];
    acc += __uint_as_float(v0 << 16);
    if (q + 1 < c) acc += __uint_as_float(v1 << 16);
    if (q + 2 < c) acc += __uint_as_float(v2 << 16);
    if (q + 3 < c) acc += __uint_as_float(v3 << 16);
  }
  out[l * 64 + plane * 32 + f] = (c > 0) ? acc / (float)c : 0.f;
}

extern "C" void kernel_launch(void* const* d_in, const int* in_sizes, int n_in,
                              void* d_out, int out_size, void* d_ws, size_t ws_size,
                              hipStream_t stream) {
  const float* feat_ret  = (const float*)d_in[0];
  const float* feat_dram = (const float*)d_in[1];
  const float* feat_link = (const float*)d_in[2];
  const float* W_ret  = (const float*)d_in[3];
  const float* b_ret  = (const float*)d_in[4];
  const float* W_dram = (const float*)d_in[5];
  const float* b_dram = (const float*)d_in[6];
  const float* W_link = (const float*)d_in[7];
  const float* b_link = (const float*)d_in[8];
  const float* W_task = (const float*)d_in[9];
  const float* b_task = (const float*)d_in[10];
  const int* task_ret  = (const int*)d_in[11];
  const int* mod_ret   = (const int*)d_in[12];
  const int* task_dram = (const int*)d_in[13];
  const int* mod_dram  = (const int*)d_in[14];
  const int* task_link = (const int*)d_in[15];
  const int* mod_link  = (const int*)d_in[16];
  float* out = (float*)d_out;

  char* ws = (char*)d_ws;
  float* s_ret  = (float*)(ws + WS_SRET);
  float* s_dram = (float*)(ws + WS_SDRAM);
  float* s_link = (float*)(ws + WS_SLINK);
  int*   cnt    = (int*)(ws + WS_CNT);
  int*   offs   = (int*)(ws + WS_OFFS);
  unsigned* tmax = (unsigned*)(ws + WS_TMAX);
  unsigned* tmin = (unsigned*)(ws + WS_TMIN);
  int* tcur = (int*)(ws + WS_BCNT);
  int* rcnt = (int*)(ws + WS_RCNT);
  int* csr  = (int*)(ws + WS_CSR);
  int* blkcnt_m = (int*)(ws + WS_BLKM);
  int* blkb = (int*)(ws + WS_BLKB);  // blkbase (tier-1) / blkcnt_t (tier-2)
  u64* mrec_ret  = (u64*)(ws + WS_MREC_RET);
  u64* mrec_dram = (u64*)(ws + WS_MREC_DRAM);
  u64* mrec_link = (u64*)(ws + WS_MREC_LINK);

  unsigned short* hp0;
  unsigned short* hp1;
  unsigned short* wtb;

  if (ws_size >= (size_t)WS_NEED1) {
    // ---- tier-1: no ascatter, 4B trecs, single-pass mscatter ----
    unsigned* partials = (unsigned*)(ws + WS_PART1);
    unsigned* trec_ret  = (unsigned*)(ws + WS_TREC32_RET);
    unsigned* trec_dram = (unsigned*)(ws + WS_TREC32_DRAM);
    unsigned* trec_link = (unsigned*)(ws + WS_TREC32_LINK);
    hp0 = (unsigned short*)(ws + WS_HPL0_1);
    hp1 = (unsigned short*)(ws + WS_HPL1_1);
    wtb = (unsigned short*)(ws + WS_WTB_1);
    k_count3<<<NS_TOT + 49, 256, 0, stream>>>(mod_ret, mod_dram, mod_link,
                                              W_task, wtb, blkcnt_m, tcur);
    k_scan3<<<336, 512, 0, stream>>>(blkcnt_m, blkb, rcnt);
    k_mscatter3<<<NS_TOT, 256, 0, stream>>>(mod_ret, mod_dram, mod_link,
                                            task_ret, task_dram, task_link,
                                            feat_ret, feat_dram, feat_link,
                                            blkcnt_m, blkb,
                                            mrec_ret, mrec_dram, mrec_link);
    k_msum3<<<336, 256, 0, stream>>>(mrec_ret, mrec_dram, mrec_link, rcnt,
                                     cnt, offs, csr, tcur,
                                     trec_ret, trec_dram, trec_link);
    k_passb3<<<16 * (SUB_RET + SUB_DRAM + SUB_LINK), 256, 0, stream>>>(
        trec_ret, trec_dram, trec_link, tcur, partials);
    k_mmred3<<<(3 * N_TASK + 255) / 256, 256, 0, stream>>>(partials, tmax, tmin);
  } else if (ws_size >= (size_t)WS_NEED2) {
    // ---- tier-2: R7 path ----
    unsigned* partials = (unsigned*)(ws + WS_PART2);
    u64* trec_ret  = (u64*)(ws + WS_TREC_RET);
    u64* trec_dram = (u64*)(ws + WS_TREC_DRAM);
    u64* trec_link = (u64*)(ws + WS_TREC_LINK);
    hp0 = (unsigned short*)(ws + WS_HPL0_2);
    hp1 = (unsigned short*)(ws + WS_HPL1_2);
    wtb = (unsigned short*)(ws + WS_WTB_2);
    k_count<<<2 * NS_TOT + 48, 256, 0, stream>>>(mod_ret, mod_dram, mod_link,
                                                 task_ret, task_dram, task_link,
                                                 W_task, wtb, blkcnt_m, blkb);
    k_scan<<<384, 512, 0, stream>>>(blkcnt_m, blkb, rcnt, tcur);
    k_mscatter2<<<NS_TOT, 256, 0, stream>>>(mod_ret, mod_dram, mod_link, task_link,
                                            feat_ret, feat_dram, feat_link, blkcnt_m,
                                            mrec_ret, mrec_dram, mrec_link);
    k_msum<<<336, 256, 0, stream>>>(mrec_ret, mrec_dram, mrec_link, rcnt,
                                    s_ret, s_dram, s_link, cnt, offs, csr);
    k_ascatter2<<<NS_TOT, 256, 0, stream>>>(task_ret, mod_ret, task_dram, mod_dram,
                                            task_link, mod_link, s_ret, s_dram, s_link,
                                            blkb, trec_ret, trec_dram, trec_link);
    k_passb<<<16 * (SUB_RET + SUB_DRAM + SUB_LINK), 256, 0, stream>>>(
        trec_ret, trec_dram, trec_link, tcur, partials);
    k_mmred2<<<(3 * N_TASK + 255) / 256, 256, 0, stream>>>(partials, tmax, tmin);
  } else {
    // ---- tier-3: global-atomic fallback ----
    int* part   = (int*)(ws + WS_BLKM);
    int* partx  = (int*)(ws + WS_BLKM + 4096);
    int* cursor = (int*)(ws + WS_BLKB);
    hp0 = (unsigned short*)(ws + WS_HPL0_2);
    hp1 = (unsigned short*)(ws + WS_HPL1_2);
    wtb = (unsigned short*)(ws + WS_WTB_2);
    hipMemsetAsync(ws, 0, 1900000, stream);
    hipMemsetAsync(ws + WS_TMIN, 0xFF, 600000, stream);
    const int totalE = E_RET + E_DRAM + E_LINK;
    int nblk_e = (totalE + 255) / 256;
    f_segsum<<<nblk_e, 256, 0, stream>>>(feat_ret, feat_dram, feat_link,
                                         mod_ret, mod_dram, mod_link,
                                         s_ret, s_dram, s_link, cnt);
    f_minmax<<<nblk_e, 256, 0, stream>>>(s_ret, s_dram, s_link,
                                         task_ret, mod_ret, task_dram, mod_dram,
                                         task_link, mod_link, tmax, tmin);
    const int npart = (N_LINK + 255) / 256;
    f_part<<<npart, 256, 0, stream>>>(cnt, part);
    f_scanpart<<<1, 512, 0, stream>>>(part, partx, npart);
    f_offs<<<npart, 256, 0, stream>>>(cnt, partx, offs, cursor);
    f_scatter<<<(E_LINK + 255) / 256, 256, 0, stream>>>(task_link, mod_link, cursor, csr);
    k_wprep<<<48, 256, 0, stream>>>(W_task, wtb);
  }

  k_taskm<<<(N_TASK / 16 + 3) / 4, 256, 0, stream>>>(W_ret, b_ret, W_dram, b_dram,
                                                     W_link, b_link, wtb, b_task,
                                                     tmax, tmin, hp0, hp1);
  k_link2<<<N_LINK / 8, 256, 0, stream>>>(hp0, offs, cnt, csr, out, 0);
  k_link2<<<N_LINK / 8, 256, 0, stream>>>(hp1, offs, cnt, csr, out, 1);
}

// Round 9
// 309.671 us; speedup vs baseline: 4.0187x; 1.1262x over previous
//
#include <hip/hip_runtime.h>
#include <stdint.h>

#define N_TASK 50000
#define N_RET 20000
#define N_DRAM 5000
#define N_LINK 100000
#define E_RET 1000000
#define E_DRAM 250000
#define E_LINK 2000000

// ---- module-range bucketing ----
#define SBE 4096                // edges per scatter/count block
#define NS_RET 245              // ceil(1e6/4096)
#define NS_DRAM 62
#define NS_LINK 489
#define NS_TOT (NS_RET + NS_DRAM + NS_LINK)   // 796
#define MR_RET 64
#define RSZ_RET 313             // 64*313 = 20032 >= 20000
#define MR_DRAM 16
#define RSZ_DRAM 313
#define MR_LINK 256
#define RSZ_LINK 391            // 256*391 = 100096 >= 100000
#define RECIP313 107203u        // validated rounds 4-8
#define RECIP391 85817u
#define CAPM_RET 16250
#define CAPM_DRAM 16250
#define CAPM_LINK 8255
// m-blkcnt element offsets
#define BM4_RET 0
#define BM4_DRAM (MR_RET * NS_RET)                 // 15680
#define BM4_LINK (BM4_DRAM + MR_DRAM * NS_DRAM)    // 16672
#define BM4_TOT (BM4_LINK + MR_LINK * NS_LINK)     // 141856
// t-blkcnt element offsets (tier-2 only)
#define BT_RET 0
#define BT_DRAM (16 * NS_RET)
#define BT_LINK (BT_DRAM + 16 * NS_DRAM)
#define BT_TOT (BT_LINK + 16 * NS_LINK)

// ---- task-range bucketing (per-task min/max) ----
#define R_PART 3125             // 16*3125 == N_TASK
#define CAP_RET 63800
#define CAP_DRAM 16300
#define CAP_LINK 126800
#define SUB_RET 4
#define SUB_DRAM 1
#define SUB_LINK 8
#define PB_RET 0
#define PB_DRAM (16 * SUB_RET * R_PART)             // 200000
#define PB_LINK (PB_DRAM + 16 * SUB_DRAM * R_PART)  // 250000
#define PB_TOT (PB_LINK + 16 * SUB_LINK * R_PART)   // 650000 words per plane

// ---- workspace byte offsets (shared) ----
#define WS_SRET 0
#define WS_SDRAM 80000
#define WS_SLINK 100000
#define WS_CNT 500000           // 100000 i
#define WS_OFFS 900000          // 100000 i
#define WS_TMAX 1300000         // 150000 u
#define WS_TMIN 1900000         // 150000 u
#define WS_BCNT 2500000         // 48 i (t cursors in tier-1)
#define WS_RCNT 2500192         // 336 i
#define WS_CSR 2501536          // 2M i -> ends 10501536
#define WS_BLKM 10501536        // 141856 i counts -> 11068960
#define WS_BLKB 11068960        // 141856 i bases (tier-1) / blkcnt_t (tier-2)
// mrec region
#define WS_MREC_RET 15701536    // 64*16250*8  -> 24021536
#define WS_MREC_DRAM 24021536   // 16*16250*8  -> 26101536
#define WS_MREC_LINK 26101536   // 256*8255*8  -> 43007776
// ---- tier-1 layout ----
#define WS_PART1 15701536       // partials (5.2MB) alias mrec after msum3
#define WS_HPL0_1 20901536
#define WS_HPL1_1 24101536
#define WS_TREC32_RET 43007776  // 16*63800*4  -> 47090976
#define WS_TREC32_DRAM 47090976 // 16*16300*4  -> 48134176
#define WS_TREC32_LINK 48134176 // 16*126800*4 -> 56249376
#define WS_WTB_1 56249376       // 24576 B
#define WS_NEED1 56273952
// ---- tier-2 (R7) layout ----
#define WS_PART2 10501536
#define WS_TREC_RET 15701536
#define WS_TREC_DRAM 23867936
#define WS_TREC_LINK 25954336
#define WS_HPL0_2 15701536
#define WS_HPL1_2 18901536
#define WS_WTB_2 43007776
#define WS_NEED2 43032352

typedef __attribute__((ext_vector_type(8))) short bf16x8;
typedef __attribute__((ext_vector_type(4))) float f32x4;
typedef unsigned long long u64;

__device__ __forceinline__ unsigned ford(float f) {
  unsigned u = __float_as_uint(f);
  return (u & 0x80000000u) ? ~u : (u | 0x80000000u);
}
__device__ __forceinline__ float funord(unsigned t) {
  unsigned u = (t & 0x80000000u) ? (t & 0x7fffffffu) : ~t;
  return __uint_as_float(u);
}
__device__ __forceinline__ unsigned short bf16rne(float f) {
  unsigned u = __float_as_uint(f);
  return (unsigned short)((u + 0x7fffu + ((u >> 16) & 1u)) >> 16);
}

__device__ __forceinline__ void decode_sblk(int bx, int& e, int& blk, int& E0, int& NB,
                                            int& NR, unsigned& RECIP, int& RSZ, int& base) {
  if (bx < NS_RET) {
    e = 0; blk = bx; E0 = E_RET; NB = NS_RET; NR = MR_RET; RECIP = RECIP313; RSZ = RSZ_RET; base = BM4_RET;
  } else if (bx < NS_RET + NS_DRAM) {
    e = 1; blk = bx - NS_RET; E0 = E_DRAM; NB = NS_DRAM; NR = MR_DRAM; RECIP = RECIP313; RSZ = RSZ_DRAM; base = BM4_DRAM;
  } else {
    e = 2; blk = bx - NS_RET - NS_DRAM; E0 = E_LINK; NB = NS_LINK; NR = MR_LINK; RECIP = RECIP391; RSZ = RSZ_LINK; base = BM4_LINK;
  }
}
__device__ __forceinline__ void decode_stblk(int bx, int& e, int& blk, int& E0, int& NB,
                                             int& baset) {
  if (bx < NS_RET) { e = 0; blk = bx; E0 = E_RET; NB = NS_RET; baset = BT_RET; }
  else if (bx < NS_RET + NS_DRAM) { e = 1; blk = bx - NS_RET; E0 = E_DRAM; NB = NS_DRAM; baset = BT_DRAM; }
  else { e = 2; blk = bx - NS_RET - NS_DRAM; E0 = E_LINK; NB = NS_LINK; baset = BT_LINK; }
}

// =================== TIER-1 kernels ===================

// m-counts [0,796) + wprep [796,844) + tcur zero [844]
__global__ __launch_bounds__(256) void k_count3(
    const int* __restrict__ mr, const int* __restrict__ md, const int* __restrict__ ml,
    const float* __restrict__ W_task, unsigned short* __restrict__ wtb,
    int* __restrict__ blkcnt_m, int* __restrict__ tcur) {
  int bx = blockIdx.x, tid = threadIdx.x;
  if (bx == NS_TOT + 48) {
    if (tid < 48) tcur[tid] = 0;
    return;
  }
  if (bx >= NS_TOT) {
    int i = (bx - NS_TOT) * 256 + tid;
    if (i < 64 * 192) wtb[i] = bf16rne(W_task[i]);
    return;
  }
  __shared__ int c[256];
  int e, blk, E0, NB, NR, RSZ, base; unsigned RECIP;
  decode_sblk(bx, e, blk, E0, NB, NR, RECIP, RSZ, base);
  const int* mod = (e == 0) ? mr : (e == 1) ? md : ml;
  c[tid] = 0;
  __syncthreads();
  int i0 = blk * SBE;
#pragma unroll
  for (int q = 0; q < 16; q++) {
    int i = i0 + q * 256 + tid;
    if (i < E0) {
      int m = mod[i];
      int r = (int)(((u64)(unsigned)m * RECIP) >> 25);
      atomicAdd(&c[r], 1);
    }
  }
  __syncthreads();
  for (int r = tid; r < NR; r += 256)
    blkcnt_m[base + r * NB + blk] = c[r];
}

// scan counts -> blkbase (exclusive), counts preserved; totals -> rcnt
__global__ __launch_bounds__(512) void k_scan3(const int* __restrict__ blkcnt_m,
                                               int* __restrict__ blkbase_m,
                                               int* __restrict__ rcnt) {
  __shared__ int sm[512];
  int gb = blockIdx.x, tid = threadIdx.x;
  int NB, off;
  if (gb < 64) { NB = NS_RET; off = BM4_RET + gb * NS_RET; }
  else if (gb < 80) { NB = NS_DRAM; off = BM4_DRAM + (gb - 64) * NS_DRAM; }
  else { NB = NS_LINK; off = BM4_LINK + (gb - 80) * NS_LINK; }
  int v = (tid < NB) ? blkcnt_m[off + tid] : 0;
  sm[tid] = v;
  __syncthreads();
  for (int d = 1; d < 512; d <<= 1) {
    int x = (tid >= d) ? sm[tid - d] : 0;
    __syncthreads();
    sm[tid] += x;
    __syncthreads();
  }
  if (tid < NB) blkbase_m[off + tid] = sm[tid] - v;
  if (tid == 511) rcnt[gb] = sm[511];
}

// single-pass staged m-scatter (no recount); 512 threads (51KB LDS -> 3 blk/CU, 24 w/CU)
__global__ __launch_bounds__(512) void k_mscatter3(
    const int* __restrict__ mr, const int* __restrict__ md, const int* __restrict__ ml,
    const int* __restrict__ tr, const int* __restrict__ td, const int* __restrict__ tl,
    const float* __restrict__ fr, const float* __restrict__ fd, const float* __restrict__ fl,
    const int* __restrict__ blkcnt_m, const int* __restrict__ blkbase_m,
    u64* __restrict__ mrec_ret, u64* __restrict__ mrec_dram, u64* __restrict__ mrec_link) {
  __shared__ int lcur[256];
  __shared__ int pdelta[256];
  __shared__ int sscan[256];
  __shared__ u64 srec[SBE];
  __shared__ int sdelta[SBE];
  int tid = threadIdx.x;
  int e, blk, E0, NB, NR, RSZ, base; unsigned RECIP;
  decode_sblk(blockIdx.x, e, blk, E0, NB, NR, RECIP, RSZ, base);
  const int* mod = (e == 0) ? mr : (e == 1) ? md : ml;
  const int* task = (e == 0) ? tr : (e == 1) ? td : tl;
  const float* feat = (e == 0) ? fr : (e == 1) ? fd : fl;
  u64* out = (e == 0) ? mrec_ret : (e == 1) ? mrec_dram : mrec_link;
  int CAP = (e == 0) ? CAPM_RET : (e == 1) ? CAPM_DRAM : CAPM_LINK;
  int cnt_r = 0, base_r = 0;
  if (tid < NR) {
    cnt_r = blkcnt_m[base + tid * NB + blk];
    base_r = blkbase_m[base + tid * NB + blk];
  }
  if (tid < 256) sscan[tid] = cnt_r;
  __syncthreads();
  for (int d = 1; d < 256; d <<= 1) {
    int x = (tid < 256 && tid >= d) ? sscan[tid - d] : 0;
    __syncthreads();
    if (tid < 256) sscan[tid] += x;
    __syncthreads();
  }
  if (tid < 256) {
    int excl = sscan[tid] - cnt_r;
    lcur[tid] = excl;
    pdelta[tid] = tid * CAP + base_r - excl;
  }
  __syncthreads();
  int i0 = blk * SBE;
#pragma unroll
  for (int q = 0; q < 8; q++) {
    int i = i0 + q * 512 + tid;
    if (i < E0) {
      int m = mod[i];
      int r = (int)(((u64)(unsigned)m * RECIP) >> 25);
      unsigned mloc = (unsigned)(m - r * RSZ);
      unsigned tk = (unsigned)task[i];
      unsigned fu = __float_as_uint(feat[i]);
      int slot = atomicAdd(&lcur[r], 1);
      srec[slot] = ((u64)fu << 32) | (tk << 16) | mloc;
      int gpos = pdelta[r] + slot - r * CAP;
      sdelta[slot] = (gpos < CAP) ? pdelta[r] : (int)0x80000000;
    }
  }
  __syncthreads();
  int total = E0 - i0; if (total > SBE) total = SBE;
  for (int s = tid; s < total; s += 512) {
    int d = sdelta[s];
    if (d != (int)0x80000000) out[d + s] = srec[s];
  }
}

// sums (LDS) + link cnt/offs/CSR + direct trec32 emission — 1024 threads (16 waves)
__global__ __launch_bounds__(1024) void k_msum3(
    const u64* __restrict__ mrec_ret, const u64* __restrict__ mrec_dram,
    const u64* __restrict__ mrec_link, const int* __restrict__ rcnt,
    int* __restrict__ cnt, int* __restrict__ offs, int* __restrict__ csr,
    int* __restrict__ tcur,
    unsigned* __restrict__ trec_ret, unsigned* __restrict__ trec_dram,
    unsigned* __restrict__ trec_link) {
  __shared__ float ssum[RSZ_LINK];
  __shared__ int scnt[RSZ_LINK];
  __shared__ int soff[RSZ_LINK + 1];
  __shared__ int red[512];
  __shared__ int tcnt16[16][16];   // per-wave replicas
  __shared__ int tbase16[16][16];
  int gb = blockIdx.x, tid = threadIdx.x;
  int w = tid >> 6;  // 0..15
  int e, rl, RSZ, CAPM, Ntot, CAPT;
  const u64* p;
  unsigned* trec;
  if (gb < MR_RET) {
    e = 0; rl = gb; p = mrec_ret + (long)rl * CAPM_RET;
    RSZ = RSZ_RET; CAPM = CAPM_RET; Ntot = N_RET; CAPT = CAP_RET; trec = trec_ret;
  } else if (gb < MR_RET + MR_DRAM) {
    e = 1; rl = gb - MR_RET; p = mrec_dram + (long)rl * CAPM_DRAM;
    RSZ = RSZ_DRAM; CAPM = CAPM_DRAM; Ntot = N_DRAM; CAPT = CAP_DRAM; trec = trec_dram;
  } else {
    e = 2; rl = gb - MR_RET - MR_DRAM; p = mrec_link + (long)rl * CAPM_LINK;
    RSZ = RSZ_LINK; CAPM = CAPM_LINK; Ntot = N_LINK; CAPT = CAP_LINK; trec = trec_link;
  }
  int m0 = rl * RSZ;
  int nmod = Ntot - m0; if (nmod > RSZ) nmod = RSZ;
  for (int j = tid; j < RSZ; j += 1024) { ssum[j] = 0.f; scnt[j] = 0; }
  if (tid < 256) tcnt16[tid >> 4][tid & 15] = 0;
  __syncthreads();
  int count = rcnt[gb]; if (count > CAPM) count = CAPM;
  for (int i = tid; i < count; i += 1024) {
    u64 rec = p[i];
    int mloc = (int)(rec & 0xFFFFull);
    int task = (int)((rec >> 16) & 0xFFFFull);
    atomicAdd(&ssum[mloc], __uint_as_float((unsigned)(rec >> 32)));
    if (e == 2) atomicAdd(&scnt[mloc], 1);
    atomicAdd(&tcnt16[w][task / R_PART], 1);
  }
  __syncthreads();
  // block-level trec reservation: 1 global atomic per bucket per block
  if (tid < 16) {
    int b2 = tid, tot = 0;
    for (int w2 = 0; w2 < 16; w2++) { tbase16[w2][b2] = tot; tot += tcnt16[w2][b2]; }
    int g0 = atomicAdd(&tcur[e * 16 + b2], tot);
    for (int w2 = 0; w2 < 16; w2++) { tbase16[w2][b2] += g0; tcnt16[w2][b2] = 0; }
  }
  if (e == 2) {
    // rb = sum of preceding link-range totals (gb-80 <= 255)
    int partial = (tid < 256 && 80 + tid < gb) ? rcnt[80 + tid] : 0;
    if (tid < 256) red[tid] = partial;
    __syncthreads();
    for (int s = 128; s > 0; s >>= 1) {
      if (tid < s) red[tid] += red[tid + s];
      __syncthreads();
    }
    int rb = red[0];
    __syncthreads();
    // exclusive scan of scnt[0..nmod), nmod <= 391 < 512: 512-wide single pass
    int vv = (tid < 512 && tid < nmod) ? scnt[tid] : 0;
    if (tid < 512) red[tid] = vv;
    __syncthreads();
    for (int d = 1; d < 512; d <<= 1) {
      int x = (tid < 512 && tid >= d) ? red[tid - d] : 0;
      __syncthreads();
      if (tid < 512) red[tid] += x;
      __syncthreads();
    }
    if (tid < nmod) soff[tid] = red[tid] - vv;
    __syncthreads();
    for (int j = tid; j < nmod; j += 1024) {
      cnt[m0 + j] = scnt[j];
      offs[m0 + j] = rb + soff[j];
    }
    __syncthreads();
    // CSR emission via LDS cursors (soff becomes cursor)
    for (int i = tid; i < count; i += 1024) {
      u64 rec = p[i];
      int mloc = (int)(rec & 0xFFFFull);
      int task = (int)((rec >> 16) & 0xFFFFull);
      int lp = atomicAdd(&soff[mloc], 1);
      csr[rb + lp] = task;
    }
  }
  __syncthreads();
  // trec32 emission: (ford(s) & ~0xFFF) | taskLocal12 — truncation is monotone,
  // so bucket max/min of truncated == truncated true max/min (err <= 2^-11 rel).
  for (int i = tid; i < count; i += 1024) {
    u64 rec = p[i];
    int mloc = (int)(rec & 0xFFFFull);
    int task = (int)((rec >> 16) & 0xFFFFull);
    int b = task / R_PART;
    unsigned tl12 = (unsigned)(task - b * R_PART);
    unsigned u = (ford(ssum[mloc]) & 0xFFFFF000u) | tl12;
    int local = atomicAdd(&tcnt16[w][b], 1);
    int pos = tbase16[w][b] + local;
    if (pos < CAPT) trec[(long)b * CAPT + pos] = u;
  }
}

__global__ __launch_bounds__(256) void k_passb3(
    const unsigned* __restrict__ trec_ret, const unsigned* __restrict__ trec_dram,
    const unsigned* __restrict__ trec_link,
    const int* __restrict__ tcur, unsigned* __restrict__ partials) {
  __shared__ unsigned lmax[R_PART];
  __shared__ unsigned lmin[R_PART];
  int blk = blockIdx.x;
  int e, b, sub, Nb, PB, CAP;
  const unsigned* bkt;
  if (blk < 16 * SUB_RET) {
    e = 0; b = blk >> 2; sub = blk & 3; Nb = SUB_RET; PB = PB_RET; CAP = CAP_RET; bkt = trec_ret;
  } else if (blk < 16 * (SUB_RET + SUB_DRAM)) {
    int q = blk - 16 * SUB_RET;
    e = 1; b = q; sub = 0; Nb = SUB_DRAM; PB = PB_DRAM; CAP = CAP_DRAM; bkt = trec_dram;
  } else {
    int q = blk - 16 * (SUB_RET + SUB_DRAM);
    e = 2; b = q >> 3; sub = q & 7; Nb = SUB_LINK; PB = PB_LINK; CAP = CAP_LINK; bkt = trec_link;
  }
  for (int idx = threadIdx.x; idx < R_PART; idx += 256) {
    lmax[idx] = 0u;
    lmin[idx] = 0xFFFFFFFFu;
  }
  __syncthreads();
  int count = tcur[e * 16 + b];
  if (count > CAP) count = CAP;
  int chunk = (count + Nb - 1) / Nb;
  int s0 = sub * chunk;
  int s1 = s0 + chunk; if (s1 > count) s1 = count;
  const unsigned* p = bkt + (long)b * CAP;
  for (int i = s0 + threadIdx.x; i < s1; i += 256) {
    unsigned rec = p[i];
    unsigned r = rec & 0xFFFu;  // low 12 bits constant per slot -> full-rec cmp ok
    atomicMax(&lmax[r], rec);
    atomicMin(&lmin[r], rec);
  }
  __syncthreads();
  unsigned gbase = PB + (unsigned)(b * Nb + sub) * R_PART;
  for (int idx = threadIdx.x; idx < R_PART; idx += 256) {
    partials[gbase + idx] = lmax[idx];
    partials[PB_TOT + gbase + idx] = lmin[idx];
  }
}

__global__ __launch_bounds__(256) void k_mmred3(const unsigned* __restrict__ partials,
                                                unsigned* __restrict__ tmax,
                                                unsigned* __restrict__ tmin) {
  int gid = blockIdx.x * 256 + threadIdx.x;
  if (gid >= 3 * N_TASK) return;
  int e = gid / N_TASK;
  int t = gid - e * N_TASK;
  int Nb = (e == 0) ? SUB_RET : (e == 1) ? SUB_DRAM : SUB_LINK;
  int PB = (e == 0) ? PB_RET : (e == 1) ? PB_DRAM : PB_LINK;
  int b = t / R_PART;
  int r = t - b * R_PART;
  unsigned umax = 0u, umin = 0xFFFFFFFFu;
  for (int sub = 0; sub < Nb; sub++) {
    unsigned idx = PB + (unsigned)(b * Nb + sub) * R_PART + r;
    unsigned wv = partials[idx];
    if (wv > umax) umax = wv;
    unsigned w2 = partials[PB_TOT + idx];
    if (w2 < umin) umin = w2;
  }
  tmax[gid] = umax & 0xFFFFF000u;  // 0 iff no edges (sentinel)
  tmin[gid] = umin & 0xFFFFF000u;
}

// =================== TIER-2 kernels (R7 path, unchanged) ===================

__global__ __launch_bounds__(256) void k_count(
    const int* __restrict__ mr, const int* __restrict__ md, const int* __restrict__ ml,
    const int* __restrict__ tr, const int* __restrict__ td, const int* __restrict__ tl,
    const float* __restrict__ W_task, unsigned short* __restrict__ wtb,
    int* __restrict__ blkcnt_m, int* __restrict__ blkcnt_t) {
  int bx = blockIdx.x, tid = threadIdx.x;
  if (bx >= 2 * NS_TOT) {
    int i = (bx - 2 * NS_TOT) * 256 + tid;
    if (i < 64 * 192) wtb[i] = bf16rne(W_task[i]);
    return;
  }
  __shared__ int c[256];
  c[tid] = 0;
  __syncthreads();
  if (bx < NS_TOT) {
    int e, blk, E0, NB, NR, RSZ, base; unsigned RECIP;
    decode_sblk(bx, e, blk, E0, NB, NR, RECIP, RSZ, base);
    const int* mod = (e == 0) ? mr : (e == 1) ? md : ml;
    int i0 = blk * SBE;
#pragma unroll
    for (int q = 0; q < 16; q++) {
      int i = i0 + q * 256 + tid;
      if (i < E0) {
        int m = mod[i];
        int r = (int)(((u64)(unsigned)m * RECIP) >> 25);
        atomicAdd(&c[r], 1);
      }
    }
    __syncthreads();
    for (int r = tid; r < NR; r += 256)
      blkcnt_m[base + r * NB + blk] = c[r];
  } else {
    int e, blk, E0, NB, baset;
    decode_stblk(bx - NS_TOT, e, blk, E0, NB, baset);
    const int* task = (e == 0) ? tr : (e == 1) ? td : tl;
    int i0 = blk * SBE;
#pragma unroll
    for (int q = 0; q < 16; q++) {
      int i = i0 + q * 256 + tid;
      if (i < E0) atomicAdd(&c[task[i] / R_PART], 1);
    }
    __syncthreads();
    if (tid < 16) blkcnt_t[baset + tid * NB + blk] = c[tid];
  }
}

__global__ __launch_bounds__(512) void k_scan(int* __restrict__ blkcnt_m,
                                              int* __restrict__ blkcnt_t,
                                              int* __restrict__ rcnt, int* __restrict__ bcnt) {
  __shared__ int sm[512];
  int gb = blockIdx.x, tid = threadIdx.x;
  int* arr; int NB; int* outp;
  if (gb < 336) {
    int off;
    if (gb < 64) { NB = NS_RET; off = BM4_RET + gb * NS_RET; }
    else if (gb < 80) { NB = NS_DRAM; off = BM4_DRAM + (gb - 64) * NS_DRAM; }
    else { NB = NS_LINK; off = BM4_LINK + (gb - 80) * NS_LINK; }
    arr = blkcnt_m + off; outp = rcnt + gb;
  } else {
    int g = gb - 336; int e = g >> 4, b = g & 15;
    int NBe = (e == 0) ? NS_RET : (e == 1) ? NS_DRAM : NS_LINK;
    int baset = (e == 0) ? BT_RET : (e == 1) ? BT_DRAM : BT_LINK;
    NB = NBe; arr = blkcnt_t + baset + b * NBe; outp = bcnt + g;
  }
  int v = (tid < NB) ? arr[tid] : 0;
  sm[tid] = v;
  __syncthreads();
  for (int d = 1; d < 512; d <<= 1) {
    int x = (tid >= d) ? sm[tid - d] : 0;
    __syncthreads();
    sm[tid] += x;
    __syncthreads();
  }
  if (tid < NB) arr[tid] = sm[tid] - v;
  if (tid == 511) *outp = sm[511];
}

__global__ __launch_bounds__(256) void k_mscatter2(
    const int* __restrict__ mr, const int* __restrict__ md, const int* __restrict__ ml,
    const int* __restrict__ tl,
    const float* __restrict__ fr, const float* __restrict__ fd, const float* __restrict__ fl,
    const int* __restrict__ blkcnt_m,
    u64* __restrict__ mrec_ret, u64* __restrict__ mrec_dram, u64* __restrict__ mrec_link) {
  __shared__ int lcur[256];
  __shared__ int pdelta[256];
  __shared__ int sscan[256];
  __shared__ u64 srec[SBE];
  __shared__ int sdelta[SBE];
  int tid = threadIdx.x;
  int e, blk, E0, NB, NR, RSZ, base; unsigned RECIP;
  decode_sblk(blockIdx.x, e, blk, E0, NB, NR, RECIP, RSZ, base);
  const int* mod = (e == 0) ? mr : (e == 1) ? md : ml;
  const float* feat = (e == 0) ? fr : (e == 1) ? fd : fl;
  u64* out = (e == 0) ? mrec_ret : (e == 1) ? mrec_dram : mrec_link;
  int CAP = (e == 0) ? CAPM_RET : (e == 1) ? CAPM_DRAM : CAPM_LINK;
  lcur[tid] = 0;
  __syncthreads();
  int i0 = blk * SBE;
#pragma unroll
  for (int q = 0; q < 16; q++) {
    int i = i0 + q * 256 + tid;
    if (i < E0) {
      int m = mod[i];
      int r = (int)(((u64)(unsigned)m * RECIP) >> 25);
      atomicAdd(&lcur[r], 1);
    }
  }
  __syncthreads();
  int v = lcur[tid];
  sscan[tid] = v;
  __syncthreads();
  for (int d = 1; d < 256; d <<= 1) {
    int x = (tid >= d) ? sscan[tid - d] : 0;
    __syncthreads();
    sscan[tid] += x;
    __syncthreads();
  }
  int excl = sscan[tid] - v;
  int total = sscan[255];
  int gbv = (tid < NR) ? blkcnt_m[base + tid * NB + blk] : 0;
  __syncthreads();
  lcur[tid] = excl;
  pdelta[tid] = tid * CAP + gbv - excl;
  __syncthreads();
#pragma unroll
  for (int q = 0; q < 16; q++) {
    int i = i0 + q * 256 + tid;
    if (i < E0) {
      int m = mod[i];
      int r = (int)(((u64)(unsigned)m * RECIP) >> 25);
      unsigned mloc = (unsigned)(m - r * RSZ);
      unsigned task = (e == 2) ? (unsigned)tl[i] : 0u;
      unsigned fu = __float_as_uint(feat[i]);
      int slot = atomicAdd(&lcur[r], 1);
      srec[slot] = ((u64)fu << 32) | (task << 16) | mloc;
      int gpos = pdelta[r] + slot - r * CAP;
      sdelta[slot] = (gpos < CAP) ? pdelta[r] : (int)0x80000000;
    }
  }
  __syncthreads();
  for (int s = tid; s < total; s += 256) {
    int d = sdelta[s];
    if (d != (int)0x80000000) out[d + s] = srec[s];
  }
}

__global__ __launch_bounds__(256) void k_msum(
    const u64* __restrict__ mrec_ret, const u64* __restrict__ mrec_dram,
    const u64* __restrict__ mrec_link, const int* __restrict__ rcnt,
    float* __restrict__ s_ret, float* __restrict__ s_dram, float* __restrict__ s_link,
    int* __restrict__ cnt, int* __restrict__ offs, int* __restrict__ csr) {
  __shared__ float ssum[RSZ_LINK];
  __shared__ int scnt[RSZ_LINK];
  __shared__ int soff[RSZ_LINK + 1];
  __shared__ int red[256];
  int gb = blockIdx.x, tid = threadIdx.x;
  int e, rl, RSZ, CAP, Ntot;
  const u64* p;
  float* sout;
  if (gb < MR_RET) {
    e = 0; rl = gb; p = mrec_ret + (long)rl * CAPM_RET; sout = s_ret;
    RSZ = RSZ_RET; CAP = CAPM_RET; Ntot = N_RET;
  } else if (gb < MR_RET + MR_DRAM) {
    e = 1; rl = gb - MR_RET; p = mrec_dram + (long)rl * CAPM_DRAM; sout = s_dram;
    RSZ = RSZ_DRAM; CAP = CAPM_DRAM; Ntot = N_DRAM;
  } else {
    e = 2; rl = gb - MR_RET - MR_DRAM; p = mrec_link + (long)rl * CAPM_LINK; sout = s_link;
    RSZ = RSZ_LINK; CAP = CAPM_LINK; Ntot = N_LINK;
  }
  int m0 = rl * RSZ;
  int nmod = Ntot - m0; if (nmod > RSZ) nmod = RSZ;
  for (int j = tid; j < RSZ; j += 256) { ssum[j] = 0.f; scnt[j] = 0; }
  __syncthreads();
  int count = rcnt[gb]; if (count > CAP) count = CAP;
  for (int i = tid; i < count; i += 256) {
    u64 rec = p[i];
    int mloc = (int)(rec & 0xFFFFull);
    atomicAdd(&ssum[mloc], __uint_as_float((unsigned)(rec >> 32)));
    if (e == 2) atomicAdd(&scnt[mloc], 1);
  }
  __syncthreads();
  for (int j = tid; j < nmod; j += 256) sout[m0 + j] = ssum[j];
  if (e != 2) return;
  int partial = (80 + tid < gb) ? rcnt[80 + tid] : 0;
  red[tid] = partial;
  __syncthreads();
  for (int s = 128; s > 0; s >>= 1) {
    if (tid < s) red[tid] += red[tid + s];
    __syncthreads();
  }
  int rb = red[0];
  __syncthreads();
  int a0 = (2 * tid < nmod) ? scnt[2 * tid] : 0;
  int a1 = (2 * tid + 1 < nmod) ? scnt[2 * tid + 1] : 0;
  red[tid] = a0 + a1;
  __syncthreads();
  for (int d = 1; d < 256; d <<= 1) {
    int x = (tid >= d) ? red[tid - d] : 0;
    __syncthreads();
    red[tid] += x;
    __syncthreads();
  }
  int excl = red[tid] - (a0 + a1);
  if (2 * tid < RSZ_LINK) soff[2 * tid] = excl;
  if (2 * tid + 1 < RSZ_LINK) soff[2 * tid + 1] = excl + a0;
  __syncthreads();
  for (int j = tid; j < nmod; j += 256) {
    cnt[m0 + j] = scnt[j];
    offs[m0 + j] = rb + soff[j];
  }
  __syncthreads();
  for (int i = tid; i < count; i += 256) {
    u64 rec = p[i];
    int mloc = (int)(rec & 0xFFFFull);
    int task = (int)((rec >> 16) & 0xFFFFull);
    int lp = atomicAdd(&soff[mloc], 1);
    csr[rb + lp] = task;
  }
}

__global__ __launch_bounds__(256) void k_ascatter2(
    const int* __restrict__ tr, const int* __restrict__ mr,
    const int* __restrict__ td, const int* __restrict__ md,
    const int* __restrict__ tl, const int* __restrict__ ml,
    const float* __restrict__ s_ret, const float* __restrict__ s_dram,
    const float* __restrict__ s_link, const int* __restrict__ blkcnt_t,
    u64* __restrict__ trec_ret, u64* __restrict__ trec_dram, u64* __restrict__ trec_link) {
  __shared__ int lcur[256];
  __shared__ int pdelta[256];
  __shared__ int sscan[256];
  __shared__ u64 srec[SBE];
  __shared__ int sdelta[SBE];
  int tid = threadIdx.x;
  int e, blk, E0, NB, baset;
  decode_stblk(blockIdx.x, e, blk, E0, NB, baset);
  const int* task = (e == 0) ? tr : (e == 1) ? td : tl;
  const int* mod = (e == 0) ? mr : (e == 1) ? md : ml;
  const float* s = (e == 0) ? s_ret : (e == 1) ? s_dram : s_link;
  u64* out = (e == 0) ? trec_ret : (e == 1) ? trec_dram : trec_link;
  int CAP = (e == 0) ? CAP_RET : (e == 1) ? CAP_DRAM : CAP_LINK;
  lcur[tid] = 0;
  __syncthreads();
  int i0 = blk * SBE;
#pragma unroll
  for (int q = 0; q < 16; q++) {
    int i = i0 + q * 256 + tid;
    if (i < E0) atomicAdd(&lcur[task[i] / R_PART], 1);
  }
  __syncthreads();
  int v = lcur[tid];
  sscan[tid] = v;
  __syncthreads();
  for (int d = 1; d < 256; d <<= 1) {
    int x = (tid >= d) ? sscan[tid - d] : 0;
    __syncthreads();
    sscan[tid] += x;
    __syncthreads();
  }
  int excl = sscan[tid] - v;
  int total = sscan[255];
  int gbv = (tid < 16) ? blkcnt_t[baset + tid * NB + blk] : 0;
  __syncthreads();
  lcur[tid] = excl;
  pdelta[tid] = tid * CAP + gbv - excl;
  __syncthreads();
#pragma unroll
  for (int q = 0; q < 16; q++) {
    int i = i0 + q * 256 + tid;
    if (i < E0) {
      int t = task[i];
      int r = t / R_PART;
      unsigned rloc = (unsigned)(t - r * R_PART);
      unsigned u = ford(s[mod[i]]);
      int slot = atomicAdd(&lcur[r], 1);
      srec[slot] = ((u64)u << 32) | rloc;
      int gpos = pdelta[r] + slot - r * CAP;
      sdelta[slot] = (gpos < CAP) ? pdelta[r] : (int)0x80000000;
    }
  }
  __syncthreads();
  for (int sidx = tid; sidx < total; sidx += 256) {
    int d = sdelta[sidx];
    if (d != (int)0x80000000) out[d + sidx] = srec[sidx];
  }
}

__global__ __launch_bounds__(256) void k_passb(
    const u64* __restrict__ trec_ret, const u64* __restrict__ trec_dram,
    const u64* __restrict__ trec_link,
    const int* __restrict__ bcnt, unsigned* __restrict__ partials) {
  __shared__ unsigned lmax[R_PART];
  __shared__ unsigned lmin[R_PART];
  int blk = blockIdx.x;
  int e, b, sub, Nb, PB, CAP;
  const u64* bkt;
  if (blk < 16 * SUB_RET) {
    e = 0; b = blk >> 2; sub = blk & 3; Nb = SUB_RET; PB = PB_RET; CAP = CAP_RET; bkt = trec_ret;
  } else if (blk < 16 * (SUB_RET + SUB_DRAM)) {
    int q = blk - 16 * SUB_RET;
    e = 1; b = q; sub = 0; Nb = SUB_DRAM; PB = PB_DRAM; CAP = CAP_DRAM; bkt = trec_dram;
  } else {
    int q = blk - 16 * (SUB_RET + SUB_DRAM);
    e = 2; b = q >> 3; sub = q & 7; Nb = SUB_LINK; PB = PB_LINK; CAP = CAP_LINK; bkt = trec_link;
  }
  for (int idx = threadIdx.x; idx < R_PART; idx += 256) {
    lmax[idx] = 0u;
    lmin[idx] = 0xFFFFFFFFu;
  }
  __syncthreads();
  int count = bcnt[e * 16 + b];
  if (count > CAP) count = CAP;
  int chunk = (count + Nb - 1) / Nb;
  int s0 = sub * chunk;
  int s1 = s0 + chunk; if (s1 > count) s1 = count;
  const u64* p = bkt + (long)b * CAP;
  for (int i = s0 + threadIdx.x; i < s1; i += 256) {
    u64 rec = p[i];
    unsigned r = (unsigned)rec;
    unsigned u = (unsigned)(rec >> 32);
    atomicMax(&lmax[r], u);
    atomicMin(&lmin[r], u);
  }
  __syncthreads();
  unsigned gbase = PB + (unsigned)(b * Nb + sub) * R_PART;
  for (int idx = threadIdx.x; idx < R_PART; idx += 256) {
    partials[gbase + idx] = lmax[idx];
    partials[PB_TOT + gbase + idx] = lmin[idx];
  }
}

__global__ __launch_bounds__(256) void k_mmred2(const unsigned* __restrict__ partials,
                                                unsigned* __restrict__ tmax,
                                                unsigned* __restrict__ tmin) {
  int gid = blockIdx.x * 256 + threadIdx.x;
  if (gid >= 3 * N_TASK) return;
  int e = gid / N_TASK;
  int t = gid - e * N_TASK;
  int Nb = (e == 0) ? SUB_RET : (e == 1) ? SUB_DRAM : SUB_LINK;
  int PB = (e == 0) ? PB_RET : (e == 1) ? PB_DRAM : PB_LINK;
  int b = t / R_PART;
  int r = t - b * R_PART;
  unsigned umax = 0u, umin = 0xFFFFFFFFu;
  for (int sub = 0; sub < Nb; sub++) {
    unsigned idx = PB + (unsigned)(b * Nb + sub) * R_PART + r;
    unsigned wv = partials[idx];
    if (wv > umax) umax = wv;
    unsigned w2 = partials[PB_TOT + idx];
    if (w2 < umin) umin = w2;
  }
  tmax[gid] = umax;
  tmin[gid] = umin;
}

// =================== TIER-3 fallback ===================

__global__ void k_wprep(const float* __restrict__ W_task, unsigned short* __restrict__ wtb) {
  int i = blockIdx.x * 256 + threadIdx.x;
  if (i < 64 * 192) wtb[i] = bf16rne(W_task[i]);
}

__global__ void f_segsum(const float* __restrict__ fr, const float* __restrict__ fd,
                         const float* __restrict__ fl,
                         const int* __restrict__ mr, const int* __restrict__ md,
                         const int* __restrict__ ml,
                         float* s_ret, float* s_dram, float* s_link, int* cnt) {
  int i = blockIdx.x * blockDim.x + threadIdx.x;
  const int total = E_RET + E_DRAM + E_LINK;
  if (i >= total) return;
  if (i < E_RET) {
    atomicAdd(&s_ret[mr[i]], fr[i]);
  } else if (i < E_RET + E_DRAM) {
    int j = i - E_RET;
    atomicAdd(&s_dram[md[j]], fd[j]);
  } else {
    int j = i - (E_RET + E_DRAM);
    int m = ml[j];
    atomicAdd(&s_link[m], fl[j]);
    atomicAdd(&cnt[m], 1);
  }
}

__global__ void f_minmax(const float* __restrict__ s_ret, const float* __restrict__ s_dram,
                         const float* __restrict__ s_link,
                         const int* __restrict__ tr, const int* __restrict__ mr,
                         const int* __restrict__ td, const int* __restrict__ md,
                         const int* __restrict__ tl, const int* __restrict__ ml,
                         unsigned* tmax, unsigned* tmin) {
  int i = blockIdx.x * blockDim.x + threadIdx.x;
  const int total = E_RET + E_DRAM + E_LINK;
  if (i >= total) return;
  int e, task; unsigned u;
  if (i < E_RET) {
    u = ford(s_ret[mr[i]]); task = tr[i]; e = 0;
  } else if (i < E_RET + E_DRAM) {
    int j = i - E_RET;
    u = ford(s_dram[md[j]]); task = td[j]; e = 1;
  } else {
    int j = i - (E_RET + E_DRAM);
    u = ford(s_link[ml[j]]); task = tl[j]; e = 2;
  }
  atomicMax(&tmax[e * N_TASK + task], u);
  atomicMin(&tmin[e * N_TASK + task], u);
}

__global__ void f_part(const int* __restrict__ cnt, int* part) {
  __shared__ int sm[256];
  int i = blockIdx.x * 256 + threadIdx.x;
  sm[threadIdx.x] = (i < N_LINK) ? cnt[i] : 0;
  __syncthreads();
  for (int s = 128; s > 0; s >>= 1) {
    if (threadIdx.x < s) sm[threadIdx.x] += sm[threadIdx.x + s];
    __syncthreads();
  }
  if (threadIdx.x == 0) part[blockIdx.x] = sm[0];
}

__global__ void f_scanpart(const int* __restrict__ part, int* partx, int npart) {
  __shared__ int sm[512];
  int t = threadIdx.x;
  int v = (t < npart) ? part[t] : 0;
  sm[t] = v;
  __syncthreads();
  for (int d = 1; d < 512; d <<= 1) {
    int x = (t >= d) ? sm[t - d] : 0;
    __syncthreads();
    sm[t] += x;
    __syncthreads();
  }
  if (t < npart) partx[t] = sm[t] - v;
}

__global__ void f_offs(const int* __restrict__ cnt, const int* __restrict__ partx,
                       int* offs, int* cursor) {
  __shared__ int sm[256];
  int i = blockIdx.x * 256 + threadIdx.x;
  int t = threadIdx.x;
  int v = (i < N_LINK) ? cnt[i] : 0;
  sm[t] = v;
  __syncthreads();
  for (int d = 1; d < 256; d <<= 1) {
    int x = (t >= d) ? sm[t - d] : 0;
    __syncthreads();
    sm[t] += x;
    __syncthreads();
  }
  if (i < N_LINK) {
    int o = partx[blockIdx.x] + sm[t] - v;
    offs[i] = o;
    cursor[i] = o;
  }
}

__global__ void f_scatter(const int* __restrict__ tl, const int* __restrict__ ml,
                          int* cursor, int* csr) {
  int i = blockIdx.x * blockDim.x + threadIdx.x;
  if (i >= E_LINK) return;
  int pos = atomicAdd(&cursor[ml[i]], 1);
  csr[pos] = tl[i];
}

// =================== shared tail: task GEMM (MFMA) + link mean ===================

__global__ __launch_bounds__(256) void k_taskm(
    const float* __restrict__ W_ret, const float* __restrict__ b_ret,
    const float* __restrict__ W_dram, const float* __restrict__ b_dram,
    const float* __restrict__ W_link, const float* __restrict__ b_link,
    const unsigned short* __restrict__ wtb, const float* __restrict__ b_task,
    const unsigned* __restrict__ tmax, const unsigned* __restrict__ tmin,
    unsigned short* __restrict__ hp0, unsigned short* __restrict__ hp1) {
  int wave = threadIdx.x >> 6;
  int lane = threadIdx.x & 63;
  int tile = blockIdx.x * 4 + wave;
  if (tile >= N_TASK / 16) return;
  int t0 = tile * 16;
  int l16 = lane & 15;
  int quad = lane >> 4;
  int t = t0 + l16;

  f32x4 acc[4];
#pragma unroll
  for (int nf = 0; nf < 4; nf++) acc[nf] = (f32x4){0.f, 0.f, 0.f, 0.f};

  const float* We[3] = {W_ret, W_dram, W_link};
  const float* be[3] = {b_ret, b_dram, b_link};

  for (int e = 0; e < 3; e++) {
    unsigned um = tmax[e * N_TASK + t];
    float smax = funord(um);
    float smin = funord(tmin[e * N_TASK + t]);
    bool live = (um != 0u);
#pragma unroll
    for (int h = 0; h < 2; h++) {
      int kb = h * 32 + quad * 8;
      float4 w0 = *(const float4*)&We[e][kb];
      float4 w1 = *(const float4*)&We[e][kb + 4];
      float4 b0 = *(const float4*)&be[e][kb];
      float4 b1 = *(const float4*)&be[e][kb + 4];
      float wv[8] = {w0.x, w0.y, w0.z, w0.w, w1.x, w1.y, w1.z, w1.w};
      float bv[8] = {b0.x, b0.y, b0.z, b0.w, b1.x, b1.y, b1.z, b1.w};
      bf16x8 afrag;
#pragma unroll
      for (int j = 0; j < 8; j++) {
        float wj = wv[j];
        float ss = (wj >= 0.f) ? smax : smin;
        float hc = live ? tanhf(fmaf(ss, wj, bv[j])) : 0.f;
        afrag[j] = (short)bf16rne(hc);
      }
      int kk = e * 64 + h * 32 + quad * 8;
#pragma unroll
      for (int nf = 0; nf < 4; nf++) {
        int o = nf * 16 + l16;
        bf16x8 bfrag = *(const bf16x8*)&wtb[o * 192 + kk];
        acc[nf] = __builtin_amdgcn_mfma_f32_16x16x32_bf16(afrag, bfrag, acc[nf], 0, 0, 0);
      }
    }
  }

#pragma unroll
  for (int nf = 0; nf < 4; nf++) {
    int n = nf * 16 + l16;
    float bt = b_task[n];
    unsigned short* hp = (n < 32) ? hp0 : hp1;
    int f = n & 31;
#pragma unroll
    for (int r = 0; r < 4; r++) {
      int m = quad * 4 + r;
      float v = tanhf(acc[nf][r] + bt);
      hp[(t0 + m) * 32 + f] = bf16rne(v);
    }
  }
}

__global__ __launch_bounds__(256) void k_link2(const unsigned short* __restrict__ hp,
                                               const int* __restrict__ offs,
                                               const int* __restrict__ cnt,
                                               const int* __restrict__ csr,
                                               float* __restrict__ out, int plane) {
  int l = blockIdx.x * 8 + (threadIdx.x >> 5);
  int f = threadIdx.x & 31;
  int start = offs[l];
  int c = cnt[l];
  float acc = 0.f;
  for (int q = 0; q < c; q += 4) {
    int i1 = (q + 1 < c) ? q + 1 : c - 1;
    int i2 = (q + 2 < c) ? q + 2 : c - 1;
    int i3 = (q + 3 < c) ? q + 3 : c - 1;
    int t0 = csr[start + q];
    int t1 = csr[start + i1];
    int t2 = csr[start + i2];
    int t3 = csr[start + i3];
    unsigned v0 = hp[t0 * 32 + f];
    unsigned v1 = hp[t1 * 32 + f];
    unsigned v2 = hp[t2 * 32 + f];
    unsigned v3 = hp[t3 * 32 + f];
    acc += __uint_as_float(v0 << 16);
    if (q + 1 < c) acc += __uint_as_float(v1 << 16);
    if (q + 2 < c) acc += __uint_as_float(v2 << 16);
    if (q + 3 < c) acc += __uint_as_float(v3 << 16);
  }
  out[l * 64 + plane * 32 + f] = (c > 0) ? acc / (float)c : 0.f;
}

extern "C" void kernel_launch(void* const* d_in, const int* in_sizes, int n_in,
                              void* d_out, int out_size, void* d_ws, size_t ws_size,
                              hipStream_t stream) {
  const float* feat_ret  = (const float*)d_in[0];
  const float* feat_dram = (const float*)d_in[1];
  const float* feat_link = (const float*)d_in[2];
  const float* W_ret  = (const float*)d_in[3];
  const float* b_ret  = (const float*)d_in[4];
  const float* W_dram = (const float*)d_in[5];
  const float* b_dram = (const float*)d_in[6];
  const float* W_link = (const float*)d_in[7];
  const float* b_link = (const float*)d_in[8];
  const float* W_task = (const float*)d_in[9];
  const float* b_task = (const float*)d_in[10];
  const int* task_ret  = (const int*)d_in[11];
  const int* mod_ret   = (const int*)d_in[12];
  const int* task_dram = (const int*)d_in[13];
  const int* mod_dram  = (const int*)d_in[14];
  const int* task_link = (const int*)d_in[15];
  const int* mod_link  = (const int*)d_in[16];
  float* out = (float*)d_out;

  char* ws = (char*)d_ws;
  float* s_ret  = (float*)(ws + WS_SRET);
  float* s_dram = (float*)(ws + WS_SDRAM);
  float* s_link = (float*)(ws + WS_SLINK);
  int*   cnt    = (int*)(ws + WS_CNT);
  int*   offs   = (int*)(ws + WS_OFFS);
  unsigned* tmax = (unsigned*)(ws + WS_TMAX);
  unsigned* tmin = (unsigned*)(ws + WS_TMIN);
  int* tcur = (int*)(ws + WS_BCNT);
  int* rcnt = (int*)(ws + WS_RCNT);
  int* csr  = (int*)(ws + WS_CSR);
  int* blkcnt_m = (int*)(ws + WS_BLKM);
  int* blkb = (int*)(ws + WS_BLKB);  // blkbase (tier-1) / blkcnt_t (tier-2)
  u64* mrec_ret  = (u64*)(ws + WS_MREC_RET);
  u64* mrec_dram = (u64*)(ws + WS_MREC_DRAM);
  u64* mrec_link = (u64*)(ws + WS_MREC_LINK);

  unsigned short* hp0;
  unsigned short* hp1;
  unsigned short* wtb;

  if (ws_size >= (size_t)WS_NEED1) {
    // ---- tier-1: no ascatter, 4B trecs, single-pass mscatter ----
    unsigned* partials = (unsigned*)(ws + WS_PART1);
    unsigned* trec_ret  = (unsigned*)(ws + WS_TREC32_RET);
    unsigned* trec_dram = (unsigned*)(ws + WS_TREC32_DRAM);
    unsigned* trec_link = (unsigned*)(ws + WS_TREC32_LINK);
    hp0 = (unsigned short*)(ws + WS_HPL0_1);
    hp1 = (unsigned short*)(ws + WS_HPL1_1);
    wtb = (unsigned short*)(ws + WS_WTB_1);
    k_count3<<<NS_TOT + 49, 256, 0, stream>>>(mod_ret, mod_dram, mod_link,
                                              W_task, wtb, blkcnt_m, tcur);
    k_scan3<<<336, 512, 0, stream>>>(blkcnt_m, blkb, rcnt);
    k_mscatter3<<<NS_TOT, 512, 0, stream>>>(mod_ret, mod_dram, mod_link,
                                            task_ret, task_dram, task_link,
                                            feat_ret, feat_dram, feat_link,
                                            blkcnt_m, blkb,
                                            mrec_ret, mrec_dram, mrec_link);
    k_msum3<<<336, 1024, 0, stream>>>(mrec_ret, mrec_dram, mrec_link, rcnt,
                                      cnt, offs, csr, tcur,
                                      trec_ret, trec_dram, trec_link);
    k_passb3<<<16 * (SUB_RET + SUB_DRAM + SUB_LINK), 256, 0, stream>>>(
        trec_ret, trec_dram, trec_link, tcur, partials);
    k_mmred3<<<(3 * N_TASK + 255) / 256, 256, 0, stream>>>(partials, tmax, tmin);
  } else if (ws_size >= (size_t)WS_NEED2) {
    // ---- tier-2: R7 path ----
    unsigned* partials = (unsigned*)(ws + WS_PART2);
    u64* trec_ret  = (u64*)(ws + WS_TREC_RET);
    u64* trec_dram = (u64*)(ws + WS_TREC_DRAM);
    u64* trec_link = (u64*)(ws + WS_TREC_LINK);
    hp0 = (unsigned short*)(ws + WS_HPL0_2);
    hp1 = (unsigned short*)(ws + WS_HPL1_2);
    wtb = (unsigned short*)(ws + WS_WTB_2);
    k_count<<<2 * NS_TOT + 48, 256, 0, stream>>>(mod_ret, mod_dram, mod_link,
                                                 task_ret, task_dram, task_link,
                                                 W_task, wtb, blkcnt_m, blkb);
    k_scan<<<384, 512, 0, stream>>>(blkcnt_m, blkb, rcnt, tcur);
    k_mscatter2<<<NS_TOT, 256, 0, stream>>>(mod_ret, mod_dram, mod_link, task_link,
                                            feat_ret, feat_dram, feat_link, blkcnt_m,
                                            mrec_ret, mrec_dram, mrec_link);
    k_msum<<<336, 256, 0, stream>>>(mrec_ret, mrec_dram, mrec_link, rcnt,
                                    s_ret, s_dram, s_link, cnt, offs, csr);
    k_ascatter2<<<NS_TOT, 256, 0, stream>>>(task_ret, mod_ret, task_dram, mod_dram,
                                            task_link, mod_link, s_ret, s_dram, s_link,
                                            blkb, trec_ret, trec_dram, trec_link);
    k_passb<<<16 * (SUB_RET + SUB_DRAM + SUB_LINK), 256, 0, stream>>>(
        trec_ret, trec_dram, trec_link, tcur, partials);
    k_mmred2<<<(3 * N_TASK + 255) / 256, 256, 0, stream>>>(partials, tmax, tmin);
  } else {
    // ---- tier-3: global-atomic fallback ----
    int* part   = (int*)(ws + WS_BLKM);
    int* partx  = (int*)(ws + WS_BLKM + 4096);
    int* cursor = (int*)(ws + WS_BLKB);
    hp0 = (unsigned short*)(ws + WS_HPL0_2);
    hp1 = (unsigned short*)(ws + WS_HPL1_2);
    wtb = (unsigned short*)(ws + WS_WTB_2);
    hipMemsetAsync(ws, 0, 1900000, stream);
    hipMemsetAsync(ws + WS_TMIN, 0xFF, 600000, stream);
    const int totalE = E_RET + E_DRAM + E_LINK;
    int nblk_e = (totalE + 255) / 256;
    f_segsum<<<nblk_e, 256, 0, stream>>>(feat_ret, feat_dram, feat_link,
                                         mod_ret, mod_dram, mod_link,
                                         s_ret, s_dram, s_link, cnt);
    f_minmax<<<nblk_e, 256, 0, stream>>>(s_ret, s_dram, s_link,
                                         task_ret, mod_ret, task_dram, mod_dram,
                                         task_link, mod_link, tmax, tmin);
    const int npart = (N_LINK + 255) / 256;
    f_part<<<npart, 256, 0, stream>>>(cnt, part);
    f_scanpart<<<1, 512, 0, stream>>>(part, partx, npart);
    f_offs<<<npart, 256, 0, stream>>>(cnt, partx, offs, cursor);
    f_scatter<<<(E_LINK + 255) / 256, 256, 0, stream>>>(task_link, mod_link, cursor, csr);
    k_wprep<<<48, 256, 0, stream>>>(W_task, wtb);
  }

  k_taskm<<<(N_TASK / 16 + 3) / 4, 256, 0, stream>>>(W_ret, b_ret, W_dram, b_dram,
                                                     W_link, b_link, wtb, b_task,
                                                     tmax, tmin, hp0, hp1);
  k_link2<<<N_LINK / 8, 256, 0, stream>>>(hp0, offs, cnt, csr, out, 0);
  k_link2<<<N_LINK / 8, 256, 0, stream>>>(hp1, offs, cnt, csr, out, 1);
}